// Round 1
// baseline (7039.490 us; speedup 1.0000x reference)
//
#include <hip/hip_runtime.h>
#include <hip/hip_bf16.h>

// Problem constants (fixed by the reference)
#define H_DIM 512
#define N_HEADS 8
#define HEAD_DIM 64
#define NBATCH 16

// ---------------------------------------------------------------------------
// Tiled fp32 GEMM:  C[M,N] = A[M,K] @ W[N,K]^T + bias[N]   (NT, both row-major)
// 64x64 tile, 256 threads, 4x4 micro-tile per thread, K-chunk 16.
// ---------------------------------------------------------------------------
__global__ __launch_bounds__(256) void gemm_nt_bias(
    const float* __restrict__ A, const float* __restrict__ W,
    const float* __restrict__ bias, float* __restrict__ C,
    int M, int N, int K) {
  __shared__ float As[16][65];
  __shared__ float Ws[16][65];
  const int tid = threadIdx.x;
  const int tx = tid & 15, ty = tid >> 4;
  const int bm = blockIdx.x * 64, bn = blockIdx.y * 64;
  float acc[4][4] = {};
  for (int k0 = 0; k0 < K; k0 += 16) {
#pragma unroll
    for (int t = 0; t < 4; ++t) {
      int lin = tid + t * 256;          // 0..1023
      int r = lin >> 4, kk = lin & 15;  // 64 rows x 16 ks
      int gr = bm + r;
      As[kk][r] = (gr < M) ? A[(size_t)gr * K + k0 + kk] : 0.f;
      int gn = bn + r;
      Ws[kk][r] = (gn < N) ? W[(size_t)gn * K + k0 + kk] : 0.f;
    }
    __syncthreads();
#pragma unroll
    for (int kk = 0; kk < 16; ++kk) {
      float a[4], b[4];
#pragma unroll
      for (int i = 0; i < 4; ++i) a[i] = As[kk][ty + 16 * i];
#pragma unroll
      for (int j = 0; j < 4; ++j) b[j] = Ws[kk][tx + 16 * j];
#pragma unroll
      for (int i = 0; i < 4; ++i)
#pragma unroll
        for (int j = 0; j < 4; ++j) acc[i][j] = fmaf(a[i], b[j], acc[i][j]);
    }
    __syncthreads();
  }
#pragma unroll
  for (int i = 0; i < 4; ++i) {
    int r = bm + ty + 16 * i;
    if (r >= M) continue;
#pragma unroll
    for (int j = 0; j < 4; ++j) {
      int c = bn + tx + 16 * j;
      if (c >= N) continue;
      C[(size_t)r * N + c] = acc[i][j] + bias[c];
    }
  }
}

// ---------------------------------------------------------------------------
// Concat GEMM: C[M,512] = [A1 | A2][M,1024] @ W[512,1024]^T + bias
// K chunks of 16 never straddle the 512 boundary.
// ---------------------------------------------------------------------------
__global__ __launch_bounds__(256) void gemm_cat_nt_bias(
    const float* __restrict__ A1, const float* __restrict__ A2,
    const float* __restrict__ W, const float* __restrict__ bias,
    float* __restrict__ C, int M) {
  __shared__ float As[16][65];
  __shared__ float Ws[16][65];
  const int tid = threadIdx.x;
  const int tx = tid & 15, ty = tid >> 4;
  const int bm = blockIdx.x * 64, bn = blockIdx.y * 64;
  float acc[4][4] = {};
  for (int k0 = 0; k0 < 1024; k0 += 16) {
    const float* Asrc = (k0 < 512) ? A1 : A2;
    const int kbase = (k0 < 512) ? k0 : (k0 - 512);
#pragma unroll
    for (int t = 0; t < 4; ++t) {
      int lin = tid + t * 256;
      int r = lin >> 4, kk = lin & 15;
      int gr = bm + r;
      As[kk][r] = (gr < M) ? Asrc[(size_t)gr * 512 + kbase + kk] : 0.f;
      int gn = bn + r;
      Ws[kk][r] = W[(size_t)gn * 1024 + k0 + kk];
    }
    __syncthreads();
#pragma unroll
    for (int kk = 0; kk < 16; ++kk) {
      float a[4], b[4];
#pragma unroll
      for (int i = 0; i < 4; ++i) a[i] = As[kk][ty + 16 * i];
#pragma unroll
      for (int j = 0; j < 4; ++j) b[j] = Ws[kk][tx + 16 * j];
#pragma unroll
      for (int i = 0; i < 4; ++i)
#pragma unroll
        for (int j = 0; j < 4; ++j) acc[i][j] = fmaf(a[i], b[j], acc[i][j]);
    }
    __syncthreads();
  }
#pragma unroll
  for (int i = 0; i < 4; ++i) {
    int r = bm + ty + 16 * i;
    if (r >= M) continue;
#pragma unroll
    for (int j = 0; j < 4; ++j) {
      int c = bn + tx + 16 * j;
      C[(size_t)r * 512 + c] = acc[i][j] + bias[c];
    }
  }
}

// ---------------------------------------------------------------------------
// Attention: one 64-lane wave per (dst_row, head).
// Channel layout: c = d*N_HEADS + h (interleaved heads, stride 8).
// ---------------------------------------------------------------------------
__global__ __launch_bounds__(64) void attn_kernel(
    const float* __restrict__ Q, const float* __restrict__ K,
    const float* __restrict__ V, const int* __restrict__ dlens,
    const int* __restrict__ slens, float* __restrict__ O) {
  const int row = blockIdx.x;   // flat dst row
  const int h = blockIdx.y;     // head
  const int lane = threadIdx.x; // 0..63

  // Find batch b and src offset by scanning the 16 lengths (uniform).
  int b = 0;
  {
    int accum = 0;
    for (int i = 0; i < NBATCH; ++i) {
      int l = dlens[i];
      if (row < accum + l) { b = i; break; }
      accum += l;
    }
  }
  int soff = 0;
  for (int i = 0; i < NBATCH; ++i) soff += (i < b) ? slens[i] : 0;
  const int slen = slens[b];

  __shared__ float qs[64];
  __shared__ float sc[512];  // src_len <= 512

  qs[lane] = Q[(size_t)row * H_DIM + lane * N_HEADS + h];
  __syncthreads();

  // scores
  for (int m = lane; m < slen; m += 64) {
    const float* krow = K + (size_t)(soff + m) * H_DIM + h;
    float s = 0.f;
#pragma unroll
    for (int d = 0; d < 64; ++d) s = fmaf(qs[d], krow[d * N_HEADS], s);
    sc[m] = s * 0.125f;  // 1/sqrt(64)
  }
  __syncthreads();

  // max over valid scores (single wave == block, shuffle reduce)
  float mx = -1e30f;
  for (int m = lane; m < slen; m += 64) mx = fmaxf(mx, sc[m]);
#pragma unroll
  for (int o = 32; o > 0; o >>= 1) mx = fmaxf(mx, __shfl_xor(mx, o, 64));

  float sum = 0.f;
  for (int m = lane; m < slen; m += 64) {
    float e = __expf(sc[m] - mx);
    sc[m] = e;
    sum += e;
  }
#pragma unroll
  for (int o = 32; o > 0; o >>= 1) sum += __shfl_xor(sum, o, 64);
  __syncthreads();
  const float inv = 1.f / sum;

  // PV: lane == d
  float oacc = 0.f;
  const float* vbase = V + (size_t)soff * H_DIM + lane * N_HEADS + h;
  for (int m = 0; m < slen; ++m) oacc = fmaf(sc[m], vbase[(size_t)m * H_DIM], oacc);
  O[(size_t)row * H_DIM + lane * N_HEADS + h] = oacc * inv;
}

// ---------------------------------------------------------------------------
// BatchNorm statistics: per-channel sum / sumsq over M rows (512 channels).
// stats[0..511] = sum, stats[512..1023] = sumsq. Must be pre-zeroed.
// ---------------------------------------------------------------------------
__global__ __launch_bounds__(256) void bn_stats(
    const float* __restrict__ X, float* __restrict__ stats, int M) {
  const int c0 = threadIdx.x;            // channel t and t+256
  const int nb = gridDim.x;
  const int rows = (M + nb - 1) / nb;
  const int r0 = blockIdx.x * rows;
  const int r1 = (r0 + rows < M) ? (r0 + rows) : M;
  float s0 = 0.f, q0 = 0.f, s1 = 0.f, q1 = 0.f;
  for (int r = r0; r < r1; ++r) {
    float x0 = X[(size_t)r * H_DIM + c0];
    float x1 = X[(size_t)r * H_DIM + c0 + 256];
    s0 += x0; q0 = fmaf(x0, x0, q0);
    s1 += x1; q1 = fmaf(x1, x1, q1);
  }
  atomicAdd(&stats[c0], s0);
  atomicAdd(&stats[H_DIM + c0], q0);
  atomicAdd(&stats[c0 + 256], s1);
  atomicAdd(&stats[H_DIM + c0 + 256], q1);
}

// ---------------------------------------------------------------------------
// BN apply: y = (x-m)/sqrt(v+eps)*g + be ; optional ReLU ; optional residual.
// ---------------------------------------------------------------------------
__global__ __launch_bounds__(256) void bn_apply(
    const float* __restrict__ X, const float* __restrict__ stats,
    const float* __restrict__ g, const float* __restrict__ be,
    const float* __restrict__ resid, float* __restrict__ Y,
    int M, float invM, int relu) {
  const size_t total = (size_t)M * H_DIM;
  for (size_t i = (size_t)blockIdx.x * 256 + threadIdx.x; i < total;
       i += (size_t)gridDim.x * 256) {
    int c = (int)(i & (H_DIM - 1));
    float mean = stats[c] * invM;
    float var = fmaf(-mean, mean, stats[H_DIM + c] * invM);
    float x = X[i];
    float y = (x - mean) * rsqrtf(var + 1e-5f) * g[c] + be[c];
    if (relu) y = fmaxf(y, 0.f);
    if (resid) y += resid[i];
    Y[i] = y;
  }
}

// ---------------------------------------------------------------------------
extern "C" void kernel_launch(void* const* d_in, const int* in_sizes, int n_in,
                              void* d_out, int out_size, void* d_ws, size_t ws_size,
                              hipStream_t stream) {
  const float* src_h = (const float*)d_in[0];
  const float* dst_h = (const float*)d_in[1];
  const int* s_lens  = (const int*)d_in[2];
  const int* d_lens  = (const int*)d_in[3];
  const float* Wq = (const float*)d_in[4];  const float* bq = (const float*)d_in[5];
  const float* Wk = (const float*)d_in[6];  const float* bk = (const float*)d_in[7];
  const float* Wv = (const float*)d_in[8];  const float* bv = (const float*)d_in[9];
  const float* Wm = (const float*)d_in[10]; const float* bm = (const float*)d_in[11];
  const float* W1 = (const float*)d_in[12]; const float* b1 = (const float*)d_in[13];
  const float* g1 = (const float*)d_in[14]; const float* be1 = (const float*)d_in[15];
  const float* W2 = (const float*)d_in[16]; const float* b2 = (const float*)d_in[17];
  const float* g2 = (const float*)d_in[18]; const float* be2 = (const float*)d_in[19];

  const int total_src = in_sizes[0] / H_DIM;  // 7232
  const int total_dst = in_sizes[1] / H_DIM;  // 6016

  // Workspace layout (floats). Peak ~54.3 MB.
  float* ws = (float*)d_ws;
  float* Qb = ws;                                   // [total_dst,512]
  float* Kb = Qb + (size_t)total_dst * H_DIM;       // [total_src,512]
  float* Vb = Kb + (size_t)total_src * H_DIM;       // [total_src,512]
  float* Ob = Vb + (size_t)total_src * H_DIM;       // [total_dst,512]
  float* st1 = Ob + (size_t)total_dst * H_DIM;      // 1024 floats
  float* st2 = st1 + 1024;                          // 1024 floats
  float* Mb = Qb;  // h_msg reuses Q buffer (free after attention)
  float* X1 = Kb;  // FFN1 out reuses K buffer
  float* X2 = Vb;  // FFN2 out reuses V buffer

  const int mbd = (total_dst + 63) / 64;  // 94
  const int mbs = (total_src + 63) / 64;  // 113
  const dim3 blk(256);

  // 1-3: Q/K/V projections
  gemm_nt_bias<<<dim3(mbd, 8), blk, 0, stream>>>(dst_h, Wq, bq, Qb, total_dst, H_DIM, H_DIM);
  gemm_nt_bias<<<dim3(mbs, 8), blk, 0, stream>>>(src_h, Wk, bk, Kb, total_src, H_DIM, H_DIM);
  gemm_nt_bias<<<dim3(mbs, 8), blk, 0, stream>>>(src_h, Wv, bv, Vb, total_src, H_DIM, H_DIM);

  // 4: ragged attention per (dst_row, head)
  attn_kernel<<<dim3(total_dst, N_HEADS), dim3(64), 0, stream>>>(Qb, Kb, Vb, d_lens, s_lens, Ob);

  // 5: merge projection
  gemm_nt_bias<<<dim3(mbd, 8), blk, 0, stream>>>(Ob, Wm, bm, Mb, total_dst, H_DIM, H_DIM);

  // 6: FFN1 on concat([dst_h, h_msg])
  gemm_cat_nt_bias<<<dim3(mbd, 8), blk, 0, stream>>>(dst_h, Mb, W1, b1, X1, total_dst);

  // 7-8: BN1 + ReLU (in place)
  hipMemsetAsync(st1, 0, 1024 * sizeof(float), stream);
  bn_stats<<<dim3(64), blk, 0, stream>>>(X1, st1, total_dst);
  bn_apply<<<dim3(512), blk, 0, stream>>>(X1, st1, g1, be1, nullptr, X1, total_dst,
                                          1.f / (float)total_dst, 1);

  // 9: FFN2
  gemm_nt_bias<<<dim3(mbd, 8), blk, 0, stream>>>(X1, W2, b2, X2, total_dst, H_DIM, H_DIM);

  // 10-11: BN2 + residual -> out
  hipMemsetAsync(st2, 0, 1024 * sizeof(float), stream);
  bn_stats<<<dim3(64), blk, 0, stream>>>(X2, st2, total_dst);
  bn_apply<<<dim3(512), blk, 0, stream>>>(X2, st2, g2, be2, dst_h, (float*)d_out, total_dst,
                                          1.f / (float)total_dst, 0);
}

// Round 2
// 1094.402 us; speedup vs baseline: 6.4323x; 6.4323x over previous
//
#include <hip/hip_runtime.h>
#include <hip/hip_bf16.h>

// Problem constants (fixed by the reference)
#define H_DIM 512
#define N_HEADS 8
#define HEAD_DIM 64
#define NBATCH 16

#define TS_D 32   // dst rows per attention tile
#define TS_S 64   // src rows per attention chunk

// ---------------------------------------------------------------------------
// Tiled fp32 GEMM:  C[M,N] = A[M,K] @ W[N,K]^T + bias[N]   (NT, both row-major)
// 64x64 tile, 256 threads, 4x4 micro-tile per thread, K-chunk 16.
// head_major: write C element (r,c) to plane layout [(c&7)][r][c>>3] (N==512).
// ---------------------------------------------------------------------------
__global__ __launch_bounds__(256) void gemm_nt_bias(
    const float* __restrict__ A, const float* __restrict__ W,
    const float* __restrict__ bias, float* __restrict__ C,
    int M, int N, int K, int head_major) {
  __shared__ float As[16][65];
  __shared__ float Ws[16][65];
  const int tid = threadIdx.x;
  const int tx = tid & 15, ty = tid >> 4;
  const int bm = blockIdx.x * 64, bn = blockIdx.y * 64;
  float acc[4][4] = {};
  for (int k0 = 0; k0 < K; k0 += 16) {
#pragma unroll
    for (int t = 0; t < 4; ++t) {
      int lin = tid + t * 256;          // 0..1023
      int r = lin >> 4, kk = lin & 15;  // 64 rows x 16 ks
      int gr = bm + r;
      As[kk][r] = (gr < M) ? A[(size_t)gr * K + k0 + kk] : 0.f;
      int gn = bn + r;
      Ws[kk][r] = (gn < N) ? W[(size_t)gn * K + k0 + kk] : 0.f;
    }
    __syncthreads();
#pragma unroll
    for (int kk = 0; kk < 16; ++kk) {
      float a[4], b[4];
#pragma unroll
      for (int i = 0; i < 4; ++i) a[i] = As[kk][ty + 16 * i];
#pragma unroll
      for (int j = 0; j < 4; ++j) b[j] = Ws[kk][tx + 16 * j];
#pragma unroll
      for (int i = 0; i < 4; ++i)
#pragma unroll
        for (int j = 0; j < 4; ++j) acc[i][j] = fmaf(a[i], b[j], acc[i][j]);
    }
    __syncthreads();
  }
#pragma unroll
  for (int i = 0; i < 4; ++i) {
    int r = bm + ty + 16 * i;
    if (r >= M) continue;
#pragma unroll
    for (int j = 0; j < 4; ++j) {
      int c = bn + tx + 16 * j;
      if (c >= N) continue;
      float val = acc[i][j] + bias[c];
      if (head_major) {
        int hh = c & 7, dd = c >> 3;
        C[(((size_t)hh * M) + r) * 64 + dd] = val;
      } else {
        C[(size_t)r * N + c] = val;
      }
    }
  }
}

// ---------------------------------------------------------------------------
// Concat GEMM: C[M,512] = [A1 | A2][M,1024] @ W[512,1024]^T + bias
// ---------------------------------------------------------------------------
__global__ __launch_bounds__(256) void gemm_cat_nt_bias(
    const float* __restrict__ A1, const float* __restrict__ A2,
    const float* __restrict__ W, const float* __restrict__ bias,
    float* __restrict__ C, int M) {
  __shared__ float As[16][65];
  __shared__ float Ws[16][65];
  const int tid = threadIdx.x;
  const int tx = tid & 15, ty = tid >> 4;
  const int bm = blockIdx.x * 64, bn = blockIdx.y * 64;
  float acc[4][4] = {};
  for (int k0 = 0; k0 < 1024; k0 += 16) {
    const float* Asrc = (k0 < 512) ? A1 : A2;
    const int kbase = (k0 < 512) ? k0 : (k0 - 512);
#pragma unroll
    for (int t = 0; t < 4; ++t) {
      int lin = tid + t * 256;
      int r = lin >> 4, kk = lin & 15;
      int gr = bm + r;
      As[kk][r] = (gr < M) ? Asrc[(size_t)gr * 512 + kbase + kk] : 0.f;
      int gn = bn + r;
      Ws[kk][r] = W[(size_t)gn * 1024 + k0 + kk];
    }
    __syncthreads();
#pragma unroll
    for (int kk = 0; kk < 16; ++kk) {
      float a[4], b[4];
#pragma unroll
      for (int i = 0; i < 4; ++i) a[i] = As[kk][ty + 16 * i];
#pragma unroll
      for (int j = 0; j < 4; ++j) b[j] = Ws[kk][tx + 16 * j];
#pragma unroll
      for (int i = 0; i < 4; ++i)
#pragma unroll
        for (int j = 0; j < 4; ++j) acc[i][j] = fmaf(a[i], b[j], acc[i][j]);
    }
    __syncthreads();
  }
#pragma unroll
  for (int i = 0; i < 4; ++i) {
    int r = bm + ty + 16 * i;
    if (r >= M) continue;
#pragma unroll
    for (int j = 0; j < 4; ++j) {
      int c = bn + tx + 16 * j;
      C[(size_t)r * 512 + c] = acc[i][j] + bias[c];
    }
  }
}

// ---------------------------------------------------------------------------
// Flash-style ragged attention.
// Inputs in head-major planes: Qh[h][dst_row][64], Kh/Vh[h][src_row][64].
// Output O in standard layout [dst_row][512] with c = d*8 + h.
// Grid: (batch=16, head=8, dst_tile<=16). Block: 256 threads.
// ---------------------------------------------------------------------------
__global__ __launch_bounds__(256) void attn_v2(
    const float* __restrict__ Qh, const float* __restrict__ Kh,
    const float* __restrict__ Vh, const int* __restrict__ dlens,
    const int* __restrict__ slens, float* __restrict__ O,
    int Md, int Ms) {
  const int b = blockIdx.x, h = blockIdx.y, tile = blockIdx.z;
  int doff = 0, soff = 0;
  for (int i = 0; i < NBATCH; ++i) {
    if (i < b) { doff += dlens[i]; soff += slens[i]; }
  }
  const int dlen = dlens[b], slen = slens[b];
  const int i0 = tile * TS_D;
  if (i0 >= dlen) return;
  const int ni = (TS_D < dlen - i0) ? TS_D : (dlen - i0);

  // LDS: strides chosen so row starts are 16B-aligned (float4 stores) and
  // score-phase reads are <=2-way bank aliased.
  __shared__ float Qs[TS_D * 68];
  __shared__ float Ks[TS_S * 68];
  __shared__ float Vs[TS_S * 64];
  __shared__ float Ps[TS_D * 68];
  __shared__ float alpha_s[TS_D];
  __shared__ float linv_s[TS_D];

  const int t = threadIdx.x;
  const int tx = t & 15, ty = t >> 4;            // scores: j = 4*tx.., i = 2*ty..
  const int pv_i = t >> 3, pv_d0 = (t & 7) * 8;  // PV: O[pv_i][pv_d0..pv_d0+7]

  // Load Q tile (coalesced float4 from head plane)
  const float* Qp = Qh + (((size_t)h * Md) + doff + i0) * 64;
  for (int s = t; s < TS_D * 16; s += 256) {
    int i = s >> 4, d4 = (s & 15) * 4;
    float4 v = (i < ni) ? *(const float4*)(Qp + (size_t)i * 64 + d4)
                        : make_float4(0.f, 0.f, 0.f, 0.f);
    *(float4*)(Qs + i * 68 + d4) = v;
  }

  float o_acc[8] = {0.f, 0.f, 0.f, 0.f, 0.f, 0.f, 0.f, 0.f};
  float m_i = -3.0e38f, l_i = 0.f;  // live in threads t < TS_D (row t)

  const float* Kp = Kh + (((size_t)h * Ms) + soff) * 64;
  const float* Vp = Vh + (((size_t)h * Ms) + soff) * 64;

  for (int j0 = 0; j0 < slen; j0 += TS_S) {
    const int nj = (TS_S < slen - j0) ? TS_S : (slen - j0);
    // Load K/V chunk
    for (int s = t; s < TS_S * 16; s += 256) {
      int j = s >> 4, d4 = (s & 15) * 4;
      float4 kv = (j < nj) ? *(const float4*)(Kp + (size_t)(j0 + j) * 64 + d4)
                           : make_float4(0.f, 0.f, 0.f, 0.f);
      *(float4*)(Ks + j * 68 + d4) = kv;
      float4 vv = (j < nj) ? *(const float4*)(Vp + (size_t)(j0 + j) * 64 + d4)
                           : make_float4(0.f, 0.f, 0.f, 0.f);
      *(float4*)(Vs + j * 64 + d4) = vv;
    }
    __syncthreads();

    // Scores: 2x4 micro-tile per thread
    float acc[2][4] = {};
#pragma unroll 4
    for (int d = 0; d < 64; ++d) {
      float q0 = Qs[(2 * ty) * 68 + d];
      float q1 = Qs[(2 * ty + 1) * 68 + d];
      float k0 = Ks[(4 * tx + 0) * 68 + d];
      float k1 = Ks[(4 * tx + 1) * 68 + d];
      float k2 = Ks[(4 * tx + 2) * 68 + d];
      float k3 = Ks[(4 * tx + 3) * 68 + d];
      acc[0][0] = fmaf(q0, k0, acc[0][0]);
      acc[0][1] = fmaf(q0, k1, acc[0][1]);
      acc[0][2] = fmaf(q0, k2, acc[0][2]);
      acc[0][3] = fmaf(q0, k3, acc[0][3]);
      acc[1][0] = fmaf(q1, k0, acc[1][0]);
      acc[1][1] = fmaf(q1, k1, acc[1][1]);
      acc[1][2] = fmaf(q1, k2, acc[1][2]);
      acc[1][3] = fmaf(q1, k3, acc[1][3]);
    }
#pragma unroll
    for (int r = 0; r < 2; ++r)
#pragma unroll
      for (int c = 0; c < 4; ++c)
        Ps[(2 * ty + r) * 68 + 4 * tx + c] = acc[r][c] * 0.125f;
    __syncthreads();

    // Online softmax: thread t < TS_D owns row t
    if (t < TS_D) {
      float cm = -3.0e38f;
      for (int j = 0; j < nj; ++j) cm = fmaxf(cm, Ps[t * 68 + j]);
      float mn = fmaxf(m_i, cm);
      float al = __expf(m_i - mn);
      float sum = 0.f;
      for (int j = 0; j < nj; ++j) {
        float e = __expf(Ps[t * 68 + j] - mn);
        Ps[t * 68 + j] = e;
        sum += e;
      }
      for (int j = nj; j < TS_S; ++j) Ps[t * 68 + j] = 0.f;
      m_i = mn;
      l_i = l_i * al + sum;
      alpha_s[t] = al;
    }
    __syncthreads();

    // PV accumulate: thread owns (pv_i, pv_d0..pv_d0+7)
    {
      float al = alpha_s[pv_i];
#pragma unroll
      for (int c = 0; c < 8; ++c) o_acc[c] *= al;
#pragma unroll 4
      for (int j = 0; j < TS_S; ++j) {
        float p = Ps[pv_i * 68 + j];
        const float* vr = Vs + j * 64 + pv_d0;
        float4 va = *(const float4*)(vr);
        float4 vb = *(const float4*)(vr + 4);
        o_acc[0] = fmaf(p, va.x, o_acc[0]);
        o_acc[1] = fmaf(p, va.y, o_acc[1]);
        o_acc[2] = fmaf(p, va.z, o_acc[2]);
        o_acc[3] = fmaf(p, va.w, o_acc[3]);
        o_acc[4] = fmaf(p, vb.x, o_acc[4]);
        o_acc[5] = fmaf(p, vb.y, o_acc[5]);
        o_acc[6] = fmaf(p, vb.z, o_acc[6]);
        o_acc[7] = fmaf(p, vb.w, o_acc[7]);
      }
    }
    __syncthreads();  // protect Ks/Vs/Ps before next chunk load
  }

  if (t < TS_D) linv_s[t] = 1.f / l_i;
  __syncthreads();
  if (pv_i < ni) {
    float inv = linv_s[pv_i];
    float* orow = O + (size_t)(doff + i0 + pv_i) * H_DIM + h;
#pragma unroll
    for (int c = 0; c < 8; ++c) orow[(pv_d0 + c) * 8] = o_acc[c] * inv;
  }
}

// ---------------------------------------------------------------------------
// BatchNorm statistics: per-channel sum / sumsq over M rows (512 channels).
// ---------------------------------------------------------------------------
__global__ __launch_bounds__(256) void bn_stats(
    const float* __restrict__ X, float* __restrict__ stats, int M) {
  const int c0 = threadIdx.x;
  const int nb = gridDim.x;
  const int rows = (M + nb - 1) / nb;
  const int r0 = blockIdx.x * rows;
  const int r1 = (r0 + rows < M) ? (r0 + rows) : M;
  float s0 = 0.f, q0 = 0.f, s1 = 0.f, q1 = 0.f;
  for (int r = r0; r < r1; ++r) {
    float x0 = X[(size_t)r * H_DIM + c0];
    float x1 = X[(size_t)r * H_DIM + c0 + 256];
    s0 += x0; q0 = fmaf(x0, x0, q0);
    s1 += x1; q1 = fmaf(x1, x1, q1);
  }
  atomicAdd(&stats[c0], s0);
  atomicAdd(&stats[H_DIM + c0], q0);
  atomicAdd(&stats[c0 + 256], s1);
  atomicAdd(&stats[H_DIM + c0 + 256], q1);
}

// ---------------------------------------------------------------------------
// BN apply: y = (x-m)/sqrt(v+eps)*g + be ; optional ReLU ; optional residual.
// ---------------------------------------------------------------------------
__global__ __launch_bounds__(256) void bn_apply(
    const float* __restrict__ X, const float* __restrict__ stats,
    const float* __restrict__ g, const float* __restrict__ be,
    const float* __restrict__ resid, float* __restrict__ Y,
    int M, float invM, int relu) {
  const size_t total = (size_t)M * H_DIM;
  for (size_t i = (size_t)blockIdx.x * 256 + threadIdx.x; i < total;
       i += (size_t)gridDim.x * 256) {
    int c = (int)(i & (H_DIM - 1));
    float mean = stats[c] * invM;
    float var = fmaf(-mean, mean, stats[H_DIM + c] * invM);
    float x = X[i];
    float y = (x - mean) * rsqrtf(var + 1e-5f) * g[c] + be[c];
    if (relu) y = fmaxf(y, 0.f);
    if (resid) y += resid[i];
    Y[i] = y;
  }
}

// ---------------------------------------------------------------------------
extern "C" void kernel_launch(void* const* d_in, const int* in_sizes, int n_in,
                              void* d_out, int out_size, void* d_ws, size_t ws_size,
                              hipStream_t stream) {
  const float* src_h = (const float*)d_in[0];
  const float* dst_h = (const float*)d_in[1];
  const int* s_lens  = (const int*)d_in[2];
  const int* d_lens  = (const int*)d_in[3];
  const float* Wq = (const float*)d_in[4];  const float* bq = (const float*)d_in[5];
  const float* Wk = (const float*)d_in[6];  const float* bk = (const float*)d_in[7];
  const float* Wv = (const float*)d_in[8];  const float* bv = (const float*)d_in[9];
  const float* Wm = (const float*)d_in[10]; const float* bm = (const float*)d_in[11];
  const float* W1 = (const float*)d_in[12]; const float* b1 = (const float*)d_in[13];
  const float* g1 = (const float*)d_in[14]; const float* be1 = (const float*)d_in[15];
  const float* W2 = (const float*)d_in[16]; const float* b2 = (const float*)d_in[17];
  const float* g2 = (const float*)d_in[18]; const float* be2 = (const float*)d_in[19];

  const int total_src = in_sizes[0] / H_DIM;  // 7232
  const int total_dst = in_sizes[1] / H_DIM;  // 6016

  // Workspace layout (floats). Peak ~54.3 MB.
  float* ws = (float*)d_ws;
  float* Qh = ws;                                   // [8][total_dst][64]
  float* Kh = Qh + (size_t)total_dst * H_DIM;       // [8][total_src][64]
  float* Vh = Kh + (size_t)total_src * H_DIM;       // [8][total_src][64]
  float* Ob = Vh + (size_t)total_src * H_DIM;       // [total_dst][512]
  float* st1 = Ob + (size_t)total_dst * H_DIM;      // 1024 floats
  float* st2 = st1 + 1024;                          // 1024 floats
  float* Mb = Qh;  // h_msg reuses Q buffer (free after attention)
  float* X1 = Kh;  // FFN1 out reuses K buffer
  float* X2 = Vh;  // FFN2 out reuses V buffer

  const int mbd = (total_dst + 63) / 64;  // 94
  const int mbs = (total_src + 63) / 64;  // 113
  const dim3 blk(256);

  // 1-3: Q/K/V projections, written directly to head-major planes
  gemm_nt_bias<<<dim3(mbd, 8), blk, 0, stream>>>(dst_h, Wq, bq, Qh, total_dst, H_DIM, H_DIM, 1);
  gemm_nt_bias<<<dim3(mbs, 8), blk, 0, stream>>>(src_h, Wk, bk, Kh, total_src, H_DIM, H_DIM, 1);
  gemm_nt_bias<<<dim3(mbs, 8), blk, 0, stream>>>(src_h, Wv, bv, Vh, total_src, H_DIM, H_DIM, 1);

  // 4: flash-style ragged attention
  attn_v2<<<dim3(NBATCH, N_HEADS, 16), blk, 0, stream>>>(Qh, Kh, Vh, d_lens, s_lens, Ob,
                                                         total_dst, total_src);

  // 5: merge projection
  gemm_nt_bias<<<dim3(mbd, 8), blk, 0, stream>>>(Ob, Wm, bm, Mb, total_dst, H_DIM, H_DIM, 0);

  // 6: FFN1 on concat([dst_h, h_msg])
  gemm_cat_nt_bias<<<dim3(mbd, 8), blk, 0, stream>>>(dst_h, Mb, W1, b1, X1, total_dst);

  // 7-8: BN1 + ReLU (in place)
  hipMemsetAsync(st1, 0, 1024 * sizeof(float), stream);
  bn_stats<<<dim3(64), blk, 0, stream>>>(X1, st1, total_dst);
  bn_apply<<<dim3(512), blk, 0, stream>>>(X1, st1, g1, be1, nullptr, X1, total_dst,
                                          1.f / (float)total_dst, 1);

  // 9: FFN2
  gemm_nt_bias<<<dim3(mbd, 8), blk, 0, stream>>>(X1, W2, b2, X2, total_dst, H_DIM, H_DIM, 0);

  // 10-11: BN2 + residual -> out
  hipMemsetAsync(st2, 0, 1024 * sizeof(float), stream);
  bn_stats<<<dim3(64), blk, 0, stream>>>(X2, st2, total_dst);
  bn_apply<<<dim3(512), blk, 0, stream>>>(X2, st2, g2, be2, dst_h, (float*)d_out, total_dst,
                                          1.f / (float)total_dst, 0);
}

// Round 3
// 543.344 us; speedup vs baseline: 12.9559x; 2.0142x over previous
//
#include <hip/hip_runtime.h>
#include <hip/hip_bf16.h>

#define H_DIM 512
#define N_HEADS 8
#define HEAD_DIM 64
#define NBATCH 16

#define TS_D 32   // dst rows per attention tile
#define TS_S 64   // src rows per attention chunk

typedef __attribute__((ext_vector_type(8))) short short8;   // 8 bf16 (4 VGPRs)
typedef __attribute__((ext_vector_type(4))) float floatx4;  // MFMA acc

typedef unsigned short us16;

__device__ inline unsigned short f2bf(float f) {
  unsigned int u = __float_as_uint(f);
  unsigned int r = (u + 0x7fffu + ((u >> 16) & 1u)) >> 16;  // RNE
  return (unsigned short)r;
}

// ---------------------------------------------------------------------------
// fp32 -> bf16 casts
// ---------------------------------------------------------------------------
__global__ __launch_bounds__(256) void cast_f2b(
    const float* __restrict__ s, us16* __restrict__ d, int n) {
  for (int i = ((int)blockIdx.x * 256 + (int)threadIdx.x) * 4; i < n;
       i += (int)gridDim.x * 256 * 4) {
    float4 v = *(const float4*)(s + i);
    ushort4 o;
    o.x = f2bf(v.x); o.y = f2bf(v.y); o.z = f2bf(v.z); o.w = f2bf(v.w);
    *(ushort4*)(d + i) = o;
  }
}

__global__ __launch_bounds__(256) void cast_w6(
    const float* __restrict__ w0, const float* __restrict__ w1,
    const float* __restrict__ w2, const float* __restrict__ w3,
    const float* __restrict__ w4, const float* __restrict__ w5,
    us16* __restrict__ dst) {
  const float* srcs[6] = {w0, w1, w2, w3, w4, w5};
  const int ns[6] = {262144, 262144, 262144, 262144, 524288, 262144};
  const int offs[6] = {0, 262144, 524288, 786432, 1048576, 1572864};
  for (int sgi = 0; sgi < 6; ++sgi) {
    const float* sp = srcs[sgi];
    us16* dp = dst + offs[sgi];
    for (int i = ((int)blockIdx.x * 256 + (int)threadIdx.x) * 4; i < ns[sgi];
         i += (int)gridDim.x * 256 * 4) {
      float4 v = *(const float4*)(sp + i);
      ushort4 o;
      o.x = f2bf(v.x); o.y = f2bf(v.y); o.z = f2bf(v.z); o.w = f2bf(v.w);
      *(ushort4*)(dp + i) = o;
    }
  }
}

// ---------------------------------------------------------------------------
// bf16 MFMA GEMM (NT): C[M,N] = A[M,K] @ W[N,K]^T + bias.
// One wave per block, 64x64 tile, 16x16x32 bf16 MFMA, 4x4 fragment grid.
// mode 0: fp32 out [M,N]; mode 1: bf16 head planes [(c&7)][r][c>>3] (N=512);
// mode 2: bf16 out [M,N].  Requires M%64==0, N%64==0, K%32==0.
// ---------------------------------------------------------------------------
__global__ __launch_bounds__(64) void gemm_bf16(
    const us16* __restrict__ A, const us16* __restrict__ W,
    const float* __restrict__ bias, void* __restrict__ C,
    int M, int N, int K, int mode) {
  __shared__ __align__(16) us16 As[64 * 56];  // pitch 56 elems = 112 B
  __shared__ __align__(16) us16 Bs[64 * 56];
  const int t = threadIdx.x;
  const int bm = blockIdx.x * 64, bn = blockIdx.y * 64;
  const int lane15 = t & 15, quad = t >> 4;
  const int sr = t >> 2, sc = (t & 3) * 8;  // staging: row-in-16-group, col

  floatx4 acc[4][4];
#pragma unroll
  for (int mt = 0; mt < 4; ++mt)
#pragma unroll
    for (int nt = 0; nt < 4; ++nt) acc[mt][nt] = (floatx4){0.f, 0.f, 0.f, 0.f};

  for (int k0 = 0; k0 < K; k0 += 32) {
#pragma unroll
    for (int p = 0; p < 4; ++p) {
      int row = sr + p * 16;
      uint4 av = *(const uint4*)(A + (size_t)(bm + row) * K + k0 + sc);
      *(uint4*)(&As[row * 56 + sc]) = av;
      uint4 wv = *(const uint4*)(W + (size_t)(bn + row) * K + k0 + sc);
      *(uint4*)(&Bs[row * 56 + sc]) = wv;
    }
    __syncthreads();
    short8 af[4], bfr[4];
#pragma unroll
    for (int mt = 0; mt < 4; ++mt)
      af[mt] = *(const short8*)(&As[(mt * 16 + lane15) * 56 + quad * 8]);
#pragma unroll
    for (int nt = 0; nt < 4; ++nt)
      bfr[nt] = *(const short8*)(&Bs[(nt * 16 + lane15) * 56 + quad * 8]);
#pragma unroll
    for (int mt = 0; mt < 4; ++mt)
#pragma unroll
      for (int nt = 0; nt < 4; ++nt)
        acc[mt][nt] = __builtin_amdgcn_mfma_f32_16x16x32_bf16(
            af[mt], bfr[nt], acc[mt][nt], 0, 0, 0);
    __syncthreads();
  }

#pragma unroll
  for (int mt = 0; mt < 4; ++mt) {
    int row0 = bm + mt * 16 + quad * 4;
#pragma unroll
    for (int nt = 0; nt < 4; ++nt) {
      int col = bn + nt * 16 + lane15;
      float bv = bias[col];
#pragma unroll
      for (int r = 0; r < 4; ++r) {
        float val = acc[mt][nt][r] + bv;
        int rr = row0 + r;
        if (mode == 0) {
          ((float*)C)[(size_t)rr * N + col] = val;
        } else if (mode == 1) {
          int hh = col & 7, dd = col >> 3;
          ((us16*)C)[(((size_t)hh * M) + rr) * 64 + dd] = f2bf(val);
        } else {
          ((us16*)C)[(size_t)rr * N + col] = f2bf(val);
        }
      }
    }
  }
}

// Concat variant: C[M,512] = [A1|A2][M,1024] @ W[512,1024]^T + bias, fp32 out.
__global__ __launch_bounds__(64) void gemm_cat_bf16(
    const us16* __restrict__ A1, const us16* __restrict__ A2,
    const us16* __restrict__ W, const float* __restrict__ bias,
    float* __restrict__ C, int M) {
  __shared__ __align__(16) us16 As[64 * 56];
  __shared__ __align__(16) us16 Bs[64 * 56];
  const int t = threadIdx.x;
  const int bm = blockIdx.x * 64, bn = blockIdx.y * 64;
  const int lane15 = t & 15, quad = t >> 4;
  const int sr = t >> 2, sc = (t & 3) * 8;

  floatx4 acc[4][4];
#pragma unroll
  for (int mt = 0; mt < 4; ++mt)
#pragma unroll
    for (int nt = 0; nt < 4; ++nt) acc[mt][nt] = (floatx4){0.f, 0.f, 0.f, 0.f};

  for (int k0 = 0; k0 < 1024; k0 += 32) {
    const us16* Asrc = (k0 < 512) ? A1 : A2;
    const int kb = k0 & 511;
#pragma unroll
    for (int p = 0; p < 4; ++p) {
      int row = sr + p * 16;
      uint4 av = *(const uint4*)(Asrc + (size_t)(bm + row) * 512 + kb + sc);
      *(uint4*)(&As[row * 56 + sc]) = av;
      uint4 wv = *(const uint4*)(W + (size_t)(bn + row) * 1024 + k0 + sc);
      *(uint4*)(&Bs[row * 56 + sc]) = wv;
    }
    __syncthreads();
    short8 af[4], bfr[4];
#pragma unroll
    for (int mt = 0; mt < 4; ++mt)
      af[mt] = *(const short8*)(&As[(mt * 16 + lane15) * 56 + quad * 8]);
#pragma unroll
    for (int nt = 0; nt < 4; ++nt)
      bfr[nt] = *(const short8*)(&Bs[(nt * 16 + lane15) * 56 + quad * 8]);
#pragma unroll
    for (int mt = 0; mt < 4; ++mt)
#pragma unroll
      for (int nt = 0; nt < 4; ++nt)
        acc[mt][nt] = __builtin_amdgcn_mfma_f32_16x16x32_bf16(
            af[mt], bfr[nt], acc[mt][nt], 0, 0, 0);
    __syncthreads();
  }

#pragma unroll
  for (int mt = 0; mt < 4; ++mt) {
    int row0 = bm + mt * 16 + quad * 4;
#pragma unroll
    for (int nt = 0; nt < 4; ++nt) {
      int col = bn + nt * 16 + lane15;
      float bv = bias[col];
#pragma unroll
      for (int r = 0; r < 4; ++r)
        C[(size_t)(row0 + r) * 512 + col] = acc[mt][nt][r] + bv;
    }
  }
}

// ---------------------------------------------------------------------------
// Flash-style ragged attention, bf16 head-plane inputs, bf16 [M,512] output.
// Score-phase lane map j = tx + 16*cblk keeps all LDS traffic <=2-way banked.
// ---------------------------------------------------------------------------
__global__ __launch_bounds__(256) void attn_v3(
    const us16* __restrict__ Qh, const us16* __restrict__ Kh,
    const us16* __restrict__ Vh, const int* __restrict__ dlens,
    const int* __restrict__ slens, us16* __restrict__ O,
    int Md, int Ms) {
  const int b = blockIdx.x, h = blockIdx.y, tile = blockIdx.z;
  int doff = 0, soff = 0;
  for (int i = 0; i < NBATCH; ++i)
    if (i < b) { doff += dlens[i]; soff += slens[i]; }
  const int dlen = dlens[b], slen = slens[b];
  const int i0 = tile * TS_D;
  if (i0 >= dlen) return;
  const int ni = (TS_D < dlen - i0) ? TS_D : (dlen - i0);

  __shared__ __align__(16) float Qs[TS_D * 68];
  __shared__ __align__(16) float Ks[TS_S * 68];
  __shared__ __align__(16) float Vs[TS_S * 64];
  __shared__ __align__(16) float Ps[TS_D * 68];
  __shared__ float alpha_s[TS_D];
  __shared__ float linv_s[TS_D];

  const int t = threadIdx.x;
  const int tx = t & 15, ty = (t >> 4) & 3;      // per-wave-uniform micro-tile
  const int wv = t >> 6;                          // wave id 0..3
  const int pv_i = t >> 3, pv_d0 = (t & 7) * 8;  // PV mapping

  // Q tile: 32x64 bf16 -> fp32 LDS (one pass, 8 elems/thread)
  {
    int i = t >> 3, d0 = (t & 7) * 8;
    float4 fa, fb;
    if (i < ni) {
      uint4 v = *(const uint4*)(Qh + (((size_t)h * Md) + doff + i0 + i) * 64 + d0);
      fa.x = __uint_as_float(v.x << 16); fa.y = __uint_as_float(v.x & 0xffff0000u);
      fa.z = __uint_as_float(v.y << 16); fa.w = __uint_as_float(v.y & 0xffff0000u);
      fb.x = __uint_as_float(v.z << 16); fb.y = __uint_as_float(v.z & 0xffff0000u);
      fb.z = __uint_as_float(v.w << 16); fb.w = __uint_as_float(v.w & 0xffff0000u);
    } else {
      fa = make_float4(0.f, 0.f, 0.f, 0.f); fb = fa;
    }
    *(float4*)(Qs + i * 68 + d0) = fa;
    *(float4*)(Qs + i * 68 + d0 + 4) = fb;
  }

  float o_acc[8] = {0.f, 0.f, 0.f, 0.f, 0.f, 0.f, 0.f, 0.f};
  float m_i = -3.0e38f, l_i = 0.f;  // rows owned by t < TS_D

  const us16* Kp = Kh + (((size_t)h * Ms) + soff) * 64;
  const us16* Vp = Vh + (((size_t)h * Ms) + soff) * 64;

  // score-phase row pair for this thread: i = 2*(4*wv+ty)+r  -> need i<32:
  const int qi = 2 * (4 * wv + ty);  // 0,2,...,30 across the block

  for (int j0 = 0; j0 < slen; j0 += TS_S) {
    const int nj = (TS_S < slen - j0) ? TS_S : (slen - j0);
    // K/V chunk: 64x64 bf16 -> fp32 LDS (two passes)
#pragma unroll
    for (int p = 0; p < 2; ++p) {
      int j = (t >> 3) + p * 32, d0 = (t & 7) * 8;
      float4 fa, fb, ga, gb;
      if (j < nj) {
        uint4 v = *(const uint4*)(Kp + (size_t)(j0 + j) * 64 + d0);
        fa.x = __uint_as_float(v.x << 16); fa.y = __uint_as_float(v.x & 0xffff0000u);
        fa.z = __uint_as_float(v.y << 16); fa.w = __uint_as_float(v.y & 0xffff0000u);
        fb.x = __uint_as_float(v.z << 16); fb.y = __uint_as_float(v.z & 0xffff0000u);
        fb.z = __uint_as_float(v.w << 16); fb.w = __uint_as_float(v.w & 0xffff0000u);
        uint4 w = *(const uint4*)(Vp + (size_t)(j0 + j) * 64 + d0);
        ga.x = __uint_as_float(w.x << 16); ga.y = __uint_as_float(w.x & 0xffff0000u);
        ga.z = __uint_as_float(w.y << 16); ga.w = __uint_as_float(w.y & 0xffff0000u);
        gb.x = __uint_as_float(w.z << 16); gb.y = __uint_as_float(w.z & 0xffff0000u);
        gb.z = __uint_as_float(w.w << 16); gb.w = __uint_as_float(w.w & 0xffff0000u);
      } else {
        fa = make_float4(0.f, 0.f, 0.f, 0.f); fb = fa; ga = fa; gb = fa;
      }
      *(float4*)(Ks + j * 68 + d0) = fa;
      *(float4*)(Ks + j * 68 + d0 + 4) = fb;
      *(float4*)(Vs + j * 64 + d0) = ga;
      *(float4*)(Vs + j * 64 + d0 + 4) = gb;
    }
    __syncthreads();

    // Scores: rows {qi, qi+1}, cols {tx, tx+16, tx+32, tx+48}
    float acc[2][4] = {};
#pragma unroll 4
    for (int d = 0; d < 64; ++d) {
      float q0 = Qs[qi * 68 + d];
      float q1 = Qs[(qi + 1) * 68 + d];
      float k0 = Ks[(tx) * 68 + d];
      float k1 = Ks[(tx + 16) * 68 + d];
      float k2 = Ks[(tx + 32) * 68 + d];
      float k3 = Ks[(tx + 48) * 68 + d];
      acc[0][0] = fmaf(q0, k0, acc[0][0]);
      acc[0][1] = fmaf(q0, k1, acc[0][1]);
      acc[0][2] = fmaf(q0, k2, acc[0][2]);
      acc[0][3] = fmaf(q0, k3, acc[0][3]);
      acc[1][0] = fmaf(q1, k0, acc[1][0]);
      acc[1][1] = fmaf(q1, k1, acc[1][1]);
      acc[1][2] = fmaf(q1, k2, acc[1][2]);
      acc[1][3] = fmaf(q1, k3, acc[1][3]);
    }
#pragma unroll
    for (int r = 0; r < 2; ++r)
#pragma unroll
      for (int c = 0; c < 4; ++c)
        Ps[(qi + r) * 68 + tx + 16 * c] = acc[r][c] * 0.125f;
    __syncthreads();

    // Online softmax: thread t < TS_D owns row t
    if (t < TS_D) {
      float cm = -3.0e38f;
      for (int j = 0; j < nj; ++j) cm = fmaxf(cm, Ps[t * 68 + j]);
      float mn = fmaxf(m_i, cm);
      float al = __expf(m_i - mn);
      float sum = 0.f;
      for (int j = 0; j < nj; ++j) {
        float e = __expf(Ps[t * 68 + j] - mn);
        Ps[t * 68 + j] = e;
        sum += e;
      }
      for (int j = nj; j < TS_S; ++j) Ps[t * 68 + j] = 0.f;
      m_i = mn;
      l_i = l_i * al + sum;
      alpha_s[t] = al;
    }
    __syncthreads();

    // PV accumulate
    {
      float al = alpha_s[pv_i];
#pragma unroll
      for (int c = 0; c < 8; ++c) o_acc[c] *= al;
#pragma unroll 4
      for (int j = 0; j < TS_S; ++j) {
        float p = Ps[pv_i * 68 + j];
        const float* vr = Vs + j * 64 + pv_d0;
        float4 va = *(const float4*)(vr);
        float4 vb = *(const float4*)(vr + 4);
        o_acc[0] = fmaf(p, va.x, o_acc[0]);
        o_acc[1] = fmaf(p, va.y, o_acc[1]);
        o_acc[2] = fmaf(p, va.z, o_acc[2]);
        o_acc[3] = fmaf(p, va.w, o_acc[3]);
        o_acc[4] = fmaf(p, vb.x, o_acc[4]);
        o_acc[5] = fmaf(p, vb.y, o_acc[5]);
        o_acc[6] = fmaf(p, vb.z, o_acc[6]);
        o_acc[7] = fmaf(p, vb.w, o_acc[7]);
      }
    }
    __syncthreads();
  }

  if (t < TS_D) linv_s[t] = 1.f / l_i;
  __syncthreads();
  if (pv_i < ni) {
    float inv = linv_s[pv_i];
    us16* orow = O + (size_t)(doff + i0 + pv_i) * H_DIM + h;
#pragma unroll
    for (int c = 0; c < 8; ++c) orow[(pv_d0 + c) * 8] = f2bf(o_acc[c] * inv);
  }
}

// ---------------------------------------------------------------------------
// BatchNorm statistics (fp32 input): stats[0..511]=sum, [512..1023]=sumsq.
// ---------------------------------------------------------------------------
__global__ __launch_bounds__(256) void bn_stats(
    const float* __restrict__ X, float* __restrict__ stats, int M) {
  const int c0 = threadIdx.x;
  const int nb = gridDim.x;
  const int rows = (M + nb - 1) / nb;
  const int r0 = blockIdx.x * rows;
  const int r1 = (r0 + rows < M) ? (r0 + rows) : M;
  float s0 = 0.f, q0 = 0.f, s1 = 0.f, q1 = 0.f;
  for (int r = r0; r < r1; ++r) {
    float x0 = X[(size_t)r * H_DIM + c0];
    float x1 = X[(size_t)r * H_DIM + c0 + 256];
    s0 += x0; q0 = fmaf(x0, x0, q0);
    s1 += x1; q1 = fmaf(x1, x1, q1);
  }
  atomicAdd(&stats[c0], s0);
  atomicAdd(&stats[H_DIM + c0], q0);
  atomicAdd(&stats[c0 + 256], s1);
  atomicAdd(&stats[H_DIM + c0 + 256], q1);
}

// ---------------------------------------------------------------------------
// BN apply: optional ReLU / residual; out_bf selects bf16 vs fp32 output.
// ---------------------------------------------------------------------------
__global__ __launch_bounds__(256) void bn_apply(
    const float* __restrict__ X, const float* __restrict__ stats,
    const float* __restrict__ g, const float* __restrict__ be,
    const float* __restrict__ resid, void* __restrict__ Y,
    int M, float invM, int relu, int out_bf) {
  const size_t total = (size_t)M * H_DIM;
  for (size_t i = (size_t)blockIdx.x * 256 + threadIdx.x; i < total;
       i += (size_t)gridDim.x * 256) {
    int c = (int)(i & (H_DIM - 1));
    float mean = stats[c] * invM;
    float var = fmaf(-mean, mean, stats[H_DIM + c] * invM);
    float x = X[i];
    float y = (x - mean) * rsqrtf(var + 1e-5f) * g[c] + be[c];
    if (relu) y = fmaxf(y, 0.f);
    if (resid) y += resid[i];
    if (out_bf) ((us16*)Y)[i] = f2bf(y);
    else ((float*)Y)[i] = y;
  }
}

// ---------------------------------------------------------------------------
extern "C" void kernel_launch(void* const* d_in, const int* in_sizes, int n_in,
                              void* d_out, int out_size, void* d_ws, size_t ws_size,
                              hipStream_t stream) {
  const float* src_h = (const float*)d_in[0];
  const float* dst_h = (const float*)d_in[1];
  const int* s_lens  = (const int*)d_in[2];
  const int* d_lens  = (const int*)d_in[3];
  const float* Wq = (const float*)d_in[4];  const float* bq = (const float*)d_in[5];
  const float* Wk = (const float*)d_in[6];  const float* bk = (const float*)d_in[7];
  const float* Wv = (const float*)d_in[8];  const float* bv = (const float*)d_in[9];
  const float* Wm = (const float*)d_in[10]; const float* bm = (const float*)d_in[11];
  const float* W1 = (const float*)d_in[12]; const float* b1 = (const float*)d_in[13];
  const float* g1 = (const float*)d_in[14]; const float* be1 = (const float*)d_in[15];
  const float* W2 = (const float*)d_in[16]; const float* b2 = (const float*)d_in[17];
  const float* g2 = (const float*)d_in[18]; const float* be2 = (const float*)d_in[19];

  const int total_src = in_sizes[0] / H_DIM;  // 7232 (= 113*64)
  const int total_dst = in_sizes[1] / H_DIM;  // 6016 (= 94*64)

  // ---- workspace layout (byte offsets, all 256-aligned); peak ~50.5 MB ----
  char* ws = (char*)d_ws;
  us16* src_bf = (us16*)(ws + 0);                    //  7,405,568
  us16* dst_bf = (us16*)(ws + 7405568);              //  6,160,384
  us16* wbf    = (us16*)(ws + 13565952);             //  3,670,016
  us16* Qh     = (us16*)(ws + 17235968);             //  6,160,384
  us16* Kh     = (us16*)(ws + 23396352);             //  7,405,568
  us16* Vh     = (us16*)(ws + 30801920);             //  7,405,568
  us16* Ob     = (us16*)(ws + 38207488);             //  6,160,384
  us16* Mb     = (us16*)(ws + 44367872);             //  6,160,384
  float* st    = (float*)(ws + 50528256);            //  8,192
  float* X1    = (float*)(ws + 17235968);            // aliases Qh+Kh (dead)
  float* X2    = (float*)(ws + 30801920);            // aliases Vh+Ob (dead)
  us16* X1bf   = Mb;                                  // aliases Mb (dead)
  float* st1 = st, *st2 = st + 1024;

  us16* Wqb = wbf;
  us16* Wkb = wbf + 262144;
  us16* Wvb = wbf + 524288;
  us16* Wmb = wbf + 786432;
  us16* W1b = wbf + 1048576;
  us16* W2b = wbf + 1572864;

  const int mbd = total_dst / 64;  // 94
  const int mbs = total_src / 64;  // 113
  const dim3 blk256(256), blk64(64);

  // 0: casts
  cast_f2b<<<dim3(1024), blk256, 0, stream>>>(src_h, src_bf, total_src * H_DIM);
  cast_f2b<<<dim3(1024), blk256, 0, stream>>>(dst_h, dst_bf, total_dst * H_DIM);
  cast_w6<<<dim3(512), blk256, 0, stream>>>(Wq, Wk, Wv, Wm, W1, W2, wbf);

  // 1-3: Q/K/V projections -> bf16 head planes
  gemm_bf16<<<dim3(mbd, 8), blk64, 0, stream>>>(dst_bf, Wqb, bq, Qh, total_dst, H_DIM, H_DIM, 1);
  gemm_bf16<<<dim3(mbs, 8), blk64, 0, stream>>>(src_bf, Wkb, bk, Kh, total_src, H_DIM, H_DIM, 1);
  gemm_bf16<<<dim3(mbs, 8), blk64, 0, stream>>>(src_bf, Wvb, bv, Vh, total_src, H_DIM, H_DIM, 1);

  // 4: flash attention -> Ob (bf16 [M,512])
  attn_v3<<<dim3(NBATCH, N_HEADS, 16), blk256, 0, stream>>>(Qh, Kh, Vh, d_lens, s_lens, Ob,
                                                            total_dst, total_src);

  // 5: merge projection -> Mb (bf16)
  gemm_bf16<<<dim3(mbd, 8), blk64, 0, stream>>>(Ob, Wmb, bm, Mb, total_dst, H_DIM, H_DIM, 2);

  // 6: FFN1 concat -> X1 (fp32)
  gemm_cat_bf16<<<dim3(mbd, 8), blk64, 0, stream>>>(dst_bf, Mb, W1b, b1, X1, total_dst);

  // 7-8: BN1 + ReLU -> X1bf (bf16)
  hipMemsetAsync(st1, 0, 1024 * sizeof(float), stream);
  bn_stats<<<dim3(64), blk256, 0, stream>>>(X1, st1, total_dst);
  bn_apply<<<dim3(512), blk256, 0, stream>>>(X1, st1, g1, be1, nullptr, X1bf, total_dst,
                                             1.f / (float)total_dst, 1, 1);

  // 9: FFN2 -> X2 (fp32)
  gemm_bf16<<<dim3(mbd, 8), blk64, 0, stream>>>(X1bf, W2b, b2, X2, total_dst, H_DIM, H_DIM, 0);

  // 10-11: BN2 + residual -> d_out (fp32)
  hipMemsetAsync(st2, 0, 1024 * sizeof(float), stream);
  bn_stats<<<dim3(64), blk256, 0, stream>>>(X2, st2, total_dst);
  bn_apply<<<dim3(512), blk256, 0, stream>>>(X2, st2, g2, be2, dst_h, d_out, total_dst,
                                             1.f / (float)total_dst, 0, 0);
}

// Round 4
// 370.241 us; speedup vs baseline: 19.0133x; 1.4675x over previous
//
#include <hip/hip_runtime.h>
#include <hip/hip_bf16.h>

#define H_DIM 512
#define N_HEADS 8
#define HEAD_DIM 64
#define NBATCH 16

#define TS_D 32   // dst rows per attention tile
#define TS_S 64   // src rows per attention chunk

typedef __attribute__((ext_vector_type(8))) short short8;   // 8 bf16 (4 VGPRs)
typedef __attribute__((ext_vector_type(4))) float floatx4;  // MFMA acc

typedef unsigned short us16;

__device__ inline unsigned short f2bf(float f) {
  unsigned int u = __float_as_uint(f);
  unsigned int r = (u + 0x7fffu + ((u >> 16) & 1u)) >> 16;  // RNE
  return (unsigned short)r;
}

// ---------------------------------------------------------------------------
// fp32 -> bf16 casts
// ---------------------------------------------------------------------------
__global__ __launch_bounds__(256) void cast_f2b(
    const float* __restrict__ s, us16* __restrict__ d, int n) {
  for (int i = ((int)blockIdx.x * 256 + (int)threadIdx.x) * 4; i < n;
       i += (int)gridDim.x * 256 * 4) {
    float4 v = *(const float4*)(s + i);
    ushort4 o;
    o.x = f2bf(v.x); o.y = f2bf(v.y); o.z = f2bf(v.z); o.w = f2bf(v.w);
    *(ushort4*)(d + i) = o;
  }
}

__global__ __launch_bounds__(256) void cast_w6(
    const float* __restrict__ w0, const float* __restrict__ w1,
    const float* __restrict__ w2, const float* __restrict__ w3,
    const float* __restrict__ w4, const float* __restrict__ w5,
    us16* __restrict__ dst) {
  const float* srcs[6] = {w0, w1, w2, w3, w4, w5};
  const int ns[6] = {262144, 262144, 262144, 262144, 524288, 262144};
  const int offs[6] = {0, 262144, 524288, 786432, 1048576, 1572864};
  for (int sgi = 0; sgi < 6; ++sgi) {
    const float* sp = srcs[sgi];
    us16* dp = dst + offs[sgi];
    for (int i = ((int)blockIdx.x * 256 + (int)threadIdx.x) * 4; i < ns[sgi];
         i += (int)gridDim.x * 256 * 4) {
      float4 v = *(const float4*)(sp + i);
      ushort4 o;
      o.x = f2bf(v.x); o.y = f2bf(v.y); o.z = f2bf(v.z); o.w = f2bf(v.w);
      *(ushort4*)(dp + i) = o;
    }
  }
}

// ---------------------------------------------------------------------------
// bf16 MFMA GEMM (NT): C[M,N] = A[M,K] @ W[N,K]^T + bias.
// One wave per block, 64x64 tile, 16x16x32 bf16 MFMA, 4x4 fragment grid.
// mode 0: fp32 out [M,N]; mode 1: bf16 head planes [(c&7)][r][c>>3] (N=512);
// mode 2: bf16 out [M,N]; mode 3: bf16 transposed head planes
//   [(c&7)][c>>3][r]  (V^T for the PV MFMA; row length = M).
// Requires M%64==0, N%64==0, K%32==0.
// ---------------------------------------------------------------------------
__global__ __launch_bounds__(64) void gemm_bf16(
    const us16* __restrict__ A, const us16* __restrict__ W,
    const float* __restrict__ bias, void* __restrict__ C,
    int M, int N, int K, int mode) {
  __shared__ __align__(16) us16 As[64 * 56];  // pitch 56 elems = 112 B
  __shared__ __align__(16) us16 Bs[64 * 56];
  const int t = threadIdx.x;
  const int bm = blockIdx.x * 64, bn = blockIdx.y * 64;
  const int lane15 = t & 15, quad = t >> 4;
  const int sr = t >> 2, sc = (t & 3) * 8;  // staging: row-in-16-group, col

  floatx4 acc[4][4];
#pragma unroll
  for (int mt = 0; mt < 4; ++mt)
#pragma unroll
    for (int nt = 0; nt < 4; ++nt) acc[mt][nt] = (floatx4){0.f, 0.f, 0.f, 0.f};

  for (int k0 = 0; k0 < K; k0 += 32) {
#pragma unroll
    for (int p = 0; p < 4; ++p) {
      int row = sr + p * 16;
      uint4 av = *(const uint4*)(A + (size_t)(bm + row) * K + k0 + sc);
      *(uint4*)(&As[row * 56 + sc]) = av;
      uint4 wv = *(const uint4*)(W + (size_t)(bn + row) * K + k0 + sc);
      *(uint4*)(&Bs[row * 56 + sc]) = wv;
    }
    __syncthreads();
    short8 af[4], bfr[4];
#pragma unroll
    for (int mt = 0; mt < 4; ++mt)
      af[mt] = *(const short8*)(&As[(mt * 16 + lane15) * 56 + quad * 8]);
#pragma unroll
    for (int nt = 0; nt < 4; ++nt)
      bfr[nt] = *(const short8*)(&Bs[(nt * 16 + lane15) * 56 + quad * 8]);
#pragma unroll
    for (int mt = 0; mt < 4; ++mt)
#pragma unroll
      for (int nt = 0; nt < 4; ++nt)
        acc[mt][nt] = __builtin_amdgcn_mfma_f32_16x16x32_bf16(
            af[mt], bfr[nt], acc[mt][nt], 0, 0, 0);
    __syncthreads();
  }

#pragma unroll
  for (int mt = 0; mt < 4; ++mt) {
    int row0 = bm + mt * 16 + quad * 4;
#pragma unroll
    for (int nt = 0; nt < 4; ++nt) {
      int col = bn + nt * 16 + lane15;
      float bv = bias[col];
      if (mode == 3) {
        int hh = col & 7, dd = col >> 3;
        ushort4 pk;
        pk.x = f2bf(acc[mt][nt][0] + bv);
        pk.y = f2bf(acc[mt][nt][1] + bv);
        pk.z = f2bf(acc[mt][nt][2] + bv);
        pk.w = f2bf(acc[mt][nt][3] + bv);
        *(ushort4*)((us16*)C + ((size_t)(hh * 64 + dd)) * M + row0) = pk;
      } else {
#pragma unroll
        for (int r = 0; r < 4; ++r) {
          float val = acc[mt][nt][r] + bv;
          int rr = row0 + r;
          if (mode == 0) {
            ((float*)C)[(size_t)rr * N + col] = val;
          } else if (mode == 1) {
            int hh = col & 7, dd = col >> 3;
            ((us16*)C)[(((size_t)hh * M) + rr) * 64 + dd] = f2bf(val);
          } else {
            ((us16*)C)[(size_t)rr * N + col] = f2bf(val);
          }
        }
      }
    }
  }
}

// Concat variant: C[M,512] = [A1|A2][M,1024] @ W[512,1024]^T + bias, fp32 out.
__global__ __launch_bounds__(64) void gemm_cat_bf16(
    const us16* __restrict__ A1, const us16* __restrict__ A2,
    const us16* __restrict__ W, const float* __restrict__ bias,
    float* __restrict__ C, int M) {
  __shared__ __align__(16) us16 As[64 * 56];
  __shared__ __align__(16) us16 Bs[64 * 56];
  const int t = threadIdx.x;
  const int bm = blockIdx.x * 64, bn = blockIdx.y * 64;
  const int lane15 = t & 15, quad = t >> 4;
  const int sr = t >> 2, sc = (t & 3) * 8;

  floatx4 acc[4][4];
#pragma unroll
  for (int mt = 0; mt < 4; ++mt)
#pragma unroll
    for (int nt = 0; nt < 4; ++nt) acc[mt][nt] = (floatx4){0.f, 0.f, 0.f, 0.f};

  for (int k0 = 0; k0 < 1024; k0 += 32) {
    const us16* Asrc = (k0 < 512) ? A1 : A2;
    const int kb = k0 & 511;
#pragma unroll
    for (int p = 0; p < 4; ++p) {
      int row = sr + p * 16;
      uint4 av = *(const uint4*)(Asrc + (size_t)(bm + row) * 512 + kb + sc);
      *(uint4*)(&As[row * 56 + sc]) = av;
      uint4 wv = *(const uint4*)(W + (size_t)(bn + row) * 1024 + k0 + sc);
      *(uint4*)(&Bs[row * 56 + sc]) = wv;
    }
    __syncthreads();
    short8 af[4], bfr[4];
#pragma unroll
    for (int mt = 0; mt < 4; ++mt)
      af[mt] = *(const short8*)(&As[(mt * 16 + lane15) * 56 + quad * 8]);
#pragma unroll
    for (int nt = 0; nt < 4; ++nt)
      bfr[nt] = *(const short8*)(&Bs[(nt * 16 + lane15) * 56 + quad * 8]);
#pragma unroll
    for (int mt = 0; mt < 4; ++mt)
#pragma unroll
      for (int nt = 0; nt < 4; ++nt)
        acc[mt][nt] = __builtin_amdgcn_mfma_f32_16x16x32_bf16(
            af[mt], bfr[nt], acc[mt][nt], 0, 0, 0);
    __syncthreads();
  }

#pragma unroll
  for (int mt = 0; mt < 4; ++mt) {
    int row0 = bm + mt * 16 + quad * 4;
#pragma unroll
    for (int nt = 0; nt < 4; ++nt) {
      int col = bn + nt * 16 + lane15;
      float bv = bias[col];
#pragma unroll
      for (int r = 0; r < 4; ++r)
        C[(size_t)(row0 + r) * 512 + col] = acc[mt][nt][r] + bv;
    }
  }
}

// ---------------------------------------------------------------------------
// MFMA flash attention.
// Qh[h][row][64], Kh[h][row][64] bf16; Vt[h][d][src_row] bf16 (transposed).
// Output O bf16 [dst_row][512], c = d*8 + h.
// Grid: (batch, head, dst_tile). Block: 256 threads = 4 waves.
// Wave w: row-tile rt=w>>1 (16 rows), col/d-tiles {2*(w&1), 2*(w&1)+1}.
// Softmax: 8 threads per row (all 256 threads), butterfly shfl_xor.
// ---------------------------------------------------------------------------
__global__ __launch_bounds__(256) void attn_v4(
    const us16* __restrict__ Qh, const us16* __restrict__ Kh,
    const us16* __restrict__ Vt, const int* __restrict__ dlens,
    const int* __restrict__ slens, us16* __restrict__ O,
    int Md, int Ms) {
  const int b = blockIdx.x, h = blockIdx.y, tile = blockIdx.z;
  int doff = 0, soff = 0;
  for (int i = 0; i < NBATCH; ++i)
    if (i < b) { doff += dlens[i]; soff += slens[i]; }
  const int dlen = dlens[b], slen = slens[b];
  const int i0 = tile * TS_D;
  if (i0 >= dlen) return;
  const int ni = (TS_D < dlen - i0) ? TS_D : (dlen - i0);

  // LDS (36.6 KB total -> 4 blocks/CU)
  __shared__ __align__(16) us16 Qs[TS_D * 72];    // bf16, pitch 72
  __shared__ __align__(16) us16 Ks[TS_S * 72];
  __shared__ __align__(16) us16 Vts[64 * 72];     // [d][j]
  __shared__ __align__(16) float Ps32[TS_D * 68]; // scores fp32
  __shared__ __align__(16) us16 Pbf[TS_D * 72];   // P bf16 (A-layout)
  __shared__ float alpha_s[TS_D];
  __shared__ float linv_s[TS_D];

  const int t = threadIdx.x;
  const int wv = t >> 6;
  const int lane15 = t & 15, quad = (t >> 4) & 3;
  const int rt = wv >> 1;         // row tile 0/1
  const int cp = wv & 1;          // col-tile pair
  const int ct0 = 2 * cp, ct1 = 2 * cp + 1;
  const int srow = t >> 3, scg = t & 7;  // softmax: row, col-group

  const us16* Qp = Qh + ((size_t)h * Md + doff + i0) * 64;
  const us16* Kp = Kh + ((size_t)h * Ms + soff) * 64;
  const us16* Vtp = Vt + ((size_t)h * 64) * Ms + soff;

  // Stage Q tile (32 rows x 64): one 16B load per thread
  {
    int row = t >> 3, seg = t & 7;
    uint4 qv = make_uint4(0u, 0u, 0u, 0u);
    if (row < ni) qv = *(const uint4*)(Qp + (size_t)row * 64 + seg * 8);
    *(uint4*)(&Qs[row * 72 + seg * 8]) = qv;
  }
  __syncthreads();

  // Q fragments are invariant over the K-loop: hoist.
  short8 af[2];
#pragma unroll
  for (int kh = 0; kh < 2; ++kh)
    af[kh] = *(const short8*)(&Qs[(rt * 16 + lane15) * 72 + kh * 32 + quad * 8]);

  floatx4 o0 = (floatx4){0.f, 0.f, 0.f, 0.f};
  floatx4 o1 = (floatx4){0.f, 0.f, 0.f, 0.f};
  float m_i = -3.0e38f, l_i = 0.f;  // replicated per softmax thread (8/row)

  for (int j0 = 0; j0 < slen; j0 += TS_S) {
    const int nj = (TS_S < slen - j0) ? TS_S : (slen - j0);

    // ---- stage K chunk [64x64] and Vt chunk [64 d x 64 j] (bf16) ----
#pragma unroll
    for (int p = 0; p < 2; ++p) {
      int l = t + p * 256;
      int row = l >> 3, seg = l & 7;  // K: src row | Vt: d
      uint4 kv = make_uint4(0u, 0u, 0u, 0u);
      if (row < nj) kv = *(const uint4*)(Kp + (size_t)(j0 + row) * 64 + seg * 8);
      *(uint4*)(&Ks[row * 72 + seg * 8]) = kv;
      uint4 vv = make_uint4(0u, 0u, 0u, 0u);
      if (seg * 8 + 8 <= nj) {
        vv = *(const uint4*)(Vtp + (size_t)row * Ms + j0 + seg * 8);
      } else if (seg * 8 < nj) {
        us16 tmp[8] = {0, 0, 0, 0, 0, 0, 0, 0};
        for (int e = 0; e < 8; ++e)
          if (seg * 8 + e < nj) tmp[e] = Vtp[(size_t)row * Ms + j0 + seg * 8 + e];
        vv = *(uint4*)tmp;
      }
      *(uint4*)(&Vts[row * 72 + seg * 8]) = vv;
    }
    __syncthreads();

    // ---- scores: S[32,64] via MFMA, 2 tiles per wave ----
    {
      floatx4 s0 = (floatx4){0.f, 0.f, 0.f, 0.f};
      floatx4 s1 = (floatx4){0.f, 0.f, 0.f, 0.f};
#pragma unroll
      for (int kh = 0; kh < 2; ++kh) {
        short8 b0 = *(const short8*)(&Ks[(ct0 * 16 + lane15) * 72 + kh * 32 + quad * 8]);
        short8 b1 = *(const short8*)(&Ks[(ct1 * 16 + lane15) * 72 + kh * 32 + quad * 8]);
        s0 = __builtin_amdgcn_mfma_f32_16x16x32_bf16(af[kh], b0, s0, 0, 0, 0);
        s1 = __builtin_amdgcn_mfma_f32_16x16x32_bf16(af[kh], b1, s1, 0, 0, 0);
      }
#pragma unroll
      for (int r = 0; r < 4; ++r) {
        int prow = rt * 16 + quad * 4 + r;
        Ps32[prow * 68 + ct0 * 16 + lane15] = s0[r] * 0.125f;
        Ps32[prow * 68 + ct1 * 16 + lane15] = s1[r] * 0.125f;
      }
    }
    __syncthreads();

    // ---- online softmax: 8 threads per row ----
    {
      float v[8];
      float4 va = *(const float4*)(&Ps32[srow * 68 + scg * 8]);
      float4 vb = *(const float4*)(&Ps32[srow * 68 + scg * 8 + 4]);
      v[0] = va.x; v[1] = va.y; v[2] = va.z; v[3] = va.w;
      v[4] = vb.x; v[5] = vb.y; v[6] = vb.z; v[7] = vb.w;
      const int cbase = scg * 8;
#pragma unroll
      for (int e = 0; e < 8; ++e)
        if (cbase + e >= nj) v[e] = -3.0e38f;
      float mx = v[0];
#pragma unroll
      for (int e = 1; e < 8; ++e) mx = fmaxf(mx, v[e]);
      mx = fmaxf(mx, __shfl_xor(mx, 1));
      mx = fmaxf(mx, __shfl_xor(mx, 2));
      mx = fmaxf(mx, __shfl_xor(mx, 4));
      float mn = fmaxf(m_i, mx);
      float al = __expf(m_i - mn);
      float sum = 0.f;
      short8 pk;
#pragma unroll
      for (int e = 0; e < 8; ++e) {
        float ee = __expf(v[e] - mn);
        sum += ee;
        pk[e] = (short)f2bf(ee);
      }
      sum += __shfl_xor(sum, 1);
      sum += __shfl_xor(sum, 2);
      sum += __shfl_xor(sum, 4);
      m_i = mn;
      l_i = l_i * al + sum;
      *(short8*)(&Pbf[srow * 72 + cbase]) = pk;
      if (scg == 0) alpha_s[srow] = al;
    }
    __syncthreads();

    // ---- PV: O[32,64] += P[32,64] @ V[64,64] via MFMA ----
    {
      float al[4];
#pragma unroll
      for (int r = 0; r < 4; ++r) al[r] = alpha_s[rt * 16 + quad * 4 + r];
#pragma unroll
      for (int r = 0; r < 4; ++r) { o0[r] *= al[r]; o1[r] *= al[r]; }
#pragma unroll
      for (int kh = 0; kh < 2; ++kh) {
        short8 pa = *(const short8*)(&Pbf[(rt * 16 + lane15) * 72 + kh * 32 + quad * 8]);
        short8 v0 = *(const short8*)(&Vts[(ct0 * 16 + lane15) * 72 + kh * 32 + quad * 8]);
        short8 v1 = *(const short8*)(&Vts[(ct1 * 16 + lane15) * 72 + kh * 32 + quad * 8]);
        o0 = __builtin_amdgcn_mfma_f32_16x16x32_bf16(pa, v0, o0, 0, 0, 0);
        o1 = __builtin_amdgcn_mfma_f32_16x16x32_bf16(pa, v1, o1, 0, 0, 0);
      }
    }
    __syncthreads();  // Ks/Vts/Ps32/Pbf reused next chunk
  }

  if (scg == 0) linv_s[srow] = 1.f / l_i;
  __syncthreads();

  // Epilogue: O rows rt*16+quad*4+r, cols d = ct*16+lane15; c = d*8+h
#pragma unroll
  for (int r = 0; r < 4; ++r) {
    int i = rt * 16 + quad * 4 + r;
    if (i >= ni) continue;
    float inv = linv_s[i];
    us16* orow = O + (size_t)(doff + i0 + i) * H_DIM + h;
    orow[(ct0 * 16 + lane15) * 8] = f2bf(o0[r] * inv);
    orow[(ct1 * 16 + lane15) * 8] = f2bf(o1[r] * inv);
  }
}

// ---------------------------------------------------------------------------
// BatchNorm statistics (fp32 input): stats[0..511]=sum, [512..1023]=sumsq.
// ---------------------------------------------------------------------------
__global__ __launch_bounds__(256) void bn_stats(
    const float* __restrict__ X, float* __restrict__ stats, int M) {
  const int c0 = threadIdx.x;
  const int nb = gridDim.x;
  const int rows = (M + nb - 1) / nb;
  const int r0 = blockIdx.x * rows;
  const int r1 = (r0 + rows < M) ? (r0 + rows) : M;
  float s0 = 0.f, q0 = 0.f, s1 = 0.f, q1 = 0.f;
  for (int r = r0; r < r1; ++r) {
    float x0 = X[(size_t)r * H_DIM + c0];
    float x1 = X[(size_t)r * H_DIM + c0 + 256];
    s0 += x0; q0 = fmaf(x0, x0, q0);
    s1 += x1; q1 = fmaf(x1, x1, q1);
  }
  atomicAdd(&stats[c0], s0);
  atomicAdd(&stats[H_DIM + c0], q0);
  atomicAdd(&stats[c0 + 256], s1);
  atomicAdd(&stats[H_DIM + c0 + 256], q1);
}

// ---------------------------------------------------------------------------
// BN apply: optional ReLU / residual; out_bf selects bf16 vs fp32 output.
// ---------------------------------------------------------------------------
__global__ __launch_bounds__(256) void bn_apply(
    const float* __restrict__ X, const float* __restrict__ stats,
    const float* __restrict__ g, const float* __restrict__ be,
    const float* __restrict__ resid, void* __restrict__ Y,
    int M, float invM, int relu, int out_bf) {
  const size_t total = (size_t)M * H_DIM;
  for (size_t i = (size_t)blockIdx.x * 256 + threadIdx.x; i < total;
       i += (size_t)gridDim.x * 256) {
    int c = (int)(i & (H_DIM - 1));
    float mean = stats[c] * invM;
    float var = fmaf(-mean, mean, stats[H_DIM + c] * invM);
    float x = X[i];
    float y = (x - mean) * rsqrtf(var + 1e-5f) * g[c] + be[c];
    if (relu) y = fmaxf(y, 0.f);
    if (resid) y += resid[i];
    if (out_bf) ((us16*)Y)[i] = f2bf(y);
    else ((float*)Y)[i] = y;
  }
}

// ---------------------------------------------------------------------------
extern "C" void kernel_launch(void* const* d_in, const int* in_sizes, int n_in,
                              void* d_out, int out_size, void* d_ws, size_t ws_size,
                              hipStream_t stream) {
  const float* src_h = (const float*)d_in[0];
  const float* dst_h = (const float*)d_in[1];
  const int* s_lens  = (const int*)d_in[2];
  const int* d_lens  = (const int*)d_in[3];
  const float* Wq = (const float*)d_in[4];  const float* bq = (const float*)d_in[5];
  const float* Wk = (const float*)d_in[6];  const float* bk = (const float*)d_in[7];
  const float* Wv = (const float*)d_in[8];  const float* bv = (const float*)d_in[9];
  const float* Wm = (const float*)d_in[10]; const float* bm = (const float*)d_in[11];
  const float* W1 = (const float*)d_in[12]; const float* b1 = (const float*)d_in[13];
  const float* g1 = (const float*)d_in[14]; const float* be1 = (const float*)d_in[15];
  const float* W2 = (const float*)d_in[16]; const float* b2 = (const float*)d_in[17];
  const float* g2 = (const float*)d_in[18]; const float* be2 = (const float*)d_in[19];

  const int total_src = in_sizes[0] / H_DIM;  // 7232 (= 113*64)
  const int total_dst = in_sizes[1] / H_DIM;  // 6016 (= 94*64)

  // ---- workspace layout (byte offsets, all 256-aligned); peak ~50.5 MB ----
  char* ws = (char*)d_ws;
  us16* src_bf = (us16*)(ws + 0);                    //  7,405,568
  us16* dst_bf = (us16*)(ws + 7405568);              //  6,160,384
  us16* wbf    = (us16*)(ws + 13565952);             //  3,670,016
  us16* Qh     = (us16*)(ws + 17235968);             //  6,160,384
  us16* Kh     = (us16*)(ws + 23396352);             //  7,405,568
  us16* Vt     = (us16*)(ws + 30801920);             //  7,405,568 (transposed planes)
  us16* Ob     = (us16*)(ws + 38207488);             //  6,160,384
  us16* Mb     = (us16*)(ws + 44367872);             //  6,160,384
  float* st    = (float*)(ws + 50528256);            //  8,192
  float* X1    = (float*)(ws + 17235968);            // aliases Qh+Kh (dead)
  float* X2    = (float*)(ws + 30801920);            // aliases Vt+Ob (dead)
  us16* X1bf   = Mb;                                  // aliases Mb (dead)
  float* st1 = st, *st2 = st + 1024;

  us16* Wqb = wbf;
  us16* Wkb = wbf + 262144;
  us16* Wvb = wbf + 524288;
  us16* Wmb = wbf + 786432;
  us16* W1b = wbf + 1048576;
  us16* W2b = wbf + 1572864;

  const int mbd = total_dst / 64;  // 94
  const int mbs = total_src / 64;  // 113
  const dim3 blk256(256), blk64(64);

  // 0: casts
  cast_f2b<<<dim3(1024), blk256, 0, stream>>>(src_h, src_bf, total_src * H_DIM);
  cast_f2b<<<dim3(1024), blk256, 0, stream>>>(dst_h, dst_bf, total_dst * H_DIM);
  cast_w6<<<dim3(512), blk256, 0, stream>>>(Wq, Wk, Wv, Wm, W1, W2, wbf);

  // 1-3: Q/K projections -> bf16 head planes; V -> transposed planes
  gemm_bf16<<<dim3(mbd, 8), blk64, 0, stream>>>(dst_bf, Wqb, bq, Qh, total_dst, H_DIM, H_DIM, 1);
  gemm_bf16<<<dim3(mbs, 8), blk64, 0, stream>>>(src_bf, Wkb, bk, Kh, total_src, H_DIM, H_DIM, 1);
  gemm_bf16<<<dim3(mbs, 8), blk64, 0, stream>>>(src_bf, Wvb, bv, Vt, total_src, H_DIM, H_DIM, 3);

  // 4: MFMA flash attention -> Ob (bf16 [M,512])
  attn_v4<<<dim3(NBATCH, N_HEADS, 16), blk256, 0, stream>>>(Qh, Kh, Vt, d_lens, s_lens, Ob,
                                                            total_dst, total_src);

  // 5: merge projection -> Mb (bf16)
  gemm_bf16<<<dim3(mbd, 8), blk64, 0, stream>>>(Ob, Wmb, bm, Mb, total_dst, H_DIM, H_DIM, 2);

  // 6: FFN1 concat -> X1 (fp32)
  gemm_cat_bf16<<<dim3(mbd, 8), blk64, 0, stream>>>(dst_bf, Mb, W1b, b1, X1, total_dst);

  // 7-8: BN1 + ReLU -> X1bf (bf16)
  hipMemsetAsync(st1, 0, 1024 * sizeof(float), stream);
  bn_stats<<<dim3(64), blk256, 0, stream>>>(X1, st1, total_dst);
  bn_apply<<<dim3(512), blk256, 0, stream>>>(X1, st1, g1, be1, nullptr, X1bf, total_dst,
                                             1.f / (float)total_dst, 1, 1);

  // 9: FFN2 -> X2 (fp32)
  gemm_bf16<<<dim3(mbd, 8), blk64, 0, stream>>>(X1bf, W2b, b2, X2, total_dst, H_DIM, H_DIM, 0);

  // 10-11: BN2 + residual -> d_out (fp32)
  hipMemsetAsync(st2, 0, 1024 * sizeof(float), stream);
  bn_stats<<<dim3(64), blk256, 0, stream>>>(X2, st2, total_dst);
  bn_apply<<<dim3(512), blk256, 0, stream>>>(X2, st2, g2, be2, dst_h, d_out, total_dst,
                                             1.f / (float)total_dst, 0, 0);
}

// Round 5
// 307.037 us; speedup vs baseline: 22.9271x; 1.2058x over previous
//
#include <hip/hip_runtime.h>
#include <hip/hip_bf16.h>

#define H_DIM 512
#define N_HEADS 8
#define HEAD_DIM 64
#define NBATCH 16

#define TS_D 32   // dst rows per attention tile
#define TS_S 64   // src rows per attention chunk

// GEMM tile
#define BM 128
#define BN 128
#define BK 32

typedef __attribute__((ext_vector_type(8))) short short8;   // 8 bf16 (4 VGPRs)
typedef __attribute__((ext_vector_type(4))) float floatx4;  // MFMA acc

typedef unsigned short us16;

__device__ inline unsigned short f2bf(float f) {
  unsigned int u = __float_as_uint(f);
  unsigned int r = (u + 0x7fffu + ((u >> 16) & 1u)) >> 16;  // RNE
  return (unsigned short)r;
}

// async global->LDS, 16B per lane; lds dest = wave-uniform base + lane*16
__device__ inline void gld16(const us16* g, us16* l) {
  __builtin_amdgcn_global_load_lds(
      (const __attribute__((address_space(1))) void*)g,
      (__attribute__((address_space(3))) void*)l, 16, 0, 0);
}

// ---------------------------------------------------------------------------
// fp32 -> bf16 casts
// ---------------------------------------------------------------------------
__global__ __launch_bounds__(256) void cast_f2b(
    const float* __restrict__ s, us16* __restrict__ d, int n) {
  for (int i = ((int)blockIdx.x * 256 + (int)threadIdx.x) * 4; i < n;
       i += (int)gridDim.x * 256 * 4) {
    float4 v = *(const float4*)(s + i);
    ushort4 o;
    o.x = f2bf(v.x); o.y = f2bf(v.y); o.z = f2bf(v.z); o.w = f2bf(v.w);
    *(ushort4*)(d + i) = o;
  }
}

__global__ __launch_bounds__(256) void cast_w6(
    const float* __restrict__ w0, const float* __restrict__ w1,
    const float* __restrict__ w2, const float* __restrict__ w3,
    const float* __restrict__ w4, const float* __restrict__ w5,
    us16* __restrict__ dst) {
  const float* srcs[6] = {w0, w1, w2, w3, w4, w5};
  const int ns[6] = {262144, 262144, 262144, 262144, 524288, 262144};
  const int offs[6] = {0, 262144, 524288, 786432, 1048576, 1572864};
  for (int sgi = 0; sgi < 6; ++sgi) {
    const float* sp = srcs[sgi];
    us16* dp = dst + offs[sgi];
    for (int i = ((int)blockIdx.x * 256 + (int)threadIdx.x) * 4; i < ns[sgi];
         i += (int)gridDim.x * 256 * 4) {
      float4 v = *(const float4*)(sp + i);
      ushort4 o;
      o.x = f2bf(v.x); o.y = f2bf(v.y); o.z = f2bf(v.z); o.w = f2bf(v.w);
      *(ushort4*)(dp + i) = o;
    }
  }
}

// ---------------------------------------------------------------------------
// 128x128 MFMA GEMM (NT), m97-style: 256 thr / 4 waves, BK=32,
// global_load_lds(16B) staging into XOR-swizzled LDS (conflict-free b128).
// A row stride fixed 512 (all activations); k>=512 reads A2 (concat).
// W row stride = K. Requires N%128==0; M clamped on load, checked on store.
// modes:
//  0: fp32 out [M,N] + fused BN stats (sum/sumsq -> stats[0..511/512..1023])
//  1: bf16 Q head planes  C0[((c&7)*M + r)*64 + (c>>3)]
//  2: bf16 row-major [M,N]
//  4: KV fused (N=1024): c<512 -> K planes in C0; c>=512 -> Vt planes in C1
//     Vt layout: C1[((cv&7)*64 + (cv>>3))*M + r]
// ---------------------------------------------------------------------------
__global__ __launch_bounds__(256) void gemm128(
    const us16* __restrict__ A1, const us16* __restrict__ A2,
    const us16* __restrict__ W,
    const float* __restrict__ bias0, const float* __restrict__ bias1,
    void* __restrict__ C0, void* __restrict__ C1,
    float* __restrict__ stats,
    int M, int N, int K, int mode) {
  __shared__ __align__(16) us16 As[BM * BK];  // slot (row,s) at row*32 + s*8
  __shared__ __align__(16) us16 Bs[BN * BK];
  const int t = threadIdx.x;
  const int w = t >> 6, lane = t & 63;
  const int lane15 = lane & 15, quad = lane >> 4;
  const int wm = w >> 1, wn = w & 1;
  const int bm = blockIdx.x * BM, bn = blockIdx.y * BN;
  const int lr = lane >> 2;   // row within 16-row chunk
  const int sl = lane & 3;    // slot within row

  floatx4 acc[4][4];
#pragma unroll
  for (int mt = 0; mt < 4; ++mt)
#pragma unroll
    for (int nt = 0; nt < 4; ++nt) acc[mt][nt] = (floatx4){0.f, 0.f, 0.f, 0.f};

  const int sw = (lane15 >> 1) & 3;  // read-side swizzle

  for (int k0 = 0; k0 < K; k0 += BK) {
    const us16* Ab = (k0 < 512) ? A1 : A2;
    const int ka = k0 & 511;
    // stage A: 8 chunks of 16 rows; wave w does chunks {w, w+4}
#pragma unroll
    for (int p = 0; p < 2; ++p) {
      int ca = w + p * 4;
      int row = ca * 16 + lr;
      int kg = sl ^ ((row >> 1) & 3);
      int gr = bm + row; gr = (gr < M) ? gr : (M - 1);
      gld16(Ab + (size_t)gr * 512 + ka + kg * 8, As + ca * 512);
      int gn = bn + row;  // N tiles always full
      gld16(W + (size_t)gn * K + k0 + kg * 8, Bs + ca * 512);
    }
    __syncthreads();

    short8 af[4], bfr[4];
#pragma unroll
    for (int mt = 0; mt < 4; ++mt) {
      int row = wm * 64 + mt * 16 + lane15;
      af[mt] = *(const short8*)(As + row * 32 + (quad ^ sw) * 8);
    }
#pragma unroll
    for (int nt = 0; nt < 4; ++nt) {
      int row = wn * 64 + nt * 16 + lane15;
      bfr[nt] = *(const short8*)(Bs + row * 32 + (quad ^ sw) * 8);
    }
#pragma unroll
    for (int mt = 0; mt < 4; ++mt)
#pragma unroll
      for (int nt = 0; nt < 4; ++nt)
        acc[mt][nt] = __builtin_amdgcn_mfma_f32_16x16x32_bf16(
            af[mt], bfr[nt], acc[mt][nt], 0, 0, 0);
    __syncthreads();
  }

  // ---- epilogue ----
  if (mode == 0) {
    // fp32 out + fused BN stats (M%128==0 guaranteed here)
#pragma unroll
    for (int nt = 0; nt < 4; ++nt) {
      int col = bn + wn * 64 + nt * 16 + lane15;
      float bv = bias0[col];
      float s = 0.f, qq = 0.f;
#pragma unroll
      for (int mt = 0; mt < 4; ++mt) {
        int row0 = bm + wm * 64 + mt * 16 + quad * 4;
#pragma unroll
        for (int r = 0; r < 4; ++r) {
          float val = acc[mt][nt][r] + bv;
          ((float*)C0)[(size_t)(row0 + r) * N + col] = val;
          s += val; qq = fmaf(val, val, qq);
        }
      }
      s += __shfl_xor(s, 16); s += __shfl_xor(s, 32);
      qq += __shfl_xor(qq, 16); qq += __shfl_xor(qq, 32);
      if (quad == 0) {
        atomicAdd(&stats[col], s);
        atomicAdd(&stats[512 + col], qq);
      }
    }
  } else if (mode == 1) {
#pragma unroll
    for (int nt = 0; nt < 4; ++nt) {
      int col = bn + wn * 64 + nt * 16 + lane15;
      float bv = bias0[col];
      int hh = col & 7, dd = col >> 3;
#pragma unroll
      for (int mt = 0; mt < 4; ++mt) {
        int row0 = bm + wm * 64 + mt * 16 + quad * 4;
#pragma unroll
        for (int r = 0; r < 4; ++r) {
          int row = row0 + r;
          if (row < M)
            ((us16*)C0)[((size_t)hh * M + row) * 64 + dd] = f2bf(acc[mt][nt][r] + bv);
        }
      }
    }
  } else if (mode == 2) {
#pragma unroll
    for (int nt = 0; nt < 4; ++nt) {
      int col = bn + wn * 64 + nt * 16 + lane15;
      float bv = bias0[col];
#pragma unroll
      for (int mt = 0; mt < 4; ++mt) {
        int row0 = bm + wm * 64 + mt * 16 + quad * 4;
#pragma unroll
        for (int r = 0; r < 4; ++r) {
          int row = row0 + r;
          if (row < M)
            ((us16*)C0)[(size_t)row * N + col] = f2bf(acc[mt][nt][r] + bv);
        }
      }
    }
  } else {  // mode 4: KV fused
#pragma unroll
    for (int nt = 0; nt < 4; ++nt) {
      int col = bn + wn * 64 + nt * 16 + lane15;
      if (col < 512) {
        float bv = bias0[col];
        int hh = col & 7, dd = col >> 3;
#pragma unroll
        for (int mt = 0; mt < 4; ++mt) {
          int row0 = bm + wm * 64 + mt * 16 + quad * 4;
#pragma unroll
          for (int r = 0; r < 4; ++r) {
            int row = row0 + r;
            if (row < M)
              ((us16*)C0)[((size_t)hh * M + row) * 64 + dd] = f2bf(acc[mt][nt][r] + bv);
          }
        }
      } else {
        int cv = col - 512;
        float bv = bias1[cv];
        int plane = (cv & 7) * 64 + (cv >> 3);
#pragma unroll
        for (int mt = 0; mt < 4; ++mt) {
          int row0 = bm + wm * 64 + mt * 16 + quad * 4;
          if (row0 < M) {  // M%4==0 -> all 4 rows valid
            ushort4 pk;
            pk.x = f2bf(acc[mt][nt][0] + bv);
            pk.y = f2bf(acc[mt][nt][1] + bv);
            pk.z = f2bf(acc[mt][nt][2] + bv);
            pk.w = f2bf(acc[mt][nt][3] + bv);
            *(ushort4*)((us16*)C1 + (size_t)plane * M + row0) = pk;
          }
        }
      }
    }
  }
}

// ---------------------------------------------------------------------------
// MFMA flash attention (unchanged from round 4).
// ---------------------------------------------------------------------------
__global__ __launch_bounds__(256) void attn_v4(
    const us16* __restrict__ Qh, const us16* __restrict__ Kh,
    const us16* __restrict__ Vt, const int* __restrict__ dlens,
    const int* __restrict__ slens, us16* __restrict__ O,
    int Md, int Ms) {
  const int b = blockIdx.x, h = blockIdx.y, tile = blockIdx.z;
  int doff = 0, soff = 0;
  for (int i = 0; i < NBATCH; ++i)
    if (i < b) { doff += dlens[i]; soff += slens[i]; }
  const int dlen = dlens[b], slen = slens[b];
  const int i0 = tile * TS_D;
  if (i0 >= dlen) return;
  const int ni = (TS_D < dlen - i0) ? TS_D : (dlen - i0);

  __shared__ __align__(16) us16 Qs[TS_D * 72];
  __shared__ __align__(16) us16 Ks[TS_S * 72];
  __shared__ __align__(16) us16 Vts[64 * 72];
  __shared__ __align__(16) float Ps32[TS_D * 68];
  __shared__ __align__(16) us16 Pbf[TS_D * 72];
  __shared__ float alpha_s[TS_D];
  __shared__ float linv_s[TS_D];

  const int t = threadIdx.x;
  const int wv = t >> 6;
  const int lane15 = t & 15, quad = (t >> 4) & 3;
  const int rt = wv >> 1;
  const int cp = wv & 1;
  const int ct0 = 2 * cp, ct1 = 2 * cp + 1;
  const int srow = t >> 3, scg = t & 7;

  const us16* Qp = Qh + ((size_t)h * Md + doff + i0) * 64;
  const us16* Kp = Kh + ((size_t)h * Ms + soff) * 64;
  const us16* Vtp = Vt + ((size_t)h * 64) * Ms + soff;

  {
    int row = t >> 3, seg = t & 7;
    uint4 qv = make_uint4(0u, 0u, 0u, 0u);
    if (row < ni) qv = *(const uint4*)(Qp + (size_t)row * 64 + seg * 8);
    *(uint4*)(&Qs[row * 72 + seg * 8]) = qv;
  }
  __syncthreads();

  short8 af[2];
#pragma unroll
  for (int kh = 0; kh < 2; ++kh)
    af[kh] = *(const short8*)(&Qs[(rt * 16 + lane15) * 72 + kh * 32 + quad * 8]);

  floatx4 o0 = (floatx4){0.f, 0.f, 0.f, 0.f};
  floatx4 o1 = (floatx4){0.f, 0.f, 0.f, 0.f};
  float m_i = -3.0e38f, l_i = 0.f;

  for (int j0 = 0; j0 < slen; j0 += TS_S) {
    const int nj = (TS_S < slen - j0) ? TS_S : (slen - j0);
#pragma unroll
    for (int p = 0; p < 2; ++p) {
      int l = t + p * 256;
      int row = l >> 3, seg = l & 7;
      uint4 kv = make_uint4(0u, 0u, 0u, 0u);
      if (row < nj) kv = *(const uint4*)(Kp + (size_t)(j0 + row) * 64 + seg * 8);
      *(uint4*)(&Ks[row * 72 + seg * 8]) = kv;
      uint4 vv = make_uint4(0u, 0u, 0u, 0u);
      if (seg * 8 + 8 <= nj) {
        vv = *(const uint4*)(Vtp + (size_t)row * Ms + j0 + seg * 8);
      } else if (seg * 8 < nj) {
        us16 tmp[8] = {0, 0, 0, 0, 0, 0, 0, 0};
        for (int e = 0; e < 8; ++e)
          if (seg * 8 + e < nj) tmp[e] = Vtp[(size_t)row * Ms + j0 + seg * 8 + e];
        vv = *(uint4*)tmp;
      }
      *(uint4*)(&Vts[row * 72 + seg * 8]) = vv;
    }
    __syncthreads();

    {
      floatx4 s0 = (floatx4){0.f, 0.f, 0.f, 0.f};
      floatx4 s1 = (floatx4){0.f, 0.f, 0.f, 0.f};
#pragma unroll
      for (int kh = 0; kh < 2; ++kh) {
        short8 b0 = *(const short8*)(&Ks[(ct0 * 16 + lane15) * 72 + kh * 32 + quad * 8]);
        short8 b1 = *(const short8*)(&Ks[(ct1 * 16 + lane15) * 72 + kh * 32 + quad * 8]);
        s0 = __builtin_amdgcn_mfma_f32_16x16x32_bf16(af[kh], b0, s0, 0, 0, 0);
        s1 = __builtin_amdgcn_mfma_f32_16x16x32_bf16(af[kh], b1, s1, 0, 0, 0);
      }
#pragma unroll
      for (int r = 0; r < 4; ++r) {
        int prow = rt * 16 + quad * 4 + r;
        Ps32[prow * 68 + ct0 * 16 + lane15] = s0[r] * 0.125f;
        Ps32[prow * 68 + ct1 * 16 + lane15] = s1[r] * 0.125f;
      }
    }
    __syncthreads();

    {
      float v[8];
      float4 va = *(const float4*)(&Ps32[srow * 68 + scg * 8]);
      float4 vb = *(const float4*)(&Ps32[srow * 68 + scg * 8 + 4]);
      v[0] = va.x; v[1] = va.y; v[2] = va.z; v[3] = va.w;
      v[4] = vb.x; v[5] = vb.y; v[6] = vb.z; v[7] = vb.w;
      const int cbase = scg * 8;
#pragma unroll
      for (int e = 0; e < 8; ++e)
        if (cbase + e >= nj) v[e] = -3.0e38f;
      float mx = v[0];
#pragma unroll
      for (int e = 1; e < 8; ++e) mx = fmaxf(mx, v[e]);
      mx = fmaxf(mx, __shfl_xor(mx, 1));
      mx = fmaxf(mx, __shfl_xor(mx, 2));
      mx = fmaxf(mx, __shfl_xor(mx, 4));
      float mn = fmaxf(m_i, mx);
      float al = __expf(m_i - mn);
      float sum = 0.f;
      short8 pk;
#pragma unroll
      for (int e = 0; e < 8; ++e) {
        float ee = __expf(v[e] - mn);
        sum += ee;
        pk[e] = (short)f2bf(ee);
      }
      sum += __shfl_xor(sum, 1);
      sum += __shfl_xor(sum, 2);
      sum += __shfl_xor(sum, 4);
      m_i = mn;
      l_i = l_i * al + sum;
      *(short8*)(&Pbf[srow * 72 + cbase]) = pk;
      if (scg == 0) alpha_s[srow] = al;
    }
    __syncthreads();

    {
      float al[4];
#pragma unroll
      for (int r = 0; r < 4; ++r) al[r] = alpha_s[rt * 16 + quad * 4 + r];
#pragma unroll
      for (int r = 0; r < 4; ++r) { o0[r] *= al[r]; o1[r] *= al[r]; }
#pragma unroll
      for (int kh = 0; kh < 2; ++kh) {
        short8 pa = *(const short8*)(&Pbf[(rt * 16 + lane15) * 72 + kh * 32 + quad * 8]);
        short8 v0 = *(const short8*)(&Vts[(ct0 * 16 + lane15) * 72 + kh * 32 + quad * 8]);
        short8 v1 = *(const short8*)(&Vts[(ct1 * 16 + lane15) * 72 + kh * 32 + quad * 8]);
        o0 = __builtin_amdgcn_mfma_f32_16x16x32_bf16(pa, v0, o0, 0, 0, 0);
        o1 = __builtin_amdgcn_mfma_f32_16x16x32_bf16(pa, v1, o1, 0, 0, 0);
      }
    }
    __syncthreads();
  }

  if (scg == 0) linv_s[srow] = 1.f / l_i;
  __syncthreads();

#pragma unroll
  for (int r = 0; r < 4; ++r) {
    int i = rt * 16 + quad * 4 + r;
    if (i >= ni) continue;
    float inv = linv_s[i];
    us16* orow = O + (size_t)(doff + i0 + i) * H_DIM + h;
    orow[(ct0 * 16 + lane15) * 8] = f2bf(o0[r] * inv);
    orow[(ct1 * 16 + lane15) * 8] = f2bf(o1[r] * inv);
  }
}

// ---------------------------------------------------------------------------
// BN apply: optional ReLU / residual; out_bf selects bf16 vs fp32 output.
// ---------------------------------------------------------------------------
__global__ __launch_bounds__(256) void bn_apply(
    const float* __restrict__ X, const float* __restrict__ stats,
    const float* __restrict__ g, const float* __restrict__ be,
    const float* __restrict__ resid, void* __restrict__ Y,
    int M, float invM, int relu, int out_bf) {
  const size_t total = (size_t)M * H_DIM;
  for (size_t i = (size_t)blockIdx.x * 256 + threadIdx.x; i < total;
       i += (size_t)gridDim.x * 256) {
    int c = (int)(i & (H_DIM - 1));
    float mean = stats[c] * invM;
    float var = fmaf(-mean, mean, stats[H_DIM + c] * invM);
    float x = X[i];
    float y = (x - mean) * rsqrtf(var + 1e-5f) * g[c] + be[c];
    if (relu) y = fmaxf(y, 0.f);
    if (resid) y += resid[i];
    if (out_bf) ((us16*)Y)[i] = f2bf(y);
    else ((float*)Y)[i] = y;
  }
}

// ---------------------------------------------------------------------------
extern "C" void kernel_launch(void* const* d_in, const int* in_sizes, int n_in,
                              void* d_out, int out_size, void* d_ws, size_t ws_size,
                              hipStream_t stream) {
  const float* src_h = (const float*)d_in[0];
  const float* dst_h = (const float*)d_in[1];
  const int* s_lens  = (const int*)d_in[2];
  const int* d_lens  = (const int*)d_in[3];
  const float* Wq = (const float*)d_in[4];  const float* bq = (const float*)d_in[5];
  const float* Wk = (const float*)d_in[6];  const float* bk = (const float*)d_in[7];
  const float* Wv = (const float*)d_in[8];  const float* bv = (const float*)d_in[9];
  const float* Wm = (const float*)d_in[10]; const float* bm = (const float*)d_in[11];
  const float* W1 = (const float*)d_in[12]; const float* b1 = (const float*)d_in[13];
  const float* g1 = (const float*)d_in[14]; const float* be1 = (const float*)d_in[15];
  const float* W2 = (const float*)d_in[16]; const float* b2 = (const float*)d_in[17];
  const float* g2 = (const float*)d_in[18]; const float* be2 = (const float*)d_in[19];

  const int total_src = in_sizes[0] / H_DIM;  // 7232 (= 113*64)
  const int total_dst = in_sizes[1] / H_DIM;  // 6016 (= 47*128)

  // ---- workspace layout (byte offsets); peak ~50.5 MB ----
  char* ws = (char*)d_ws;
  us16* src_bf = (us16*)(ws + 0);                    //  7,405,568
  us16* dst_bf = (us16*)(ws + 7405568);              //  6,160,384
  us16* wbf    = (us16*)(ws + 13565952);             //  3,670,016
  us16* Qh     = (us16*)(ws + 17235968);             //  6,160,384
  us16* Kh     = (us16*)(ws + 23396352);             //  7,405,568
  us16* Vt     = (us16*)(ws + 30801920);             //  7,405,568
  us16* Ob     = (us16*)(ws + 38207488);             //  6,160,384
  us16* Mb     = (us16*)(ws + 44367872);             //  6,160,384
  float* st    = (float*)(ws + 50528256);            //  8,192
  float* X1    = (float*)(ws + 17235968);            // aliases Qh+Kh (dead)
  float* X2    = (float*)(ws + 30801920);            // aliases Vt+Ob (dead)
  us16* X1bf   = Mb;                                  // aliases Mb (dead)
  float* st1 = st, *st2 = st + 1024;

  us16* Wqb = wbf;
  us16* Wkv = wbf + 262144;   // Wk(512 rows) then Wv(512 rows), contiguous
  us16* Wmb = wbf + 786432;
  us16* W1b = wbf + 1048576;
  us16* W2b = wbf + 1572864;

  const int mt_d = total_dst / 128;            // 47 (exact)
  const int mt_s = (total_src + 127) / 128;    // 57 (ragged last tile)
  const dim3 blk256(256);

  // 0: casts + stats zero
  cast_f2b<<<dim3(1024), blk256, 0, stream>>>(src_h, src_bf, total_src * H_DIM);
  cast_f2b<<<dim3(1024), blk256, 0, stream>>>(dst_h, dst_bf, total_dst * H_DIM);
  cast_w6<<<dim3(512), blk256, 0, stream>>>(Wq, Wk, Wv, Wm, W1, W2, wbf);
  hipMemsetAsync(st, 0, 2048 * sizeof(float), stream);

  // 1: Q projection -> head planes (mode 1)
  gemm128<<<dim3(mt_d, 4), blk256, 0, stream>>>(
      dst_bf, dst_bf, Wqb, bq, nullptr, Qh, nullptr, nullptr,
      total_dst, H_DIM, H_DIM, 1);
  // 2: fused K+V projection (mode 4): K planes + Vt planes
  gemm128<<<dim3(mt_s, 8), blk256, 0, stream>>>(
      src_bf, src_bf, Wkv, bk, bv, Kh, Vt, nullptr,
      total_src, 1024, H_DIM, 4);

  // 3: MFMA flash attention -> Ob (bf16 [M,512])
  attn_v4<<<dim3(NBATCH, N_HEADS, 16), blk256, 0, stream>>>(
      Qh, Kh, Vt, d_lens, s_lens, Ob, total_dst, total_src);

  // 4: merge projection -> Mb (bf16, mode 2)
  gemm128<<<dim3(mt_d, 4), blk256, 0, stream>>>(
      Ob, Ob, Wmb, bm, nullptr, Mb, nullptr, nullptr,
      total_dst, H_DIM, H_DIM, 2);

  // 5: FFN1 concat -> X1 (fp32, mode 0 + fused BN1 stats)
  gemm128<<<dim3(mt_d, 4), blk256, 0, stream>>>(
      dst_bf, Mb, W1b, b1, nullptr, X1, nullptr, st1,
      total_dst, H_DIM, 1024, 0);

  // 6: BN1 + ReLU -> X1bf (bf16)
  bn_apply<<<dim3(512), blk256, 0, stream>>>(X1, st1, g1, be1, nullptr, X1bf,
                                             total_dst, 1.f / (float)total_dst, 1, 1);

  // 7: FFN2 -> X2 (fp32, mode 0 + fused BN2 stats)
  gemm128<<<dim3(mt_d, 4), blk256, 0, stream>>>(
      X1bf, X1bf, W2b, b2, nullptr, X2, nullptr, st2,
      total_dst, H_DIM, H_DIM, 0);

  // 8: BN2 + residual -> d_out (fp32)
  bn_apply<<<dim3(512), blk256, 0, stream>>>(X2, st2, g2, be2, dst_h, d_out,
                                             total_dst, 1.f / (float)total_dst, 0, 0);
}

// Round 6
// 301.233 us; speedup vs baseline: 23.3689x; 1.0193x over previous
//
#include <hip/hip_runtime.h>
#include <hip/hip_bf16.h>

#define H_DIM 512
#define N_HEADS 8
#define HEAD_DIM 64
#define NBATCH 16

typedef __attribute__((ext_vector_type(8))) short short8;   // 8 bf16 (4 VGPRs)
typedef __attribute__((ext_vector_type(4))) float floatx4;  // MFMA acc

typedef unsigned short us16;

__device__ inline unsigned short f2bf(float f) {
  unsigned int u = __float_as_uint(f);
  unsigned int r = (u + 0x7fffu + ((u >> 16) & 1u)) >> 16;  // RNE
  return (unsigned short)r;
}

// async global->LDS, 16B per lane; lds dest = wave-uniform base + lane*16
__device__ inline void gld16(const us16* g, us16* l) {
  __builtin_amdgcn_global_load_lds(
      (const __attribute__((address_space(1))) void*)g,
      (__attribute__((address_space(3))) void*)l, 16, 0, 0);
}

// ---------------------------------------------------------------------------
// One cast kernel for all fp32->bf16 conversions + BN-stat zeroing.
// ---------------------------------------------------------------------------
__global__ __launch_bounds__(256) void cast_all(
    const float* __restrict__ src_h, const float* __restrict__ dst_h,
    const float* __restrict__ w0, const float* __restrict__ w1,
    const float* __restrict__ w2, const float* __restrict__ w3,
    const float* __restrict__ w4, const float* __restrict__ w5,
    us16* __restrict__ src_bf, us16* __restrict__ dst_bf,
    us16* __restrict__ wbf, float* __restrict__ st,
    int n_src, int n_dst) {
  if (blockIdx.x == 0) {  // zero 2048 BN-stat floats
    float4 z = make_float4(0.f, 0.f, 0.f, 0.f);
    ((float4*)st)[threadIdx.x] = z;
    ((float4*)st)[threadIdx.x + 256] = z;
  }
  const float* srcs[8] = {src_h, dst_h, w0, w1, w2, w3, w4, w5};
  us16* dsts[8];
  int ns[8];
  dsts[0] = src_bf; ns[0] = n_src;
  dsts[1] = dst_bf; ns[1] = n_dst;
  const int wns[6] = {262144, 262144, 262144, 262144, 524288, 262144};
  const int woffs[6] = {0, 262144, 524288, 786432, 1048576, 1572864};
  for (int i = 0; i < 6; ++i) { dsts[2 + i] = wbf + woffs[i]; ns[2 + i] = wns[i]; }
  for (int rg = 0; rg < 8; ++rg) {
    const float* sp = srcs[rg];
    us16* dp = dsts[rg];
    int n = ns[rg];
    for (int i = ((int)blockIdx.x * 256 + (int)threadIdx.x) * 4; i < n;
         i += (int)gridDim.x * 256 * 4) {
      float4 v = *(const float4*)(sp + i);
      ushort4 o;
      o.x = f2bf(v.x); o.y = f2bf(v.y); o.z = f2bf(v.z); o.w = f2bf(v.w);
      *(ushort4*)(dp + i) = o;
    }
  }
}

// ---------------------------------------------------------------------------
// 64x64 MFMA GEMM body (NT): 256 thr / 4 waves (2x2), BK=32,
// global_load_lds(16B) into XOR-swizzled LDS. A row stride fixed 512;
// k0>=512 reads A2 (concat). Exact tiling: M%64==0, N%64==0, K%32==0.
// modes:
//  0: fp32 out [M,N] + fused BN stats (sum/sumsq -> stats[c]/stats[512+c])
//  1: bf16 Q head planes  C0[((c&7)*M + r)*64 + (c>>3)]
//  2: bf16 row-major [M,N]
//  4: KV fused (N=1024): c<512 -> K planes in C0; c>=512 -> Vt planes in C1
//     Vt layout: C1[((cv&7)*64 + (cv>>3))*M + r]
// ---------------------------------------------------------------------------
__device__ inline void gemm64_body(
    const us16* __restrict__ A1, const us16* __restrict__ A2,
    const us16* __restrict__ W,
    const float* __restrict__ bias0, const float* __restrict__ bias1,
    void* __restrict__ C0, void* __restrict__ C1,
    float* __restrict__ stats,
    int M, int N, int K, int mode, int bx, int by) {
  __shared__ __align__(16) us16 As[64 * 32];
  __shared__ __align__(16) us16 Bs[64 * 32];
  const int t = threadIdx.x;
  const int w = t >> 6, lane = t & 63;
  const int lane15 = lane & 15, quad = lane >> 4;
  const int wm = w >> 1, wn = w & 1;
  const int bm = bx * 64, bn = by * 64;
  const int srow = t >> 2;          // staging row 0..63
  const int sl = t & 3;             // k-slot
  const int kg = sl ^ ((srow >> 1) & 3);
  const int sw = (lane15 >> 1) & 3;

  floatx4 acc[2][2];
#pragma unroll
  for (int mt = 0; mt < 2; ++mt)
#pragma unroll
    for (int nt = 0; nt < 2; ++nt) acc[mt][nt] = (floatx4){0.f, 0.f, 0.f, 0.f};

  for (int k0 = 0; k0 < K; k0 += 32) {
    const us16* Ab = (k0 < 512) ? A1 : A2;
    const int ka = k0 & 511;
    gld16(Ab + (size_t)(bm + srow) * 512 + ka + kg * 8, As + w * 512);
    gld16(W + (size_t)(bn + srow) * K + k0 + kg * 8, Bs + w * 512);
    __syncthreads();
    short8 af[2], bfr[2];
#pragma unroll
    for (int mt = 0; mt < 2; ++mt) {
      int row = wm * 32 + mt * 16 + lane15;
      af[mt] = *(const short8*)(As + row * 32 + ((quad ^ sw) * 8));
    }
#pragma unroll
    for (int nt = 0; nt < 2; ++nt) {
      int row = wn * 32 + nt * 16 + lane15;
      bfr[nt] = *(const short8*)(Bs + row * 32 + ((quad ^ sw) * 8));
    }
#pragma unroll
    for (int mt = 0; mt < 2; ++mt)
#pragma unroll
      for (int nt = 0; nt < 2; ++nt)
        acc[mt][nt] = __builtin_amdgcn_mfma_f32_16x16x32_bf16(
            af[mt], bfr[nt], acc[mt][nt], 0, 0, 0);
    __syncthreads();
  }

  if (mode == 0) {
#pragma unroll
    for (int nt = 0; nt < 2; ++nt) {
      int col = bn + wn * 32 + nt * 16 + lane15;
      float bv = bias0[col];
      float s = 0.f, qq = 0.f;
#pragma unroll
      for (int mt = 0; mt < 2; ++mt) {
        int row0 = bm + wm * 32 + mt * 16 + quad * 4;
#pragma unroll
        for (int r = 0; r < 4; ++r) {
          float val = acc[mt][nt][r] + bv;
          ((float*)C0)[(size_t)(row0 + r) * N + col] = val;
          s += val; qq = fmaf(val, val, qq);
        }
      }
      s += __shfl_xor(s, 16); s += __shfl_xor(s, 32);
      qq += __shfl_xor(qq, 16); qq += __shfl_xor(qq, 32);
      if (quad == 0) {
        atomicAdd(&stats[col], s);
        atomicAdd(&stats[512 + col], qq);
      }
    }
  } else if (mode == 1) {
#pragma unroll
    for (int nt = 0; nt < 2; ++nt) {
      int col = bn + wn * 32 + nt * 16 + lane15;
      float bv = bias0[col];
      int hh = col & 7, dd = col >> 3;
#pragma unroll
      for (int mt = 0; mt < 2; ++mt) {
        int row0 = bm + wm * 32 + mt * 16 + quad * 4;
#pragma unroll
        for (int r = 0; r < 4; ++r)
          ((us16*)C0)[((size_t)hh * M + row0 + r) * 64 + dd] = f2bf(acc[mt][nt][r] + bv);
      }
    }
  } else if (mode == 2) {
#pragma unroll
    for (int nt = 0; nt < 2; ++nt) {
      int col = bn + wn * 32 + nt * 16 + lane15;
      float bv = bias0[col];
#pragma unroll
      for (int mt = 0; mt < 2; ++mt) {
        int row0 = bm + wm * 32 + mt * 16 + quad * 4;
#pragma unroll
        for (int r = 0; r < 4; ++r)
          ((us16*)C0)[(size_t)(row0 + r) * N + col] = f2bf(acc[mt][nt][r] + bv);
      }
    }
  } else {  // mode 4: KV fused
#pragma unroll
    for (int nt = 0; nt < 2; ++nt) {
      int col = bn + wn * 32 + nt * 16 + lane15;
      if (col < 512) {
        float bv = bias0[col];
        int hh = col & 7, dd = col >> 3;
#pragma unroll
        for (int mt = 0; mt < 2; ++mt) {
          int row0 = bm + wm * 32 + mt * 16 + quad * 4;
#pragma unroll
          for (int r = 0; r < 4; ++r)
            ((us16*)C0)[((size_t)hh * M + row0 + r) * 64 + dd] = f2bf(acc[mt][nt][r] + bv);
        }
      } else {
        int cv = col - 512;
        float bv = bias1[cv];
        int plane = (cv & 7) * 64 + (cv >> 3);
#pragma unroll
        for (int mt = 0; mt < 2; ++mt) {
          int row0 = bm + wm * 32 + mt * 16 + quad * 4;
          ushort4 pk;
          pk.x = f2bf(acc[mt][nt][0] + bv);
          pk.y = f2bf(acc[mt][nt][1] + bv);
          pk.z = f2bf(acc[mt][nt][2] + bv);
          pk.w = f2bf(acc[mt][nt][3] + bv);
          *(ushort4*)((us16*)C1 + (size_t)plane * M + row0) = pk;
        }
      }
    }
  }
}

__global__ __launch_bounds__(256) void gemm64(
    const us16* __restrict__ A1, const us16* __restrict__ A2,
    const us16* __restrict__ W,
    const float* __restrict__ bias0, const float* __restrict__ bias1,
    void* __restrict__ C0, void* __restrict__ C1,
    float* __restrict__ stats, int M, int N, int K, int mode) {
  gemm64_body(A1, A2, W, bias0, bias1, C0, C1, stats, M, N, K, mode,
              blockIdx.x, blockIdx.y);
}

// Q projection and fused K+V projection in one dispatch.
// grid (113, 24): y<8 -> Q (x<94), y>=8 -> KV.
__global__ __launch_bounds__(256) void gemm_qkv(
    const us16* __restrict__ dst_bf, const us16* __restrict__ src_bf,
    const us16* __restrict__ Wqb, const us16* __restrict__ Wkv,
    const float* __restrict__ bq, const float* __restrict__ bk,
    const float* __restrict__ bv,
    us16* __restrict__ Qh, us16* __restrict__ Kh, us16* __restrict__ Vt,
    int Md, int Ms) {
  if (blockIdx.y < 8) {
    if ((int)blockIdx.x >= Md / 64) return;
    gemm64_body(dst_bf, dst_bf, Wqb, bq, nullptr, Qh, nullptr, nullptr,
                Md, 512, 512, 1, blockIdx.x, blockIdx.y);
  } else {
    gemm64_body(src_bf, src_bf, Wkv, bk, bv, Kh, Vt, nullptr,
                Ms, 1024, 512, 4, blockIdx.x, blockIdx.y - 8);
  }
}

// ---------------------------------------------------------------------------
// Barrier-free MFMA flash attention: one wave per 16-row dst tile.
// Q/K fragments loaded global->VGPR directly (MFMA A/B layouts);
// V from transposed planes Vt[h][d][src]. Per-wave LDS only for the P
// C-layout -> A-layout transpose. No __syncthreads anywhere.
// Grid (batch, head, tile16). Block = 64 threads (1 wave).
// ---------------------------------------------------------------------------
__global__ __launch_bounds__(64) void attn_v5(
    const us16* __restrict__ Qh, const us16* __restrict__ Kh,
    const us16* __restrict__ Vt, const int* __restrict__ dlens,
    const int* __restrict__ slens, us16* __restrict__ O,
    int Md, int Ms) {
  const int b = blockIdx.x, h = blockIdx.y, tile = blockIdx.z;
  int doff = 0, soff = 0;
  for (int i = 0; i < NBATCH; ++i)
    if (i < b) { doff += dlens[i]; soff += slens[i]; }
  const int dlen = dlens[b], slen = slens[b];
  if (tile * 16 >= dlen) return;  // dlen is a multiple of 16
  const int i0 = tile * 16;

  __shared__ __align__(16) us16 Pw[16 * 72];  // per-wave P transpose buffer

  const int lane = threadIdx.x;
  const int lane15 = lane & 15, quad = lane >> 4;

  const us16* Qp = Qh + ((size_t)h * Md + doff + i0) * 64;
  const us16* Kp = Kh + ((size_t)h * Ms + soff) * 64;
  const us16* Vtp = Vt + ((size_t)h * 64) * Ms + soff;

  // Q fragments (A-layout): row=lane15, k = kh*32 + quad*8
  short8 af0 = *(const short8*)(Qp + (size_t)lane15 * 64 + quad * 8);
  short8 af1 = *(const short8*)(Qp + (size_t)lane15 * 64 + 32 + quad * 8);

  floatx4 oa[4];
#pragma unroll
  for (int nt = 0; nt < 4; ++nt) oa[nt] = (floatx4){0.f, 0.f, 0.f, 0.f};
  float m_r[4] = {-3.0e38f, -3.0e38f, -3.0e38f, -3.0e38f};
  float l_r[4] = {0.f, 0.f, 0.f, 0.f};

  for (int j0 = 0; j0 < slen; j0 += 64) {
    // ---- scores: 4 j-tiles of 16 cols, K fragments direct from global ----
    floatx4 s[4];
#pragma unroll
    for (int jt = 0; jt < 4; ++jt) {
      int j = j0 + jt * 16 + lane15;
      int jc = (j < slen) ? j : (slen - 1);
      const us16* kr = Kp + (size_t)jc * 64 + quad * 8;
      short8 b0 = *(const short8*)(kr);
      short8 b1 = *(const short8*)(kr + 32);
      floatx4 a = (floatx4){0.f, 0.f, 0.f, 0.f};
      a = __builtin_amdgcn_mfma_f32_16x16x32_bf16(af0, b0, a, 0, 0, 0);
      a = __builtin_amdgcn_mfma_f32_16x16x32_bf16(af1, b1, a, 0, 0, 0);
      s[jt] = a;
    }
    // ---- per-row (reg) online softmax, 16 lanes per row ----
    float mx[4] = {-3.0e38f, -3.0e38f, -3.0e38f, -3.0e38f};
#pragma unroll
    for (int jt = 0; jt < 4; ++jt) {
      bool valid = (j0 + jt * 16 + lane15) < slen;
#pragma unroll
      for (int r = 0; r < 4; ++r) {
        float v = valid ? s[jt][r] * 0.125f : -3.0e38f;
        s[jt][r] = v;
        mx[r] = fmaxf(mx[r], v);
      }
    }
#pragma unroll
    for (int r = 0; r < 4; ++r) {
      mx[r] = fmaxf(mx[r], __shfl_xor(mx[r], 1));
      mx[r] = fmaxf(mx[r], __shfl_xor(mx[r], 2));
      mx[r] = fmaxf(mx[r], __shfl_xor(mx[r], 4));
      mx[r] = fmaxf(mx[r], __shfl_xor(mx[r], 8));
    }
    float al[4], sum[4];
#pragma unroll
    for (int r = 0; r < 4; ++r) {
      float mn = fmaxf(m_r[r], mx[r]);
      al[r] = __expf(m_r[r] - mn);
      m_r[r] = mn;
      sum[r] = 0.f;
    }
#pragma unroll
    for (int jt = 0; jt < 4; ++jt)
#pragma unroll
      for (int r = 0; r < 4; ++r) {
        float e = __expf(s[jt][r] - m_r[r]);  // invalid cols -> exp(-inf)=0
        sum[r] += e;
        Pw[(quad * 4 + r) * 72 + jt * 16 + lane15] = f2bf(e);
      }
#pragma unroll
    for (int r = 0; r < 4; ++r) {
      sum[r] += __shfl_xor(sum[r], 1);
      sum[r] += __shfl_xor(sum[r], 2);
      sum[r] += __shfl_xor(sum[r], 4);
      sum[r] += __shfl_xor(sum[r], 8);
      l_r[r] = l_r[r] * al[r] + sum[r];
    }
    // ---- rescale O accumulators ----
#pragma unroll
    for (int nt = 0; nt < 4; ++nt)
#pragma unroll
      for (int r = 0; r < 4; ++r) oa[nt][r] *= al[r];
    // ---- P back as A-operand (wave-internal LDS round trip) ----
    short8 pa0 = *(const short8*)(&Pw[lane15 * 72 + quad * 8]);
    short8 pa1 = *(const short8*)(&Pw[lane15 * 72 + 32 + quad * 8]);
    // ---- PV: V^T fragments direct from global ----
#pragma unroll
    for (int nt = 0; nt < 4; ++nt) {
      const us16* vr = Vtp + (size_t)(nt * 16 + lane15) * Ms + j0 + quad * 8;
      short8 v0 = *(const short8*)(vr);
      short8 v1 = *(const short8*)(vr + 32);
      oa[nt] = __builtin_amdgcn_mfma_f32_16x16x32_bf16(pa0, v0, oa[nt], 0, 0, 0);
      oa[nt] = __builtin_amdgcn_mfma_f32_16x16x32_bf16(pa1, v1, oa[nt], 0, 0, 0);
    }
  }

  float linv[4];
#pragma unroll
  for (int r = 0; r < 4; ++r) linv[r] = 1.f / l_r[r];
#pragma unroll
  for (int r = 0; r < 4; ++r) {
    int i = quad * 4 + r;
    us16* orow = O + (size_t)(doff + i0 + i) * H_DIM + h;
#pragma unroll
    for (int nt = 0; nt < 4; ++nt) {
      int d = nt * 16 + lane15;
      orow[d * 8] = f2bf(oa[nt][r] * linv[r]);
    }
  }
}

// ---------------------------------------------------------------------------
// BN apply: optional ReLU / residual; out_bf selects bf16 vs fp32 output.
// ---------------------------------------------------------------------------
__global__ __launch_bounds__(256) void bn_apply(
    const float* __restrict__ X, const float* __restrict__ stats,
    const float* __restrict__ g, const float* __restrict__ be,
    const float* __restrict__ resid, void* __restrict__ Y,
    int M, float invM, int relu, int out_bf) {
  const size_t total = (size_t)M * H_DIM;
  for (size_t i = (size_t)blockIdx.x * 256 + threadIdx.x; i < total;
       i += (size_t)gridDim.x * 256) {
    int c = (int)(i & (H_DIM - 1));
    float mean = stats[c] * invM;
    float var = fmaf(-mean, mean, stats[H_DIM + c] * invM);
    float x = X[i];
    float y = (x - mean) * rsqrtf(var + 1e-5f) * g[c] + be[c];
    if (relu) y = fmaxf(y, 0.f);
    if (resid) y += resid[i];
    if (out_bf) ((us16*)Y)[i] = f2bf(y);
    else ((float*)Y)[i] = y;
  }
}

// ---------------------------------------------------------------------------
extern "C" void kernel_launch(void* const* d_in, const int* in_sizes, int n_in,
                              void* d_out, int out_size, void* d_ws, size_t ws_size,
                              hipStream_t stream) {
  const float* src_h = (const float*)d_in[0];
  const float* dst_h = (const float*)d_in[1];
  const int* s_lens  = (const int*)d_in[2];
  const int* d_lens  = (const int*)d_in[3];
  const float* Wq = (const float*)d_in[4];  const float* bq = (const float*)d_in[5];
  const float* Wk = (const float*)d_in[6];  const float* bk = (const float*)d_in[7];
  const float* Wv = (const float*)d_in[8];  const float* bv = (const float*)d_in[9];
  const float* Wm = (const float*)d_in[10]; const float* bm = (const float*)d_in[11];
  const float* W1 = (const float*)d_in[12]; const float* b1 = (const float*)d_in[13];
  const float* g1 = (const float*)d_in[14]; const float* be1 = (const float*)d_in[15];
  const float* W2 = (const float*)d_in[16]; const float* b2 = (const float*)d_in[17];
  const float* g2 = (const float*)d_in[18]; const float* be2 = (const float*)d_in[19];

  const int total_src = in_sizes[0] / H_DIM;  // 7232 = 113*64
  const int total_dst = in_sizes[1] / H_DIM;  // 6016 = 94*64

  // ---- workspace layout (byte offsets); peak ~50.5 MB ----
  char* ws = (char*)d_ws;
  us16* src_bf = (us16*)(ws + 0);                    //  7,405,568
  us16* dst_bf = (us16*)(ws + 7405568);              //  6,160,384
  us16* wbf    = (us16*)(ws + 13565952);             //  3,670,016
  us16* Qh     = (us16*)(ws + 17235968);             //  6,160,384
  us16* Kh     = (us16*)(ws + 23396352);             //  7,405,568
  us16* Vt     = (us16*)(ws + 30801920);             //  7,405,568
  us16* Ob     = (us16*)(ws + 38207488);             //  6,160,384
  us16* Mb     = (us16*)(ws + 44367872);             //  6,160,384
  float* st    = (float*)(ws + 50528256);            //  8,192
  float* X1    = (float*)(ws + 17235968);            // aliases Qh+Kh (dead)
  float* X2    = (float*)(ws + 30801920);            // aliases Vt+Ob (dead)
  us16* X1bf   = Mb;                                  // aliases Mb (dead after FFN1)
  float* st1 = st, *st2 = st + 1024;

  us16* Wqb = wbf;
  us16* Wkv = wbf + 262144;   // Wk then Wv, contiguous (1024 rows x 512)
  us16* Wmb = wbf + 786432;
  us16* W1b = wbf + 1048576;
  us16* W2b = wbf + 1572864;

  const int mbd = total_dst / 64;  // 94
  const int mbs = total_src / 64;  // 113
  const dim3 blk256(256), blk64(64);

  // 1: all casts + BN-stat zeroing (one dispatch)
  cast_all<<<dim3(2048), blk256, 0, stream>>>(
      src_h, dst_h, Wq, Wk, Wv, Wm, W1, W2,
      src_bf, dst_bf, wbf, st, total_src * H_DIM, total_dst * H_DIM);

  // 2: Q + fused K/V projections (one dispatch)
  gemm_qkv<<<dim3(mbs, 24), blk256, 0, stream>>>(
      dst_bf, src_bf, Wqb, Wkv, bq, bk, bv, Qh, Kh, Vt, total_dst, total_src);

  // 3: barrier-free MFMA flash attention -> Ob (bf16 [M,512])
  attn_v5<<<dim3(NBATCH, N_HEADS, 31), blk64, 0, stream>>>(
      Qh, Kh, Vt, d_lens, s_lens, Ob, total_dst, total_src);

  // 4: merge projection -> Mb (bf16)
  gemm64<<<dim3(mbd, 8), blk256, 0, stream>>>(
      Ob, Ob, Wmb, bm, nullptr, Mb, nullptr, nullptr, total_dst, 512, 512, 2);

  // 5: FFN1 concat -> X1 (fp32) + fused BN1 stats
  gemm64<<<dim3(mbd, 8), blk256, 0, stream>>>(
      dst_bf, Mb, W1b, b1, nullptr, X1, nullptr, st1, total_dst, 512, 1024, 0);

  // 6: BN1 + ReLU -> X1bf (bf16)
  bn_apply<<<dim3(512), blk256, 0, stream>>>(X1, st1, g1, be1, nullptr, X1bf,
                                             total_dst, 1.f / (float)total_dst, 1, 1);

  // 7: FFN2 -> X2 (fp32) + fused BN2 stats
  gemm64<<<dim3(mbd, 8), blk256, 0, stream>>>(
      X1bf, X1bf, W2b, b2, nullptr, X2, nullptr, st2, total_dst, 512, 512, 0);

  // 8: BN2 + residual -> d_out (fp32)
  bn_apply<<<dim3(512), blk256, 0, stream>>>(X2, st2, g2, be2, dst_h, d_out,
                                             total_dst, 1.f / (float)total_dst, 0, 0);
}

// Round 8
// 268.471 us; speedup vs baseline: 26.2207x; 1.1220x over previous
//
#include <hip/hip_runtime.h>
#include <hip/hip_bf16.h>

#define H_DIM 512
#define N_HEADS 8
#define HEAD_DIM 64
#define NBATCH 16

typedef __attribute__((ext_vector_type(8))) short short8;   // 8 bf16 (4 VGPRs)
typedef __attribute__((ext_vector_type(4))) float floatx4;  // MFMA acc

typedef unsigned short us16;

// 3-bit row swizzle for XOR'd LDS slots (2-way banks on b128 reads)
#define SW3(r) ((((r) >> 1) & 3) | (((r) & 1) << 2))

__device__ inline unsigned short f2bf(float f) {
  unsigned int u = __float_as_uint(f);
  unsigned int r = (u + 0x7fffu + ((u >> 16) & 1u)) >> 16;  // RNE
  return (unsigned short)r;
}

// async global->LDS, 16B/lane; lds dest = wave-uniform base + lane*16
__device__ inline void gld16(const us16* g, us16* l) {
  __builtin_amdgcn_global_load_lds(
      (const __attribute__((address_space(1))) void*)g,
      (__attribute__((address_space(3))) void*)l, 16, 0, 0);
}

// ---------------------------------------------------------------------------
// All fp32->bf16 casts + BN-stat zeroing. Region 5 is W1a (strided rows).
// ---------------------------------------------------------------------------
__global__ __launch_bounds__(256) void cast_all(
    const float* __restrict__ src_h, const float* __restrict__ dst_h,
    const float* __restrict__ Wq, const float* __restrict__ Wk,
    const float* __restrict__ Wv, const float* __restrict__ W1,
    const float* __restrict__ W2,
    us16* __restrict__ src_bf, us16* __restrict__ dst_bf,
    us16* __restrict__ Wqb, us16* __restrict__ Wkv, us16* __restrict__ Wf,
    us16* __restrict__ W2b, float* __restrict__ st,
    int n_src, int n_dst) {
  if (blockIdx.x == 0) {  // zero 2048 BN-stat floats
    float4 z = make_float4(0.f, 0.f, 0.f, 0.f);
    ((float4*)st)[threadIdx.x] = z;
    ((float4*)st)[threadIdx.x + 256] = z;
  }
  const float* srcs[7] = {src_h, dst_h, Wq, Wk, Wv, W1, W2};
  us16* dsts[7] = {src_bf, dst_bf, Wqb, Wkv, Wkv + 262144, Wf, W2b};
  int ns[7] = {n_src, n_dst, 262144, 262144, 262144, 262144, 262144};
  for (int rg = 0; rg < 7; ++rg) {
    const float* sp = srcs[rg];
    us16* dp = dsts[rg];
    const bool strided = (rg == 5);  // W1a: row n cols 0:512 of stride-1024 rows
    for (int i = ((int)blockIdx.x * 256 + (int)threadIdx.x) * 4; i < ns[rg];
         i += (int)gridDim.x * 256 * 4) {
      int j = strided ? ((i >> 9) * 1024 + (i & 511)) : i;
      float4 v = *(const float4*)(sp + j);
      ushort4 o;
      o.x = f2bf(v.x); o.y = f2bf(v.y); o.z = f2bf(v.z); o.w = f2bf(v.w);
      *(ushort4*)(dp + j) = o;
    }
  }
}

// ---------------------------------------------------------------------------
// Weight composite: Wc[n][k] = sum_j W1[n][512+j] * Wm[j][k]  (NN GEMM),
// stored bf16 into Wf[n*1024 + 512 + k]. Grid (8,8), 256 thr.
// ---------------------------------------------------------------------------
__global__ __launch_bounds__(256) void wprep(
    const float* __restrict__ W1, const float* __restrict__ Wm,
    us16* __restrict__ Wf) {
  __shared__ __align__(16) us16 As[64 * 48];  // [n][j], pitch 48
  __shared__ __align__(16) us16 Bs[64 * 48];  // [k][j], pitch 48
  const int t = threadIdx.x, w = t >> 6, lane = t & 63;
  const int lane15 = lane & 15, quad = lane >> 4;
  const int wm = w >> 1, wn = w & 1;
  const int bn_ = blockIdx.x * 64;  // n tile
  const int bk = blockIdx.y * 64;   // k tile
  floatx4 acc[2][2];
#pragma unroll
  for (int a = 0; a < 2; ++a)
#pragma unroll
    for (int c = 0; c < 2; ++c) acc[a][c] = (floatx4){0.f, 0.f, 0.f, 0.f};

  for (int j0 = 0; j0 < 512; j0 += 32) {
    {  // A tile: 64 n x 32 j
      int n = t >> 2, jj0 = (t & 3) * 8;
      const float* rp = W1 + (size_t)(bn_ + n) * 1024 + 512 + j0 + jj0;
      float4 va = *(const float4*)(rp);
      float4 vb = *(const float4*)(rp + 4);
      ushort4 pa, pb;
      pa.x = f2bf(va.x); pa.y = f2bf(va.y); pa.z = f2bf(va.z); pa.w = f2bf(va.w);
      pb.x = f2bf(vb.x); pb.y = f2bf(vb.y); pb.z = f2bf(vb.z); pb.w = f2bf(vb.w);
      *(ushort4*)(As + n * 48 + jj0) = pa;
      *(ushort4*)(As + n * 48 + jj0 + 4) = pb;
    }
    {  // B tile transposed: Bs[k][j] from Wm[j][k]
      int jj = t >> 3, kc0 = (t & 7) * 8;
      const float* rp = Wm + (size_t)(j0 + jj) * 512 + bk + kc0;
      float4 va = *(const float4*)(rp);
      float4 vb = *(const float4*)(rp + 4);
      float vv[8] = {va.x, va.y, va.z, va.w, vb.x, vb.y, vb.z, vb.w};
#pragma unroll
      for (int e = 0; e < 8; ++e) Bs[(kc0 + e) * 48 + jj] = f2bf(vv[e]);
    }
    __syncthreads();
    short8 a_[2], b_[2];
#pragma unroll
    for (int mt = 0; mt < 2; ++mt)
      a_[mt] = *(const short8*)(As + (wm * 32 + mt * 16 + lane15) * 48 + quad * 8);
#pragma unroll
    for (int nt = 0; nt < 2; ++nt)
      b_[nt] = *(const short8*)(Bs + (wn * 32 + nt * 16 + lane15) * 48 + quad * 8);
#pragma unroll
    for (int mt = 0; mt < 2; ++mt)
#pragma unroll
      for (int nt = 0; nt < 2; ++nt)
        acc[mt][nt] = __builtin_amdgcn_mfma_f32_16x16x32_bf16(
            a_[mt], b_[nt], acc[mt][nt], 0, 0, 0);
    __syncthreads();
  }
#pragma unroll
  for (int mt = 0; mt < 2; ++mt) {
    int n0 = bn_ + wm * 32 + mt * 16 + quad * 4;
#pragma unroll
    for (int nt = 0; nt < 2; ++nt) {
      int k = bk + wn * 32 + nt * 16 + lane15;
#pragma unroll
      for (int r = 0; r < 4; ++r)
        Wf[(size_t)(n0 + r) * 1024 + 512 + k] = f2bf(acc[mt][nt][r]);
    }
  }
}

// b1p[n] = b1[n] + sum_j W1[n][512+j] * bm[j].  Grid 512 x 64thr.
__global__ __launch_bounds__(64) void b1prep(
    const float* __restrict__ W1, const float* __restrict__ b1,
    const float* __restrict__ bm, float* __restrict__ b1p) {
  const int n = blockIdx.x, lane = threadIdx.x;
  const float* rp = W1 + (size_t)n * 1024 + 512 + lane * 8;
  float4 a0 = *(const float4*)(rp);
  float4 a1 = *(const float4*)(rp + 4);
  float4 c0 = *(const float4*)(bm + lane * 8);
  float4 c1 = *(const float4*)(bm + lane * 8 + 4);
  float s = a0.x * c0.x + a0.y * c0.y + a0.z * c0.z + a0.w * c0.w +
            a1.x * c1.x + a1.y * c1.y + a1.z * c1.z + a1.w * c1.w;
#pragma unroll
  for (int o = 1; o < 64; o <<= 1) s += __shfl_xor(s, o);
  if (lane == 0) b1p[n] = b1[n] + s;
}

// ---------------------------------------------------------------------------
// 64x64 MFMA GEMM body (NT), BK=128: 256 thr / 4 waves (2x2),
// global_load_lds(16B) into SW3-XOR-swizzled LDS; 16 MFMA per wave per
// barrier-pair (m97 ratio). A row stride fixed 512; k0>=512 reads A2.
// Exact tiling: M%64==0, N%64==0, K%128==0. W row stride = K.
// modes: 0 fp32 out + fused BN stats; 1 bf16 Q/K head planes; 4 KV fused.
// ---------------------------------------------------------------------------
__device__ inline void gemm_body(
    const us16* __restrict__ A1, const us16* __restrict__ A2,
    const us16* __restrict__ W,
    const float* __restrict__ bias0, const float* __restrict__ bias1,
    void* __restrict__ C0, void* __restrict__ C1, float* __restrict__ stats,
    int M, int N, int K, int mode, int bx, int by) {
  __shared__ __align__(16) us16 As[64 * 128];
  __shared__ __align__(16) us16 Bs[64 * 128];
  const int t = threadIdx.x, w = t >> 6, lane = t & 63;
  const int lane15 = lane & 15, quad = lane >> 4;
  const int wm = w >> 1, wn = w & 1;
  const int bm = bx * 64, bn = by * 64;

  floatx4 acc[2][2];
#pragma unroll
  for (int a = 0; a < 2; ++a)
#pragma unroll
    for (int c = 0; c < 2; ++c) acc[a][c] = (floatx4){0.f, 0.f, 0.f, 0.f};

  const int srl = lane >> 4;    // staging row-sub
  const int sl = lane & 15;     // staging slot

  for (int k0 = 0; k0 < K; k0 += 128) {
    const us16* Ab = (k0 < 512) ? A1 : A2;
    const int ka = k0 & 511;
#pragma unroll
    for (int p = 0; p < 4; ++p) {
      int row = w * 16 + p * 4 + srl;
      int kg = sl ^ SW3(row);
      gld16(Ab + (size_t)(bm + row) * 512 + ka + kg * 8, As + (w * 16 + p * 4) * 128);
      gld16(W + (size_t)(bn + row) * K + k0 + kg * 8, Bs + (w * 16 + p * 4) * 128);
    }
    __syncthreads();
#pragma unroll
    for (int kk = 0; kk < 4; ++kk) {
      const int g = kk * 4 + quad;
      int r0 = wm * 32 + lane15;
      int r1 = r0 + 16;
      short8 a0 = *(const short8*)(As + r0 * 128 + (g ^ SW3(r0)) * 8);
      short8 a1 = *(const short8*)(As + r1 * 128 + (g ^ SW3(r1)) * 8);
      int c0 = wn * 32 + lane15;
      int c1 = c0 + 16;
      short8 b0 = *(const short8*)(Bs + c0 * 128 + (g ^ SW3(c0)) * 8);
      short8 b1 = *(const short8*)(Bs + c1 * 128 + (g ^ SW3(c1)) * 8);
      acc[0][0] = __builtin_amdgcn_mfma_f32_16x16x32_bf16(a0, b0, acc[0][0], 0, 0, 0);
      acc[0][1] = __builtin_amdgcn_mfma_f32_16x16x32_bf16(a0, b1, acc[0][1], 0, 0, 0);
      acc[1][0] = __builtin_amdgcn_mfma_f32_16x16x32_bf16(a1, b0, acc[1][0], 0, 0, 0);
      acc[1][1] = __builtin_amdgcn_mfma_f32_16x16x32_bf16(a1, b1, acc[1][1], 0, 0, 0);
    }
    __syncthreads();
  }

  if (mode == 0) {
#pragma unroll
    for (int nt = 0; nt < 2; ++nt) {
      int col = bn + wn * 32 + nt * 16 + lane15;
      float bv = bias0[col];
      float s = 0.f, qq = 0.f;
#pragma unroll
      for (int mt = 0; mt < 2; ++mt) {
        int row0 = bm + wm * 32 + mt * 16 + quad * 4;
#pragma unroll
        for (int r = 0; r < 4; ++r) {
          float val = acc[mt][nt][r] + bv;
          ((float*)C0)[(size_t)(row0 + r) * N + col] = val;
          s += val; qq = fmaf(val, val, qq);
        }
      }
      s += __shfl_xor(s, 16); s += __shfl_xor(s, 32);
      qq += __shfl_xor(qq, 16); qq += __shfl_xor(qq, 32);
      if (quad == 0) {
        atomicAdd(&stats[col], s);
        atomicAdd(&stats[512 + col], qq);
      }
    }
  } else if (mode == 1) {
#pragma unroll
    for (int nt = 0; nt < 2; ++nt) {
      int col = bn + wn * 32 + nt * 16 + lane15;
      float bv = bias0[col];
      int hh = col & 7, dd = col >> 3;
#pragma unroll
      for (int mt = 0; mt < 2; ++mt) {
        int row0 = bm + wm * 32 + mt * 16 + quad * 4;
#pragma unroll
        for (int r = 0; r < 4; ++r)
          ((us16*)C0)[((size_t)hh * M + row0 + r) * 64 + dd] = f2bf(acc[mt][nt][r] + bv);
      }
    }
  } else {  // mode 4: KV fused (N=1024)
#pragma unroll
    for (int nt = 0; nt < 2; ++nt) {
      int col = bn + wn * 32 + nt * 16 + lane15;
      if (col < 512) {
        float bv = bias0[col];
        int hh = col & 7, dd = col >> 3;
#pragma unroll
        for (int mt = 0; mt < 2; ++mt) {
          int row0 = bm + wm * 32 + mt * 16 + quad * 4;
#pragma unroll
          for (int r = 0; r < 4; ++r)
            ((us16*)C0)[((size_t)hh * M + row0 + r) * 64 + dd] = f2bf(acc[mt][nt][r] + bv);
        }
      } else {
        int cv = col - 512;
        float bv = bias1[cv];
        int plane = (cv & 7) * 64 + (cv >> 3);
#pragma unroll
        for (int mt = 0; mt < 2; ++mt) {
          int row0 = bm + wm * 32 + mt * 16 + quad * 4;
          ushort4 pk;
          pk.x = f2bf(acc[mt][nt][0] + bv);
          pk.y = f2bf(acc[mt][nt][1] + bv);
          pk.z = f2bf(acc[mt][nt][2] + bv);
          pk.w = f2bf(acc[mt][nt][3] + bv);
          *(ushort4*)((us16*)C1 + (size_t)plane * M + row0) = pk;
        }
      }
    }
  }
}

__global__ __launch_bounds__(256) void gemm64(
    const us16* __restrict__ A1, const us16* __restrict__ A2,
    const us16* __restrict__ W,
    const float* __restrict__ bias0, const float* __restrict__ bias1,
    void* __restrict__ C0, void* __restrict__ C1,
    float* __restrict__ stats, int M, int N, int K, int mode) {
  gemm_body(A1, A2, W, bias0, bias1, C0, C1, stats, M, N, K, mode,
            blockIdx.x, blockIdx.y);
}

// Q projection + fused K/V projection, one dispatch. grid (113, 24).
__global__ __launch_bounds__(256) void gemm_qkv(
    const us16* __restrict__ dst_bf, const us16* __restrict__ src_bf,
    const us16* __restrict__ Wqb, const us16* __restrict__ Wkv,
    const float* __restrict__ bq, const float* __restrict__ bk,
    const float* __restrict__ bv,
    us16* __restrict__ Qh, us16* __restrict__ Kh, us16* __restrict__ Vt,
    int Md, int Ms) {
  if (blockIdx.y < 8) {
    if ((int)blockIdx.x >= Md / 64) return;
    gemm_body(dst_bf, dst_bf, Wqb, bq, nullptr, Qh, nullptr, nullptr,
              Md, 512, 512, 1, blockIdx.x, blockIdx.y);
  } else {
    gemm_body(src_bf, src_bf, Wkv, bk, bv, Kh, Vt, nullptr,
              Ms, 1024, 512, 4, blockIdx.x, blockIdx.y - 8);
  }
}

// ---------------------------------------------------------------------------
// attn_v6: 4 waves x 16 dst rows of one (b,h); K/Vt chunks (64x64 bf16)
// staged once per block via global_load_lds (SW3 swizzle); per-wave
// in-register online softmax (shfl over 16 lanes); 2 barriers per chunk.
// Grid (16, 8, 8), 256 thr.
// ---------------------------------------------------------------------------
__global__ __launch_bounds__(256) void attn_v6(
    const us16* __restrict__ Qh, const us16* __restrict__ Kh,
    const us16* __restrict__ Vt, const int* __restrict__ dlens,
    const int* __restrict__ slens, us16* __restrict__ O,
    int Md, int Ms) {
  const int b = blockIdx.x, h = blockIdx.y, tile = blockIdx.z;
  int doff = 0, soff = 0;
  for (int i = 0; i < NBATCH; ++i)
    if (i < b) { doff += dlens[i]; soff += slens[i]; }
  const int dlen = dlens[b], slen = slens[b];
  if (tile * 64 >= dlen) return;

  __shared__ __align__(16) us16 Ks[64 * 64];   // [j][k] swizzled
  __shared__ __align__(16) us16 Vts[64 * 64];  // [d][j] swizzled
  __shared__ __align__(16) us16 Pw[4][16 * 72];

  const int t = threadIdx.x, wv = t >> 6, lane = t & 63;
  const int lane15 = lane & 15, quad = lane >> 4;
  const int i0w = tile * 64 + wv * 16;         // this wave's dst rows
  const bool active = i0w < dlen;              // dlen % 16 == 0

  const us16* Qp = Qh + ((size_t)h * Md + doff + (active ? i0w : 0)) * 64;
  const us16* Kp = Kh + ((size_t)h * Ms + soff) * 64;
  const us16* Vtp = Vt + ((size_t)h * 64) * Ms + soff;

  // Q fragments (A-layout), direct global->VGPR
  short8 af0 = *(const short8*)(Qp + (size_t)lane15 * 64 + quad * 8);
  short8 af1 = *(const short8*)(Qp + (size_t)lane15 * 64 + 32 + quad * 8);

  floatx4 oa[4];
#pragma unroll
  for (int nt = 0; nt < 4; ++nt) oa[nt] = (floatx4){0.f, 0.f, 0.f, 0.f};
  float m_r[4] = {-3.0e38f, -3.0e38f, -3.0e38f, -3.0e38f};
  float l_r[4] = {0.f, 0.f, 0.f, 0.f};

  for (int j0 = 0; j0 < slen; j0 += 64) {
    // ---- stage K (64 j x 64 k) and Vt (64 d x 64 j), 2 issues each ----
#pragma unroll
    for (int p = 0; p < 2; ++p) {
      int row = wv * 16 + p * 8 + (lane >> 3);
      int sl = lane & 7;
      int kg = sl ^ SW3(row);
      gld16(Kp + (size_t)(j0 + row) * 64 + kg * 8, Ks + (wv * 16 + p * 8) * 64);
      gld16(Vtp + (size_t)row * Ms + j0 + kg * 8, Vts + (wv * 16 + p * 8) * 64);
    }
    __syncthreads();

    if (active) {
      // ---- scores (C-layout regs) ----
      floatx4 s[4];
#pragma unroll
      for (int jt = 0; jt < 4; ++jt) {
        int j = jt * 16 + lane15;
        short8 b0 = *(const short8*)(Ks + j * 64 + ((quad ^ SW3(j)) * 8));
        short8 b1 = *(const short8*)(Ks + j * 64 + (((4 + quad) ^ SW3(j)) * 8));
        floatx4 a = (floatx4){0.f, 0.f, 0.f, 0.f};
        a = __builtin_amdgcn_mfma_f32_16x16x32_bf16(af0, b0, a, 0, 0, 0);
        a = __builtin_amdgcn_mfma_f32_16x16x32_bf16(af1, b1, a, 0, 0, 0);
        s[jt] = a;
      }
      // ---- in-register online softmax (16 lanes per row) ----
      float mx[4] = {-3.0e38f, -3.0e38f, -3.0e38f, -3.0e38f};
#pragma unroll
      for (int jt = 0; jt < 4; ++jt) {
        bool valid = (j0 + jt * 16 + lane15) < slen;
#pragma unroll
        for (int r = 0; r < 4; ++r) {
          float v = valid ? s[jt][r] * 0.125f : -3.0e38f;
          s[jt][r] = v;
          mx[r] = fmaxf(mx[r], v);
        }
      }
#pragma unroll
      for (int r = 0; r < 4; ++r) {
        mx[r] = fmaxf(mx[r], __shfl_xor(mx[r], 1));
        mx[r] = fmaxf(mx[r], __shfl_xor(mx[r], 2));
        mx[r] = fmaxf(mx[r], __shfl_xor(mx[r], 4));
        mx[r] = fmaxf(mx[r], __shfl_xor(mx[r], 8));
      }
      float al[4], sum[4];
#pragma unroll
      for (int r = 0; r < 4; ++r) {
        float mn = fmaxf(m_r[r], mx[r]);
        al[r] = __expf(m_r[r] - mn);
        m_r[r] = mn;
        sum[r] = 0.f;
      }
#pragma unroll
      for (int jt = 0; jt < 4; ++jt)
#pragma unroll
        for (int r = 0; r < 4; ++r) {
          float e = __expf(s[jt][r] - m_r[r]);
          sum[r] += e;
          Pw[wv][(quad * 4 + r) * 72 + jt * 16 + lane15] = f2bf(e);
        }
#pragma unroll
      for (int r = 0; r < 4; ++r) {
        sum[r] += __shfl_xor(sum[r], 1);
        sum[r] += __shfl_xor(sum[r], 2);
        sum[r] += __shfl_xor(sum[r], 4);
        sum[r] += __shfl_xor(sum[r], 8);
        l_r[r] = l_r[r] * al[r] + sum[r];
      }
      // ---- rescale O, P C->A via wave-private LDS, PV ----
#pragma unroll
      for (int nt = 0; nt < 4; ++nt)
#pragma unroll
        for (int r = 0; r < 4; ++r) oa[nt][r] *= al[r];
      short8 pa0 = *(const short8*)(&Pw[wv][lane15 * 72 + quad * 8]);
      short8 pa1 = *(const short8*)(&Pw[wv][lane15 * 72 + 32 + quad * 8]);
#pragma unroll
      for (int nt = 0; nt < 4; ++nt) {
        int d = nt * 16 + lane15;
        short8 v0 = *(const short8*)(Vts + d * 64 + ((quad ^ SW3(d)) * 8));
        short8 v1 = *(const short8*)(Vts + d * 64 + (((4 + quad) ^ SW3(d)) * 8));
        oa[nt] = __builtin_amdgcn_mfma_f32_16x16x32_bf16(pa0, v0, oa[nt], 0, 0, 0);
        oa[nt] = __builtin_amdgcn_mfma_f32_16x16x32_bf16(pa1, v1, oa[nt], 0, 0, 0);
      }
    }
    __syncthreads();
  }

  if (active) {
    float linv[4];
#pragma unroll
    for (int r = 0; r < 4; ++r) linv[r] = 1.f / l_r[r];
#pragma unroll
    for (int r = 0; r < 4; ++r) {
      int i = quad * 4 + r;
      us16* orow = O + (size_t)(doff + i0w + i) * H_DIM + h;
#pragma unroll
      for (int nt = 0; nt < 4; ++nt) {
        int d = nt * 16 + lane15;
        orow[d * 8] = f2bf(oa[nt][r] * linv[r]);
      }
    }
  }
}

// ---------------------------------------------------------------------------
// BN apply: optional ReLU / residual; out_bf selects bf16 vs fp32 output.
// ---------------------------------------------------------------------------
__global__ __launch_bounds__(256) void bn_apply(
    const float* __restrict__ X, const float* __restrict__ stats,
    const float* __restrict__ g, const float* __restrict__ be,
    const float* __restrict__ resid, void* __restrict__ Y,
    int M, float invM, int relu, int out_bf) {
  const size_t total = (size_t)M * H_DIM;
  for (size_t i = (size_t)blockIdx.x * 256 + threadIdx.x; i < total;
       i += (size_t)gridDim.x * 256) {
    int c = (int)(i & (H_DIM - 1));
    float mean = stats[c] * invM;
    float var = fmaf(-mean, mean, stats[H_DIM + c] * invM);
    float x = X[i];
    float y = (x - mean) * rsqrtf(var + 1e-5f) * g[c] + be[c];
    if (relu) y = fmaxf(y, 0.f);
    if (resid) y += resid[i];
    if (out_bf) ((us16*)Y)[i] = f2bf(y);
    else ((float*)Y)[i] = y;
  }
}

// ---------------------------------------------------------------------------
extern "C" void kernel_launch(void* const* d_in, const int* in_sizes, int n_in,
                              void* d_out, int out_size, void* d_ws, size_t ws_size,
                              hipStream_t stream) {
  const float* src_h = (const float*)d_in[0];
  const float* dst_h = (const float*)d_in[1];
  const int* s_lens  = (const int*)d_in[2];
  const int* d_lens  = (const int*)d_in[3];
  const float* Wq = (const float*)d_in[4];  const float* bq = (const float*)d_in[5];
  const float* Wk = (const float*)d_in[6];  const float* bk = (const float*)d_in[7];
  const float* Wv = (const float*)d_in[8];  const float* bv = (const float*)d_in[9];
  const float* Wm = (const float*)d_in[10]; const float* bm = (const float*)d_in[11];
  const float* W1 = (const float*)d_in[12]; const float* b1 = (const float*)d_in[13];
  const float* g1 = (const float*)d_in[14]; const float* be1 = (const float*)d_in[15];
  const float* W2 = (const float*)d_in[16]; const float* b2 = (const float*)d_in[17];
  const float* g2 = (const float*)d_in[18]; const float* be2 = (const float*)d_in[19];

  const int total_src = in_sizes[0] / H_DIM;  // 7232 = 113*64
  const int total_dst = in_sizes[1] / H_DIM;  // 6016 = 94*64

  // ---- workspace layout (byte offsets); peak ~50.5 MB ----
  char* ws = (char*)d_ws;
  us16* src_bf = (us16*)(ws + 0);                    //  7,405,568
  us16* dst_bf = (us16*)(ws + 7405568);              //  6,160,384
  us16* wbf    = (us16*)(ws + 13565952);             //  3,145,728 used
  float* b1p   = (float*)(ws + 16711680);            //  2,048 (gap before Qh)
  us16* Qh     = (us16*)(ws + 17235968);             //  6,160,384
  us16* Kh     = (us16*)(ws + 23396352);             //  7,405,568
  us16* Vt     = (us16*)(ws + 30801920);             //  7,405,568
  us16* Ob     = (us16*)(ws + 38207488);             //  6,160,384
  us16* X1bf   = (us16*)(ws + 44367872);             //  6,160,384
  float* st    = (float*)(ws + 50528256);            //  8,192
  float* X1    = (float*)(ws + 17235968);            // aliases Qh+Kh (dead)
  float* X2    = (float*)(ws + 30801920);            // aliases Vt+Ob (dead)
  float* st1 = st, *st2 = st + 1024;

  us16* Wqb = wbf;                 // 262144 elems
  us16* Wkv = wbf + 262144;        // 524288 (Wk rows then Wv rows)
  us16* Wf  = wbf + 786432;        // 524288 ([W1a | Wc] rows of 1024)
  us16* W2b = wbf + 1310720;       // 262144

  const int mbd = total_dst / 64;  // 94
  const int mbs = total_src / 64;  // 113
  const dim3 blk256(256), blk64(64);

  // 1: casts (+BN-stat zero)
  cast_all<<<dim3(2048), blk256, 0, stream>>>(
      src_h, dst_h, Wq, Wk, Wv, W1, W2,
      src_bf, dst_bf, Wqb, Wkv, Wf, W2b, st,
      total_src * H_DIM, total_dst * H_DIM);

  // 2-3: weight composites (Wc = W1b@Wm -> Wf[:,512:], b1p = b1 + W1b@bm)
  wprep<<<dim3(8, 8), blk256, 0, stream>>>(W1, Wm, Wf);
  b1prep<<<dim3(512), blk64, 0, stream>>>(W1, b1, bm, b1p);

  // 4: Q + fused K/V projections
  gemm_qkv<<<dim3(mbs, 24), blk256, 0, stream>>>(
      dst_bf, src_bf, Wqb, Wkv, bq, bk, bv, Qh, Kh, Vt, total_dst, total_src);

  // 5: attention -> Ob (bf16 [M,512])
  attn_v6<<<dim3(NBATCH, N_HEADS, 8), blk256, 0, stream>>>(
      Qh, Kh, Vt, d_lens, s_lens, Ob, total_dst, total_src);

  // 6: FFN1 (merge folded in): [dst_bf | Ob] @ Wf^T + b1p -> X1 + BN1 stats
  gemm64<<<dim3(mbd, 8), blk256, 0, stream>>>(
      dst_bf, Ob, Wf, b1p, nullptr, X1, nullptr, st1, total_dst, 512, 1024, 0);

  // 7: BN1 + ReLU -> X1bf
  bn_apply<<<dim3(512), blk256, 0, stream>>>(X1, st1, g1, be1, nullptr, X1bf,
                                             total_dst, 1.f / (float)total_dst, 1, 1);

  // 8: FFN2 -> X2 + BN2 stats
  gemm64<<<dim3(mbd, 8), blk256, 0, stream>>>(
      X1bf, X1bf, W2b, b2, nullptr, X2, nullptr, st2, total_dst, 512, 512, 0);

  // 9: BN2 + residual -> d_out
  bn_apply<<<dim3(512), blk256, 0, stream>>>(X2, st2, g2, be2, dst_h, d_out,
                                             total_dst, 1.f / (float)total_dst, 0, 0);
}

// Round 9
// 261.476 us; speedup vs baseline: 26.9221x; 1.0268x over previous
//
#include <hip/hip_runtime.h>
#include <hip/hip_bf16.h>

#define H_DIM 512
#define N_HEADS 8
#define HEAD_DIM 64
#define NBATCH 16

typedef __attribute__((ext_vector_type(8))) short short8;   // 8 bf16 (4 VGPRs)
typedef __attribute__((ext_vector_type(4))) float floatx4;  // MFMA acc

typedef unsigned short us16;

// 3-bit row swizzle for XOR'd LDS slots (2-way banks on b128 reads)
#define SW3(r) ((((r) >> 1) & 3) | (((r) & 1) << 2))

__device__ inline unsigned short f2bf(float f) {
  unsigned int u = __float_as_uint(f);
  unsigned int r = (u + 0x7fffu + ((u >> 16) & 1u)) >> 16;  // RNE
  return (unsigned short)r;
}

// async global->LDS, 16B/lane; lds dest = wave-uniform base + lane*16
__device__ inline void gld16(const us16* g, us16* l) {
  __builtin_amdgcn_global_load_lds(
      (const __attribute__((address_space(1))) void*)g,
      (__attribute__((address_space(3))) void*)l, 16, 0, 0);
}

// ---------------------------------------------------------------------------
// All fp32->bf16 casts + BN-stat zeroing. Region 5 is W1a (strided rows).
// ---------------------------------------------------------------------------
__global__ __launch_bounds__(256) void cast_all(
    const float* __restrict__ src_h, const float* __restrict__ dst_h,
    const float* __restrict__ Wq, const float* __restrict__ Wk,
    const float* __restrict__ Wv, const float* __restrict__ W1,
    const float* __restrict__ W2,
    us16* __restrict__ src_bf, us16* __restrict__ dst_bf,
    us16* __restrict__ Wqb, us16* __restrict__ Wkv, us16* __restrict__ Wf,
    us16* __restrict__ W2b, float* __restrict__ st,
    int n_src, int n_dst) {
  if (blockIdx.x == 0) {  // zero 2048 BN-stat floats
    float4 z = make_float4(0.f, 0.f, 0.f, 0.f);
    ((float4*)st)[threadIdx.x] = z;
    ((float4*)st)[threadIdx.x + 256] = z;
  }
  const float* srcs[7] = {src_h, dst_h, Wq, Wk, Wv, W1, W2};
  us16* dsts[7] = {src_bf, dst_bf, Wqb, Wkv, Wkv + 262144, Wf, W2b};
  int ns[7] = {n_src, n_dst, 262144, 262144, 262144, 262144, 262144};
  for (int rg = 0; rg < 7; ++rg) {
    const float* sp = srcs[rg];
    us16* dp = dsts[rg];
    const bool strided = (rg == 5);  // W1a: row n cols 0:512 of stride-1024 rows
    for (int i = ((int)blockIdx.x * 256 + (int)threadIdx.x) * 4; i < ns[rg];
         i += (int)gridDim.x * 256 * 4) {
      int j = strided ? ((i >> 9) * 1024 + (i & 511)) : i;
      float4 v = *(const float4*)(sp + j);
      ushort4 o;
      o.x = f2bf(v.x); o.y = f2bf(v.y); o.z = f2bf(v.z); o.w = f2bf(v.w);
      *(ushort4*)(dp + j) = o;
    }
  }
}

// ---------------------------------------------------------------------------
// Weight composite: Wc[n][k] = sum_j W1[n][512+j] * Wm[j][k]  (NN GEMM),
// stored bf16 into Wf[n*1024 + 512 + k]. Grid (8,8), 256 thr.
// ---------------------------------------------------------------------------
__global__ __launch_bounds__(256) void wprep(
    const float* __restrict__ W1, const float* __restrict__ Wm,
    us16* __restrict__ Wf) {
  __shared__ __align__(16) us16 As[64 * 48];  // [n][j], pitch 48
  __shared__ __align__(16) us16 Bs[64 * 48];  // [k][j], pitch 48
  const int t = threadIdx.x, w = t >> 6, lane = t & 63;
  const int lane15 = lane & 15, quad = lane >> 4;
  const int wm = w >> 1, wn = w & 1;
  const int bn_ = blockIdx.x * 64;  // n tile
  const int bk = blockIdx.y * 64;   // k tile
  floatx4 acc[2][2];
#pragma unroll
  for (int a = 0; a < 2; ++a)
#pragma unroll
    for (int c = 0; c < 2; ++c) acc[a][c] = (floatx4){0.f, 0.f, 0.f, 0.f};

  for (int j0 = 0; j0 < 512; j0 += 32) {
    {  // A tile: 64 n x 32 j
      int n = t >> 2, jj0 = (t & 3) * 8;
      const float* rp = W1 + (size_t)(bn_ + n) * 1024 + 512 + j0 + jj0;
      float4 va = *(const float4*)(rp);
      float4 vb = *(const float4*)(rp + 4);
      ushort4 pa, pb;
      pa.x = f2bf(va.x); pa.y = f2bf(va.y); pa.z = f2bf(va.z); pa.w = f2bf(va.w);
      pb.x = f2bf(vb.x); pb.y = f2bf(vb.y); pb.z = f2bf(vb.z); pb.w = f2bf(vb.w);
      *(ushort4*)(As + n * 48 + jj0) = pa;
      *(ushort4*)(As + n * 48 + jj0 + 4) = pb;
    }
    {  // B tile transposed: Bs[k][j] from Wm[j][k]
      int jj = t >> 3, kc0 = (t & 7) * 8;
      const float* rp = Wm + (size_t)(j0 + jj) * 512 + bk + kc0;
      float4 va = *(const float4*)(rp);
      float4 vb = *(const float4*)(rp + 4);
      float vv[8] = {va.x, va.y, va.z, va.w, vb.x, vb.y, vb.z, vb.w};
#pragma unroll
      for (int e = 0; e < 8; ++e) Bs[(kc0 + e) * 48 + jj] = f2bf(vv[e]);
    }
    __syncthreads();
    short8 a_[2], b_[2];
#pragma unroll
    for (int mt = 0; mt < 2; ++mt)
      a_[mt] = *(const short8*)(As + (wm * 32 + mt * 16 + lane15) * 48 + quad * 8);
#pragma unroll
    for (int nt = 0; nt < 2; ++nt)
      b_[nt] = *(const short8*)(Bs + (wn * 32 + nt * 16 + lane15) * 48 + quad * 8);
#pragma unroll
    for (int mt = 0; mt < 2; ++mt)
#pragma unroll
      for (int nt = 0; nt < 2; ++nt)
        acc[mt][nt] = __builtin_amdgcn_mfma_f32_16x16x32_bf16(
            a_[mt], b_[nt], acc[mt][nt], 0, 0, 0);
    __syncthreads();
  }
#pragma unroll
  for (int mt = 0; mt < 2; ++mt) {
    int n0 = bn_ + wm * 32 + mt * 16 + quad * 4;
#pragma unroll
    for (int nt = 0; nt < 2; ++nt) {
      int k = bk + wn * 32 + nt * 16 + lane15;
#pragma unroll
      for (int r = 0; r < 4; ++r)
        Wf[(size_t)(n0 + r) * 1024 + 512 + k] = f2bf(acc[mt][nt][r]);
    }
  }
}

// b1p[n] = b1[n] + sum_j W1[n][512+j] * bm[j].  Grid 512 x 64thr.
__global__ __launch_bounds__(64) void b1prep(
    const float* __restrict__ W1, const float* __restrict__ b1,
    const float* __restrict__ bm, float* __restrict__ b1p) {
  const int n = blockIdx.x, lane = threadIdx.x;
  const float* rp = W1 + (size_t)n * 1024 + 512 + lane * 8;
  float4 a0 = *(const float4*)(rp);
  float4 a1 = *(const float4*)(rp + 4);
  float4 c0 = *(const float4*)(bm + lane * 8);
  float4 c1 = *(const float4*)(bm + lane * 8 + 4);
  float s = a0.x * c0.x + a0.y * c0.y + a0.z * c0.z + a0.w * c0.w +
            a1.x * c1.x + a1.y * c1.y + a1.z * c1.z + a1.w * c1.w;
#pragma unroll
  for (int o = 1; o < 64; o <<= 1) s += __shfl_xor(s, o);
  if (lane == 0) b1p[n] = b1[n] + s;
}

// ---------------------------------------------------------------------------
// 64x128 MFMA GEMM body (NT), BK=128: 256 thr / 4 waves; wave w owns the
// 32-col strip w*32 (all 64 rows): 4 m-frags x 2 n-frags, 32 MFMA + 16
// ds_read_b128 per wave per barrier-pair. global_load_lds(16B) into
// SW3-swizzled LDS. A row stride fixed 512; k0>=512 reads A2 (concat).
// Exact tiling: M%64==0, N%128==0, K%128==0. W row stride = K.
// modes: 0 fp32 out + fused BN stats; 1 bf16 Q/K head planes; 4 KV fused.
// ---------------------------------------------------------------------------
__device__ inline void gemm_body(
    const us16* __restrict__ A1, const us16* __restrict__ A2,
    const us16* __restrict__ W,
    const float* __restrict__ bias0, const float* __restrict__ bias1,
    void* __restrict__ C0, void* __restrict__ C1, float* __restrict__ stats,
    int M, int N, int K, int mode, int bx, int by) {
  __shared__ __align__(16) us16 As[64 * 128];   // 16 KB
  __shared__ __align__(16) us16 Bs[128 * 128];  // 32 KB
  const int t = threadIdx.x, w = t >> 6, lane = t & 63;
  const int lane15 = lane & 15, quad = lane >> 4;
  const int bm = bx * 64, bn = by * 128;
  const int srl = lane >> 4;    // staging row-sub 0..3
  const int sl = lane & 15;     // staging slot 0..15

  floatx4 acc[4][2];
#pragma unroll
  for (int a = 0; a < 4; ++a)
#pragma unroll
    for (int c = 0; c < 2; ++c) acc[a][c] = (floatx4){0.f, 0.f, 0.f, 0.f};

  for (int k0 = 0; k0 < K; k0 += 128) {
    const us16* Ab = (k0 < 512) ? A1 : A2;
    const int ka = k0 & 511;
    // A: 64 rows x 128 k, wave w rows [w*16, w*16+16)
#pragma unroll
    for (int p = 0; p < 4; ++p) {
      int row = w * 16 + p * 4 + srl;
      int kg = sl ^ SW3(row);
      gld16(Ab + (size_t)(bm + row) * 512 + ka + kg * 8, As + (w * 16 + p * 4) * 128);
    }
    // B: 128 rows x 128 k, wave w rows [w*32, w*32+32)
#pragma unroll
    for (int p = 0; p < 8; ++p) {
      int row = w * 32 + p * 4 + srl;
      int kg = sl ^ SW3(row);
      gld16(W + (size_t)(bn + row) * K + k0 + kg * 8, Bs + (w * 32 + p * 4) * 128);
    }
    __syncthreads();
#pragma unroll
    for (int kk = 0; kk < 4; ++kk) {
      const int g = kk * 4 + quad;
      short8 a_[4], b_[2];
#pragma unroll
      for (int mt = 0; mt < 4; ++mt) {
        int r = mt * 16 + lane15;
        a_[mt] = *(const short8*)(As + r * 128 + (g ^ SW3(r)) * 8);
      }
#pragma unroll
      for (int nt = 0; nt < 2; ++nt) {
        int c = w * 32 + nt * 16 + lane15;
        b_[nt] = *(const short8*)(Bs + c * 128 + (g ^ SW3(c)) * 8);
      }
#pragma unroll
      for (int mt = 0; mt < 4; ++mt)
#pragma unroll
        for (int nt = 0; nt < 2; ++nt)
          acc[mt][nt] = __builtin_amdgcn_mfma_f32_16x16x32_bf16(
              a_[mt], b_[nt], acc[mt][nt], 0, 0, 0);
    }
    __syncthreads();
  }

  if (mode == 0) {
#pragma unroll
    for (int nt = 0; nt < 2; ++nt) {
      int col = bn + w * 32 + nt * 16 + lane15;
      float bv = bias0[col];
      float s = 0.f, qq = 0.f;
#pragma unroll
      for (int mt = 0; mt < 4; ++mt) {
        int row0 = bm + mt * 16 + quad * 4;
#pragma unroll
        for (int r = 0; r < 4; ++r) {
          float val = acc[mt][nt][r] + bv;
          ((float*)C0)[(size_t)(row0 + r) * N + col] = val;
          s += val; qq = fmaf(val, val, qq);
        }
      }
      s += __shfl_xor(s, 16); s += __shfl_xor(s, 32);
      qq += __shfl_xor(qq, 16); qq += __shfl_xor(qq, 32);
      if (quad == 0) {
        atomicAdd(&stats[col], s);
        atomicAdd(&stats[512 + col], qq);
      }
    }
  } else if (mode == 1) {
#pragma unroll
    for (int nt = 0; nt < 2; ++nt) {
      int col = bn + w * 32 + nt * 16 + lane15;
      float bv = bias0[col];
      int hh = col & 7, dd = col >> 3;
#pragma unroll
      for (int mt = 0; mt < 4; ++mt) {
        int row0 = bm + mt * 16 + quad * 4;
#pragma unroll
        for (int r = 0; r < 4; ++r)
          ((us16*)C0)[((size_t)hh * M + row0 + r) * 64 + dd] = f2bf(acc[mt][nt][r] + bv);
      }
    }
  } else {  // mode 4: KV fused (N=1024)
#pragma unroll
    for (int nt = 0; nt < 2; ++nt) {
      int col = bn + w * 32 + nt * 16 + lane15;
      if (col < 512) {
        float bv = bias0[col];
        int hh = col & 7, dd = col >> 3;
#pragma unroll
        for (int mt = 0; mt < 4; ++mt) {
          int row0 = bm + mt * 16 + quad * 4;
#pragma unroll
          for (int r = 0; r < 4; ++r)
            ((us16*)C0)[((size_t)hh * M + row0 + r) * 64 + dd] = f2bf(acc[mt][nt][r] + bv);
        }
      } else {
        int cv = col - 512;
        float bv = bias1[cv];
        int plane = (cv & 7) * 64 + (cv >> 3);
#pragma unroll
        for (int mt = 0; mt < 4; ++mt) {
          int row0 = bm + mt * 16 + quad * 4;
          ushort4 pk;
          pk.x = f2bf(acc[mt][nt][0] + bv);
          pk.y = f2bf(acc[mt][nt][1] + bv);
          pk.z = f2bf(acc[mt][nt][2] + bv);
          pk.w = f2bf(acc[mt][nt][3] + bv);
          *(ushort4*)((us16*)C1 + (size_t)plane * M + row0) = pk;
        }
      }
    }
  }
}

// FFN GEMM: 1D grid, N-tile fastest (nN = 4) for A-panel L2/L3 locality.
__global__ __launch_bounds__(256) void gemm_ffn(
    const us16* __restrict__ A1, const us16* __restrict__ A2,
    const us16* __restrict__ W,
    const float* __restrict__ bias0, void* __restrict__ C0,
    float* __restrict__ stats, int M, int K) {
  int by = blockIdx.x & 3, bx = blockIdx.x >> 2;
  gemm_body(A1, A2, W, bias0, nullptr, C0, nullptr, stats, M, 512, K, 0, bx, by);
}

// Q projection + fused K/V projection, one 1D dispatch, N-tile fastest.
// Q: 94 m x 4 n = 376 blocks; KV: 113 m x 8 n = 904 blocks.
__global__ __launch_bounds__(256) void gemm_qkv(
    const us16* __restrict__ dst_bf, const us16* __restrict__ src_bf,
    const us16* __restrict__ Wqb, const us16* __restrict__ Wkv,
    const float* __restrict__ bq, const float* __restrict__ bk,
    const float* __restrict__ bv,
    us16* __restrict__ Qh, us16* __restrict__ Kh, us16* __restrict__ Vt,
    int Md, int Ms) {
  int i = blockIdx.x;
  int nq = (Md / 64) * 4;
  if (i < nq) {
    gemm_body(dst_bf, dst_bf, Wqb, bq, nullptr, Qh, nullptr, nullptr,
              Md, 512, 512, 1, i >> 2, i & 3);
  } else {
    int j = i - nq;
    gemm_body(src_bf, src_bf, Wkv, bk, bv, Kh, Vt, nullptr,
              Ms, 1024, 512, 4, j >> 3, j & 7);
  }
}

// ---------------------------------------------------------------------------
// attn_v6: 4 waves x 16 dst rows of one (b,h); K/Vt chunks (64x64 bf16)
// staged once per block via global_load_lds (SW3 swizzle); per-wave
// in-register online softmax (shfl over 16 lanes); 2 barriers per chunk.
// Grid (16, 8, 8), 256 thr.
// ---------------------------------------------------------------------------
__global__ __launch_bounds__(256) void attn_v6(
    const us16* __restrict__ Qh, const us16* __restrict__ Kh,
    const us16* __restrict__ Vt, const int* __restrict__ dlens,
    const int* __restrict__ slens, us16* __restrict__ O,
    int Md, int Ms) {
  const int b = blockIdx.x, h = blockIdx.y, tile = blockIdx.z;
  int doff = 0, soff = 0;
  for (int i = 0; i < NBATCH; ++i)
    if (i < b) { doff += dlens[i]; soff += slens[i]; }
  const int dlen = dlens[b], slen = slens[b];
  if (tile * 64 >= dlen) return;

  __shared__ __align__(16) us16 Ks[64 * 64];   // [j][k] swizzled
  __shared__ __align__(16) us16 Vts[64 * 64];  // [d][j] swizzled
  __shared__ __align__(16) us16 Pw[4][16 * 72];

  const int t = threadIdx.x, wv = t >> 6, lane = t & 63;
  const int lane15 = lane & 15, quad = lane >> 4;
  const int i0w = tile * 64 + wv * 16;         // this wave's dst rows
  const bool active = i0w < dlen;              // dlen % 16 == 0

  const us16* Qp = Qh + ((size_t)h * Md + doff + (active ? i0w : 0)) * 64;
  const us16* Kp = Kh + ((size_t)h * Ms + soff) * 64;
  const us16* Vtp = Vt + ((size_t)h * 64) * Ms + soff;

  // Q fragments (A-layout), direct global->VGPR
  short8 af0 = *(const short8*)(Qp + (size_t)lane15 * 64 + quad * 8);
  short8 af1 = *(const short8*)(Qp + (size_t)lane15 * 64 + 32 + quad * 8);

  floatx4 oa[4];
#pragma unroll
  for (int nt = 0; nt < 4; ++nt) oa[nt] = (floatx4){0.f, 0.f, 0.f, 0.f};
  float m_r[4] = {-3.0e38f, -3.0e38f, -3.0e38f, -3.0e38f};
  float l_r[4] = {0.f, 0.f, 0.f, 0.f};

  for (int j0 = 0; j0 < slen; j0 += 64) {
    // ---- stage K (64 j x 64 k) and Vt (64 d x 64 j), 2 issues each ----
#pragma unroll
    for (int p = 0; p < 2; ++p) {
      int row = wv * 16 + p * 8 + (lane >> 3);
      int sl = lane & 7;
      int kg = sl ^ SW3(row);
      gld16(Kp + (size_t)(j0 + row) * 64 + kg * 8, Ks + (wv * 16 + p * 8) * 64);
      gld16(Vtp + (size_t)row * Ms + j0 + kg * 8, Vts + (wv * 16 + p * 8) * 64);
    }
    __syncthreads();

    if (active) {
      // ---- scores (C-layout regs) ----
      floatx4 s[4];
#pragma unroll
      for (int jt = 0; jt < 4; ++jt) {
        int j = jt * 16 + lane15;
        short8 b0 = *(const short8*)(Ks + j * 64 + ((quad ^ SW3(j)) * 8));
        short8 b1 = *(const short8*)(Ks + j * 64 + (((4 + quad) ^ SW3(j)) * 8));
        floatx4 a = (floatx4){0.f, 0.f, 0.f, 0.f};
        a = __builtin_amdgcn_mfma_f32_16x16x32_bf16(af0, b0, a, 0, 0, 0);
        a = __builtin_amdgcn_mfma_f32_16x16x32_bf16(af1, b1, a, 0, 0, 0);
        s[jt] = a;
      }
      // ---- in-register online softmax (16 lanes per row) ----
      float mx[4] = {-3.0e38f, -3.0e38f, -3.0e38f, -3.0e38f};
#pragma unroll
      for (int jt = 0; jt < 4; ++jt) {
        bool valid = (j0 + jt * 16 + lane15) < slen;
#pragma unroll
        for (int r = 0; r < 4; ++r) {
          float v = valid ? s[jt][r] * 0.125f : -3.0e38f;
          s[jt][r] = v;
          mx[r] = fmaxf(mx[r], v);
        }
      }
#pragma unroll
      for (int r = 0; r < 4; ++r) {
        mx[r] = fmaxf(mx[r], __shfl_xor(mx[r], 1));
        mx[r] = fmaxf(mx[r], __shfl_xor(mx[r], 2));
        mx[r] = fmaxf(mx[r], __shfl_xor(mx[r], 4));
        mx[r] = fmaxf(mx[r], __shfl_xor(mx[r], 8));
      }
      float al[4], sum[4];
#pragma unroll
      for (int r = 0; r < 4; ++r) {
        float mn = fmaxf(m_r[r], mx[r]);
        al[r] = __expf(m_r[r] - mn);
        m_r[r] = mn;
        sum[r] = 0.f;
      }
#pragma unroll
      for (int jt = 0; jt < 4; ++jt)
#pragma unroll
        for (int r = 0; r < 4; ++r) {
          float e = __expf(s[jt][r] - m_r[r]);
          sum[r] += e;
          Pw[wv][(quad * 4 + r) * 72 + jt * 16 + lane15] = f2bf(e);
        }
#pragma unroll
      for (int r = 0; r < 4; ++r) {
        sum[r] += __shfl_xor(sum[r], 1);
        sum[r] += __shfl_xor(sum[r], 2);
        sum[r] += __shfl_xor(sum[r], 4);
        sum[r] += __shfl_xor(sum[r], 8);
        l_r[r] = l_r[r] * al[r] + sum[r];
      }
      // ---- rescale O, P C->A via wave-private LDS, PV ----
#pragma unroll
      for (int nt = 0; nt < 4; ++nt)
#pragma unroll
        for (int r = 0; r < 4; ++r) oa[nt][r] *= al[r];
      short8 pa0 = *(const short8*)(&Pw[wv][lane15 * 72 + quad * 8]);
      short8 pa1 = *(const short8*)(&Pw[wv][lane15 * 72 + 32 + quad * 8]);
#pragma unroll
      for (int nt = 0; nt < 4; ++nt) {
        int d = nt * 16 + lane15;
        short8 v0 = *(const short8*)(Vts + d * 64 + ((quad ^ SW3(d)) * 8));
        short8 v1 = *(const short8*)(Vts + d * 64 + (((4 + quad) ^ SW3(d)) * 8));
        oa[nt] = __builtin_amdgcn_mfma_f32_16x16x32_bf16(pa0, v0, oa[nt], 0, 0, 0);
        oa[nt] = __builtin_amdgcn_mfma_f32_16x16x32_bf16(pa1, v1, oa[nt], 0, 0, 0);
      }
    }
    __syncthreads();
  }

  if (active) {
    float linv[4];
#pragma unroll
    for (int r = 0; r < 4; ++r) linv[r] = 1.f / l_r[r];
#pragma unroll
    for (int r = 0; r < 4; ++r) {
      int i = quad * 4 + r;
      us16* orow = O + (size_t)(doff + i0w + i) * H_DIM + h;
#pragma unroll
      for (int nt = 0; nt < 4; ++nt) {
        int d = nt * 16 + lane15;
        orow[d * 8] = f2bf(oa[nt][r] * linv[r]);
      }
    }
  }
}

// ---------------------------------------------------------------------------
// BN apply: optional ReLU / residual; out_bf selects bf16 vs fp32 output.
// ---------------------------------------------------------------------------
__global__ __launch_bounds__(256) void bn_apply(
    const float* __restrict__ X, const float* __restrict__ stats,
    const float* __restrict__ g, const float* __restrict__ be,
    const float* __restrict__ resid, void* __restrict__ Y,
    int M, float invM, int relu, int out_bf) {
  const size_t total = (size_t)M * H_DIM;
  for (size_t i = (size_t)blockIdx.x * 256 + threadIdx.x; i < total;
       i += (size_t)gridDim.x * 256) {
    int c = (int)(i & (H_DIM - 1));
    float mean = stats[c] * invM;
    float var = fmaf(-mean, mean, stats[H_DIM + c] * invM);
    float x = X[i];
    float y = (x - mean) * rsqrtf(var + 1e-5f) * g[c] + be[c];
    if (relu) y = fmaxf(y, 0.f);
    if (resid) y += resid[i];
    if (out_bf) ((us16*)Y)[i] = f2bf(y);
    else ((float*)Y)[i] = y;
  }
}

// ---------------------------------------------------------------------------
extern "C" void kernel_launch(void* const* d_in, const int* in_sizes, int n_in,
                              void* d_out, int out_size, void* d_ws, size_t ws_size,
                              hipStream_t stream) {
  const float* src_h = (const float*)d_in[0];
  const float* dst_h = (const float*)d_in[1];
  const int* s_lens  = (const int*)d_in[2];
  const int* d_lens  = (const int*)d_in[3];
  const float* Wq = (const float*)d_in[4];  const float* bq = (const float*)d_in[5];
  const float* Wk = (const float*)d_in[6];  const float* bk = (const float*)d_in[7];
  const float* Wv = (const float*)d_in[8];  const float* bv = (const float*)d_in[9];
  const float* Wm = (const float*)d_in[10]; const float* bm = (const float*)d_in[11];
  const float* W1 = (const float*)d_in[12]; const float* b1 = (const float*)d_in[13];
  const float* g1 = (const float*)d_in[14]; const float* be1 = (const float*)d_in[15];
  const float* W2 = (const float*)d_in[16]; const float* b2 = (const float*)d_in[17];
  const float* g2 = (const float*)d_in[18]; const float* be2 = (const float*)d_in[19];

  const int total_src = in_sizes[0] / H_DIM;  // 7232 = 113*64
  const int total_dst = in_sizes[1] / H_DIM;  // 6016 = 94*64

  // ---- workspace layout (byte offsets); peak ~50.5 MB ----
  char* ws = (char*)d_ws;
  us16* src_bf = (us16*)(ws + 0);                    //  7,405,568
  us16* dst_bf = (us16*)(ws + 7405568);              //  6,160,384
  us16* wbf    = (us16*)(ws + 13565952);             //  3,145,728 used
  float* b1p   = (float*)(ws + 16711680);            //  2,048 (gap before Qh)
  us16* Qh     = (us16*)(ws + 17235968);             //  6,160,384
  us16* Kh     = (us16*)(ws + 23396352);             //  7,405,568
  us16* Vt     = (us16*)(ws + 30801920);             //  7,405,568
  us16* Ob     = (us16*)(ws + 38207488);             //  6,160,384
  us16* X1bf   = (us16*)(ws + 44367872);             //  6,160,384
  float* st    = (float*)(ws + 50528256);            //  8,192
  float* X1    = (float*)(ws + 17235968);            // aliases Qh+Kh (dead)
  float* X2    = (float*)(ws + 30801920);            // aliases Vt+Ob (dead)
  float* st1 = st, *st2 = st + 1024;

  us16* Wqb = wbf;                 // 262144 elems
  us16* Wkv = wbf + 262144;        // 524288 (Wk rows then Wv rows)
  us16* Wf  = wbf + 786432;        // 524288 ([W1a | Wc] rows of 1024)
  us16* W2b = wbf + 1310720;       // 262144

  const int mbd = total_dst / 64;  // 94
  const int mbs = total_src / 64;  // 113
  const dim3 blk256(256), blk64(64);

  // 1: casts (+BN-stat zero)
  cast_all<<<dim3(2048), blk256, 0, stream>>>(
      src_h, dst_h, Wq, Wk, Wv, W1, W2,
      src_bf, dst_bf, Wqb, Wkv, Wf, W2b, st,
      total_src * H_DIM, total_dst * H_DIM);

  // 2-3: weight composites (Wc = W1b@Wm -> Wf[:,512:], b1p = b1 + W1b@bm)
  wprep<<<dim3(8, 8), blk256, 0, stream>>>(W1, Wm, Wf);
  b1prep<<<dim3(512), blk64, 0, stream>>>(W1, b1, bm, b1p);

  // 4: Q + fused K/V projections (1D grid, N-fastest for A-panel locality)
  gemm_qkv<<<dim3(mbd * 4 + mbs * 8), blk256, 0, stream>>>(
      dst_bf, src_bf, Wqb, Wkv, bq, bk, bv, Qh, Kh, Vt, total_dst, total_src);

  // 5: attention -> Ob (bf16 [M,512])
  attn_v6<<<dim3(NBATCH, N_HEADS, 8), blk256, 0, stream>>>(
      Qh, Kh, Vt, d_lens, s_lens, Ob, total_dst, total_src);

  // 6: FFN1 (merge folded in): [dst_bf | Ob] @ Wf^T + b1p -> X1 + BN1 stats
  gemm_ffn<<<dim3(mbd * 4), blk256, 0, stream>>>(
      dst_bf, Ob, Wf, b1p, X1, st1, total_dst, 1024);

  // 7: BN1 + ReLU -> X1bf
  bn_apply<<<dim3(512), blk256, 0, stream>>>(X1, st1, g1, be1, nullptr, X1bf,
                                             total_dst, 1.f / (float)total_dst, 1, 1);

  // 8: FFN2 -> X2 + BN2 stats
  gemm_ffn<<<dim3(mbd * 4), blk256, 0, stream>>>(
      X1bf, X1bf, W2b, b2, X2, st2, total_dst, 512);

  // 9: BN2 + residual -> d_out
  bn_apply<<<dim3(512), blk256, 0, stream>>>(X2, st2, g2, be2, dst_h, d_out,
                                             total_dst, 1.f / (float)total_dst, 0, 0);
}

// Round 10
// 258.206 us; speedup vs baseline: 27.2630x; 1.0127x over previous
//
#include <hip/hip_runtime.h>
#include <hip/hip_bf16.h>

#define H_DIM 512
#define N_HEADS 8
#define HEAD_DIM 64
#define NBATCH 16

typedef __attribute__((ext_vector_type(8))) short short8;   // 8 bf16 (4 VGPRs)
typedef __attribute__((ext_vector_type(4))) float floatx4;  // MFMA acc

typedef unsigned short us16;

// 3-bit row swizzle for XOR'd LDS slots (structurally conflict-free b128)
#define SW3(r) ((((r) >> 1) & 3) | (((r) & 1) << 2))

__device__ inline unsigned short f2bf(float f) {
  unsigned int u = __float_as_uint(f);
  unsigned int r = (u + 0x7fffu + ((u >> 16) & 1u)) >> 16;  // RNE
  return (unsigned short)r;
}

// async global->LDS, 16B/lane; lds dest = wave-uniform base + lane*16
__device__ inline void gld16(const us16* g, us16* l) {
  __builtin_amdgcn_global_load_lds(
      (const __attribute__((address_space(1))) void*)g,
      (__attribute__((address_space(3))) void*)l, 16, 0, 0);
}

// ---------------------------------------------------------------------------
// prep_all: one dispatch for (a) all fp32->bf16 casts + BN-stat zero
// [blocks 0..2047], (b) Wc = W1b @ Wm weight composite [blocks 2048..2111],
// (c) b1p = b1 + W1b @ bm [blocks 2112..2113]. All three are independent.
// ---------------------------------------------------------------------------
__global__ __launch_bounds__(256) void prep_all(
    const float* __restrict__ src_h, const float* __restrict__ dst_h,
    const float* __restrict__ Wq, const float* __restrict__ Wk,
    const float* __restrict__ Wv, const float* __restrict__ W1,
    const float* __restrict__ W2, const float* __restrict__ Wm,
    const float* __restrict__ b1, const float* __restrict__ bm,
    us16* __restrict__ src_bf, us16* __restrict__ dst_bf,
    us16* __restrict__ Wqb, us16* __restrict__ Wkv, us16* __restrict__ Wf,
    us16* __restrict__ W2b, float* __restrict__ b1p, float* __restrict__ st,
    int n_src, int n_dst) {
  __shared__ __align__(16) us16 As[64 * 48];
  __shared__ __align__(16) us16 Bs[64 * 48];
  const int blk = blockIdx.x;
  const int t = threadIdx.x;

  if (blk < 2048) {  // ---- casts ----
    if (blk == 0) {
      float4 z = make_float4(0.f, 0.f, 0.f, 0.f);
      ((float4*)st)[t] = z;
      ((float4*)st)[t + 256] = z;
    }
    const float* srcs[7] = {src_h, dst_h, Wq, Wk, Wv, W1, W2};
    us16* dsts[7] = {src_bf, dst_bf, Wqb, Wkv, Wkv + 262144, Wf, W2b};
    int ns[7] = {n_src, n_dst, 262144, 262144, 262144, 262144, 262144};
    for (int rg = 0; rg < 7; ++rg) {
      const float* sp = srcs[rg];
      us16* dp = dsts[rg];
      const bool strided = (rg == 5);  // W1a -> Wf cols 0:512 of 1024-wide rows
      for (int i = (blk * 256 + t) * 4; i < ns[rg]; i += 2048 * 256 * 4) {
        int j = strided ? ((i >> 9) * 1024 + (i & 511)) : i;
        float4 v = *(const float4*)(sp + j);
        ushort4 o;
        o.x = f2bf(v.x); o.y = f2bf(v.y); o.z = f2bf(v.z); o.w = f2bf(v.w);
        *(ushort4*)(dp + j) = o;
      }
    }
  } else if (blk < 2112) {  // ---- wprep: Wc[n][k] into Wf[n*1024+512+k] ----
    const int bx = (blk - 2048) & 7, byk = (blk - 2048) >> 3;
    const int w = t >> 6, lane = t & 63;
    const int lane15 = lane & 15, quad = lane >> 4;
    const int wm = w >> 1, wn = w & 1;
    const int bn_ = bx * 64, bk = byk * 64;
    floatx4 acc[2][2];
#pragma unroll
    for (int a = 0; a < 2; ++a)
#pragma unroll
      for (int c = 0; c < 2; ++c) acc[a][c] = (floatx4){0.f, 0.f, 0.f, 0.f};
    for (int j0 = 0; j0 < 512; j0 += 32) {
      {
        int n = t >> 2, jj0 = (t & 3) * 8;
        const float* rp = W1 + (size_t)(bn_ + n) * 1024 + 512 + j0 + jj0;
        float4 va = *(const float4*)(rp);
        float4 vb = *(const float4*)(rp + 4);
        ushort4 pa, pb;
        pa.x = f2bf(va.x); pa.y = f2bf(va.y); pa.z = f2bf(va.z); pa.w = f2bf(va.w);
        pb.x = f2bf(vb.x); pb.y = f2bf(vb.y); pb.z = f2bf(vb.z); pb.w = f2bf(vb.w);
        *(ushort4*)(As + n * 48 + jj0) = pa;
        *(ushort4*)(As + n * 48 + jj0 + 4) = pb;
      }
      {
        int jj = t >> 3, kc0 = (t & 7) * 8;
        const float* rp = Wm + (size_t)(j0 + jj) * 512 + bk + kc0;
        float4 va = *(const float4*)(rp);
        float4 vb = *(const float4*)(rp + 4);
        float vv[8] = {va.x, va.y, va.z, va.w, vb.x, vb.y, vb.z, vb.w};
#pragma unroll
        for (int e = 0; e < 8; ++e) Bs[(kc0 + e) * 48 + jj] = f2bf(vv[e]);
      }
      __syncthreads();
      short8 a_[2], b_[2];
#pragma unroll
      for (int mt = 0; mt < 2; ++mt)
        a_[mt] = *(const short8*)(As + (wm * 32 + mt * 16 + lane15) * 48 + quad * 8);
#pragma unroll
      for (int nt = 0; nt < 2; ++nt)
        b_[nt] = *(const short8*)(Bs + (wn * 32 + nt * 16 + lane15) * 48 + quad * 8);
#pragma unroll
      for (int mt = 0; mt < 2; ++mt)
#pragma unroll
        for (int nt = 0; nt < 2; ++nt)
          acc[mt][nt] = __builtin_amdgcn_mfma_f32_16x16x32_bf16(
              a_[mt], b_[nt], acc[mt][nt], 0, 0, 0);
      __syncthreads();
    }
#pragma unroll
    for (int mt = 0; mt < 2; ++mt) {
      int n0 = bn_ + wm * 32 + mt * 16 + quad * 4;
#pragma unroll
      for (int nt = 0; nt < 2; ++nt) {
        int k = bk + wn * 32 + nt * 16 + lane15;
#pragma unroll
        for (int r = 0; r < 4; ++r)
          Wf[(size_t)(n0 + r) * 1024 + 512 + k] = f2bf(acc[mt][nt][r]);
      }
    }
  } else {  // ---- b1prep: 2 blocks x 256 threads, one n per thread ----
    int n = (blk - 2112) * 256 + t;
    if (n < 512) {
      const float* rp = W1 + (size_t)n * 1024 + 512;
      float s = 0.f;
      for (int j = 0; j < 512; j += 4) {
        float4 a = *(const float4*)(rp + j);
        float4 c = *(const float4*)(bm + j);
        s += a.x * c.x + a.y * c.y + a.z * c.z + a.w * c.w;
      }
      b1p[n] = b1[n] + s;
    }
  }
}

// ---------------------------------------------------------------------------
// 64x128 MFMA GEMM body (NT), BK=64 DOUBLE-BUFFERED: 256 thr / 4 waves;
// wave w owns col strip w*32. Per K-step per wave: 16 MFMA + 8 ds_read_b128
// + 6 gld16. Chunk i+1 is issued via global_load_lds BEFORE the MFMA work on
// chunk i, so the barrier's vmcnt(0) drain lands after a full compute phase.
// A row stride fixed 512; k0>=512 reads A2 (concat). M%64==0, N%128==0,
// K%64==0. W row stride = K.
// modes: 0 fp32 out + fused BN stats; 1 bf16 head planes; 4 KV fused.
// ---------------------------------------------------------------------------
__device__ inline void gemm_body(
    const us16* __restrict__ A1, const us16* __restrict__ A2,
    const us16* __restrict__ W,
    const float* __restrict__ bias0, const float* __restrict__ bias1,
    void* __restrict__ C0, void* __restrict__ C1, float* __restrict__ stats,
    int M, int N, int K, int mode, int bx, int by) {
  __shared__ __align__(16) us16 As[2 * 64 * 64];    // 16 KB
  __shared__ __align__(16) us16 Bs[2 * 128 * 64];   // 32 KB
  const int t = threadIdx.x, w = t >> 6, lane = t & 63;
  const int lane15 = lane & 15, quad = lane >> 4;
  const int bm = bx * 64, bn = by * 128;
  const int lrow = lane >> 3;  // 0..7
  const int sl = lane & 7;     // slot 0..7

  floatx4 acc[4][2];
#pragma unroll
  for (int a = 0; a < 4; ++a)
#pragma unroll
    for (int c = 0; c < 2; ++c) acc[a][c] = (floatx4){0.f, 0.f, 0.f, 0.f};

  const int nk = K >> 6;

  // ---- issue chunk i into buffer b (async, no waits) ----
#define ISSUE(i, b)                                                          \
  {                                                                          \
    int k0 = (i) << 6;                                                       \
    const us16* Ab = (k0 < 512) ? A1 : A2;                                   \
    int ka = k0 & 511;                                                       \
    _Pragma("unroll")                                                        \
    for (int p = 0; p < 2; ++p) {                                            \
      int rbase = p * 32 + w * 8;                                            \
      int row = rbase + lrow;                                                \
      int kg = sl ^ SW3(row);                                                \
      gld16(Ab + (size_t)(bm + row) * 512 + ka + kg * 8,                     \
            As + (b) * 4096 + rbase * 64);                                   \
    }                                                                        \
    _Pragma("unroll")                                                        \
    for (int p = 0; p < 4; ++p) {                                            \
      int rbase = p * 32 + w * 8;                                            \
      int row = rbase + lrow;                                                \
      int kg = sl ^ SW3(row);                                                \
      gld16(W + (size_t)(bn + row) * K + k0 + kg * 8,                        \
            Bs + (b) * 8192 + rbase * 64);                                   \
    }                                                                        \
  }

  ISSUE(0, 0);
  __syncthreads();
  for (int i = 0; i < nk; ++i) {
    const int cur = i & 1;
    if (i + 1 < nk) ISSUE(i + 1, cur ^ 1);
    // compute chunk i from buf cur
#pragma unroll
    for (int kh = 0; kh < 2; ++kh) {
      const int g = kh * 4 + quad;
      short8 a_[4], b_[2];
#pragma unroll
      for (int mt = 0; mt < 4; ++mt) {
        int r = mt * 16 + lane15;
        a_[mt] = *(const short8*)(As + cur * 4096 + r * 64 + (g ^ SW3(r)) * 8);
      }
#pragma unroll
      for (int nt = 0; nt < 2; ++nt) {
        int c = w * 32 + nt * 16 + lane15;
        b_[nt] = *(const short8*)(Bs + cur * 8192 + c * 64 + (g ^ SW3(c)) * 8);
      }
#pragma unroll
      for (int mt = 0; mt < 4; ++mt)
#pragma unroll
        for (int nt = 0; nt < 2; ++nt)
          acc[mt][nt] = __builtin_amdgcn_mfma_f32_16x16x32_bf16(
              a_[mt], b_[nt], acc[mt][nt], 0, 0, 0);
    }
    __syncthreads();  // drains vmcnt: chunk i+1 resident; buf cur reusable
  }
#undef ISSUE

  if (mode == 0) {
#pragma unroll
    for (int nt = 0; nt < 2; ++nt) {
      int col = bn + w * 32 + nt * 16 + lane15;
      float bv = bias0[col];
      float s = 0.f, qq = 0.f;
#pragma unroll
      for (int mt = 0; mt < 4; ++mt) {
        int row0 = bm + mt * 16 + quad * 4;
#pragma unroll
        for (int r = 0; r < 4; ++r) {
          float val = acc[mt][nt][r] + bv;
          ((float*)C0)[(size_t)(row0 + r) * N + col] = val;
          s += val; qq = fmaf(val, val, qq);
        }
      }
      s += __shfl_xor(s, 16); s += __shfl_xor(s, 32);
      qq += __shfl_xor(qq, 16); qq += __shfl_xor(qq, 32);
      if (quad == 0) {
        atomicAdd(&stats[col], s);
        atomicAdd(&stats[512 + col], qq);
      }
    }
  } else if (mode == 1) {
#pragma unroll
    for (int nt = 0; nt < 2; ++nt) {
      int col = bn + w * 32 + nt * 16 + lane15;
      float bv = bias0[col];
      int hh = col & 7, dd = col >> 3;
#pragma unroll
      for (int mt = 0; mt < 4; ++mt) {
        int row0 = bm + mt * 16 + quad * 4;
#pragma unroll
        for (int r = 0; r < 4; ++r)
          ((us16*)C0)[((size_t)hh * M + row0 + r) * 64 + dd] = f2bf(acc[mt][nt][r] + bv);
      }
    }
  } else {  // mode 4: KV fused (N=1024)
#pragma unroll
    for (int nt = 0; nt < 2; ++nt) {
      int col = bn + w * 32 + nt * 16 + lane15;
      if (col < 512) {
        float bv = bias0[col];
        int hh = col & 7, dd = col >> 3;
#pragma unroll
        for (int mt = 0; mt < 4; ++mt) {
          int row0 = bm + mt * 16 + quad * 4;
#pragma unroll
          for (int r = 0; r < 4; ++r)
            ((us16*)C0)[((size_t)hh * M + row0 + r) * 64 + dd] = f2bf(acc[mt][nt][r] + bv);
        }
      } else {
        int cv = col - 512;
        float bv = bias1[cv];
        int plane = (cv & 7) * 64 + (cv >> 3);
#pragma unroll
        for (int mt = 0; mt < 4; ++mt) {
          int row0 = bm + mt * 16 + quad * 4;
          ushort4 pk;
          pk.x = f2bf(acc[mt][nt][0] + bv);
          pk.y = f2bf(acc[mt][nt][1] + bv);
          pk.z = f2bf(acc[mt][nt][2] + bv);
          pk.w = f2bf(acc[mt][nt][3] + bv);
          *(ushort4*)((us16*)C1 + (size_t)plane * M + row0) = pk;
        }
      }
    }
  }
}

// FFN GEMM: 1D grid, N-tile fastest (4 n-tiles) for A-panel L2/L3 locality.
__global__ __launch_bounds__(256) void gemm_ffn(
    const us16* __restrict__ A1, const us16* __restrict__ A2,
    const us16* __restrict__ W,
    const float* __restrict__ bias0, void* __restrict__ C0,
    float* __restrict__ stats, int M, int K) {
  gemm_body(A1, A2, W, bias0, nullptr, C0, nullptr, stats, M, 512, K, 0,
            blockIdx.x >> 2, blockIdx.x & 3);
}

// Q projection + fused K/V projection, one 1D dispatch, N-tile fastest.
__global__ __launch_bounds__(256) void gemm_qkv(
    const us16* __restrict__ dst_bf, const us16* __restrict__ src_bf,
    const us16* __restrict__ Wqb, const us16* __restrict__ Wkv,
    const float* __restrict__ bq, const float* __restrict__ bk,
    const float* __restrict__ bv,
    us16* __restrict__ Qh, us16* __restrict__ Kh, us16* __restrict__ Vt,
    int Md, int Ms) {
  int i = blockIdx.x;
  int nq = (Md / 64) * 4;
  if (i < nq) {
    gemm_body(dst_bf, dst_bf, Wqb, bq, nullptr, Qh, nullptr, nullptr,
              Md, 512, 512, 1, i >> 2, i & 3);
  } else {
    int j = i - nq;
    gemm_body(src_bf, src_bf, Wkv, bk, bv, Kh, Vt, nullptr,
              Ms, 1024, 512, 4, j >> 3, j & 7);
  }
}

// ---------------------------------------------------------------------------
// attn_v6 (unchanged): 4 waves x 16 dst rows of one (b,h); K/Vt chunks
// staged via global_load_lds (SW3 swizzle); per-wave register softmax;
// 2 barriers per chunk. Grid (16, 8, 8), 256 thr.
// ---------------------------------------------------------------------------
__global__ __launch_bounds__(256) void attn_v6(
    const us16* __restrict__ Qh, const us16* __restrict__ Kh,
    const us16* __restrict__ Vt, const int* __restrict__ dlens,
    const int* __restrict__ slens, us16* __restrict__ O,
    int Md, int Ms) {
  const int b = blockIdx.x, h = blockIdx.y, tile = blockIdx.z;
  int doff = 0, soff = 0;
  for (int i = 0; i < NBATCH; ++i)
    if (i < b) { doff += dlens[i]; soff += slens[i]; }
  const int dlen = dlens[b], slen = slens[b];
  if (tile * 64 >= dlen) return;

  __shared__ __align__(16) us16 Ks[64 * 64];
  __shared__ __align__(16) us16 Vts[64 * 64];
  __shared__ __align__(16) us16 Pw[4][16 * 72];

  const int t = threadIdx.x, wv = t >> 6, lane = t & 63;
  const int lane15 = lane & 15, quad = lane >> 4;
  const int i0w = tile * 64 + wv * 16;
  const bool active = i0w < dlen;  // dlen % 16 == 0

  const us16* Qp = Qh + ((size_t)h * Md + doff + (active ? i0w : 0)) * 64;
  const us16* Kp = Kh + ((size_t)h * Ms + soff) * 64;
  const us16* Vtp = Vt + ((size_t)h * 64) * Ms + soff;

  short8 af0 = *(const short8*)(Qp + (size_t)lane15 * 64 + quad * 8);
  short8 af1 = *(const short8*)(Qp + (size_t)lane15 * 64 + 32 + quad * 8);

  floatx4 oa[4];
#pragma unroll
  for (int nt = 0; nt < 4; ++nt) oa[nt] = (floatx4){0.f, 0.f, 0.f, 0.f};
  float m_r[4] = {-3.0e38f, -3.0e38f, -3.0e38f, -3.0e38f};
  float l_r[4] = {0.f, 0.f, 0.f, 0.f};

  for (int j0 = 0; j0 < slen; j0 += 64) {
#pragma unroll
    for (int p = 0; p < 2; ++p) {
      int row = wv * 16 + p * 8 + (lane >> 3);
      int sl = lane & 7;
      int kg = sl ^ SW3(row);
      gld16(Kp + (size_t)(j0 + row) * 64 + kg * 8, Ks + (wv * 16 + p * 8) * 64);
      gld16(Vtp + (size_t)row * Ms + j0 + kg * 8, Vts + (wv * 16 + p * 8) * 64);
    }
    __syncthreads();

    if (active) {
      floatx4 s[4];
#pragma unroll
      for (int jt = 0; jt < 4; ++jt) {
        int j = jt * 16 + lane15;
        short8 b0 = *(const short8*)(Ks + j * 64 + ((quad ^ SW3(j)) * 8));
        short8 b1 = *(const short8*)(Ks + j * 64 + (((4 + quad) ^ SW3(j)) * 8));
        floatx4 a = (floatx4){0.f, 0.f, 0.f, 0.f};
        a = __builtin_amdgcn_mfma_f32_16x16x32_bf16(af0, b0, a, 0, 0, 0);
        a = __builtin_amdgcn_mfma_f32_16x16x32_bf16(af1, b1, a, 0, 0, 0);
        s[jt] = a;
      }
      float mx[4] = {-3.0e38f, -3.0e38f, -3.0e38f, -3.0e38f};
#pragma unroll
      for (int jt = 0; jt < 4; ++jt) {
        bool valid = (j0 + jt * 16 + lane15) < slen;
#pragma unroll
        for (int r = 0; r < 4; ++r) {
          float v = valid ? s[jt][r] * 0.125f : -3.0e38f;
          s[jt][r] = v;
          mx[r] = fmaxf(mx[r], v);
        }
      }
#pragma unroll
      for (int r = 0; r < 4; ++r) {
        mx[r] = fmaxf(mx[r], __shfl_xor(mx[r], 1));
        mx[r] = fmaxf(mx[r], __shfl_xor(mx[r], 2));
        mx[r] = fmaxf(mx[r], __shfl_xor(mx[r], 4));
        mx[r] = fmaxf(mx[r], __shfl_xor(mx[r], 8));
      }
      float al[4], sum[4];
#pragma unroll
      for (int r = 0; r < 4; ++r) {
        float mn = fmaxf(m_r[r], mx[r]);
        al[r] = __expf(m_r[r] - mn);
        m_r[r] = mn;
        sum[r] = 0.f;
      }
#pragma unroll
      for (int jt = 0; jt < 4; ++jt)
#pragma unroll
        for (int r = 0; r < 4; ++r) {
          float e = __expf(s[jt][r] - m_r[r]);
          sum[r] += e;
          Pw[wv][(quad * 4 + r) * 72 + jt * 16 + lane15] = f2bf(e);
        }
#pragma unroll
      for (int r = 0; r < 4; ++r) {
        sum[r] += __shfl_xor(sum[r], 1);
        sum[r] += __shfl_xor(sum[r], 2);
        sum[r] += __shfl_xor(sum[r], 4);
        sum[r] += __shfl_xor(sum[r], 8);
        l_r[r] = l_r[r] * al[r] + sum[r];
      }
#pragma unroll
      for (int nt = 0; nt < 4; ++nt)
#pragma unroll
        for (int r = 0; r < 4; ++r) oa[nt][r] *= al[r];
      short8 pa0 = *(const short8*)(&Pw[wv][lane15 * 72 + quad * 8]);
      short8 pa1 = *(const short8*)(&Pw[wv][lane15 * 72 + 32 + quad * 8]);
#pragma unroll
      for (int nt = 0; nt < 4; ++nt) {
        int d = nt * 16 + lane15;
        short8 v0 = *(const short8*)(Vts + d * 64 + ((quad ^ SW3(d)) * 8));
        short8 v1 = *(const short8*)(Vts + d * 64 + (((4 + quad) ^ SW3(d)) * 8));
        oa[nt] = __builtin_amdgcn_mfma_f32_16x16x32_bf16(pa0, v0, oa[nt], 0, 0, 0);
        oa[nt] = __builtin_amdgcn_mfma_f32_16x16x32_bf16(pa1, v1, oa[nt], 0, 0, 0);
      }
    }
    __syncthreads();
  }

  if (active) {
    float linv[4];
#pragma unroll
    for (int r = 0; r < 4; ++r) linv[r] = 1.f / l_r[r];
#pragma unroll
    for (int r = 0; r < 4; ++r) {
      int i = quad * 4 + r;
      us16* orow = O + (size_t)(doff + i0w + i) * H_DIM + h;
#pragma unroll
      for (int nt = 0; nt < 4; ++nt) {
        int d = nt * 16 + lane15;
        orow[d * 8] = f2bf(oa[nt][r] * linv[r]);
      }
    }
  }
}

// ---------------------------------------------------------------------------
// BN apply: optional ReLU / residual; out_bf selects bf16 vs fp32 output.
// ---------------------------------------------------------------------------
__global__ __launch_bounds__(256) void bn_apply(
    const float* __restrict__ X, const float* __restrict__ stats,
    const float* __restrict__ g, const float* __restrict__ be,
    const float* __restrict__ resid, void* __restrict__ Y,
    int M, float invM, int relu, int out_bf) {
  const size_t total = (size_t)M * H_DIM;
  for (size_t i = (size_t)blockIdx.x * 256 + threadIdx.x; i < total;
       i += (size_t)gridDim.x * 256) {
    int c = (int)(i & (H_DIM - 1));
    float mean = stats[c] * invM;
    float var = fmaf(-mean, mean, stats[H_DIM + c] * invM);
    float x = X[i];
    float y = (x - mean) * rsqrtf(var + 1e-5f) * g[c] + be[c];
    if (relu) y = fmaxf(y, 0.f);
    if (resid) y += resid[i];
    if (out_bf) ((us16*)Y)[i] = f2bf(y);
    else ((float*)Y)[i] = y;
  }
}

// ---------------------------------------------------------------------------
extern "C" void kernel_launch(void* const* d_in, const int* in_sizes, int n_in,
                              void* d_out, int out_size, void* d_ws, size_t ws_size,
                              hipStream_t stream) {
  const float* src_h = (const float*)d_in[0];
  const float* dst_h = (const float*)d_in[1];
  const int* s_lens  = (const int*)d_in[2];
  const int* d_lens  = (const int*)d_in[3];
  const float* Wq = (const float*)d_in[4];  const float* bq = (const float*)d_in[5];
  const float* Wk = (const float*)d_in[6];  const float* bk = (const float*)d_in[7];
  const float* Wv = (const float*)d_in[8];  const float* bv = (const float*)d_in[9];
  const float* Wm = (const float*)d_in[10]; const float* bm = (const float*)d_in[11];
  const float* W1 = (const float*)d_in[12]; const float* b1 = (const float*)d_in[13];
  const float* g1 = (const float*)d_in[14]; const float* be1 = (const float*)d_in[15];
  const float* W2 = (const float*)d_in[16]; const float* b2 = (const float*)d_in[17];
  const float* g2 = (const float*)d_in[18]; const float* be2 = (const float*)d_in[19];

  const int total_src = in_sizes[0] / H_DIM;  // 7232 = 113*64
  const int total_dst = in_sizes[1] / H_DIM;  // 6016 = 94*64

  // ---- workspace layout (byte offsets); peak ~50.5 MB ----
  char* ws = (char*)d_ws;
  us16* src_bf = (us16*)(ws + 0);                    //  7,405,568
  us16* dst_bf = (us16*)(ws + 7405568);              //  6,160,384
  us16* wbf    = (us16*)(ws + 13565952);             //  3,145,728 used
  float* b1p   = (float*)(ws + 16711680);            //  2,048
  us16* Qh     = (us16*)(ws + 17235968);             //  6,160,384
  us16* Kh     = (us16*)(ws + 23396352);             //  7,405,568
  us16* Vt     = (us16*)(ws + 30801920);             //  7,405,568
  us16* Ob     = (us16*)(ws + 38207488);             //  6,160,384
  us16* X1bf   = (us16*)(ws + 44367872);             //  6,160,384
  float* st    = (float*)(ws + 50528256);            //  8,192
  float* X1    = (float*)(ws + 17235968);            // aliases Qh+Kh (dead)
  float* X2    = (float*)(ws + 30801920);            // aliases Vt+Ob (dead)
  float* st1 = st, *st2 = st + 1024;

  us16* Wqb = wbf;                 // 262144 elems
  us16* Wkv = wbf + 262144;        // 524288 (Wk rows then Wv rows)
  us16* Wf  = wbf + 786432;        // 524288 ([W1a | Wc] rows of 1024)
  us16* W2b = wbf + 1310720;       // 262144

  const int mbd = total_dst / 64;  // 94
  const int mbs = total_src / 64;  // 113
  const dim3 blk256(256);

  // 1: casts + weight composites + BN-stat zero (one dispatch)
  prep_all<<<dim3(2114), blk256, 0, stream>>>(
      src_h, dst_h, Wq, Wk, Wv, W1, W2, Wm, b1, bm,
      src_bf, dst_bf, Wqb, Wkv, Wf, W2b, b1p, st,
      total_src * H_DIM, total_dst * H_DIM);

  // 2: Q + fused K/V projections (1D grid, N-fastest, dbuf)
  gemm_qkv<<<dim3(mbd * 4 + mbs * 8), blk256, 0, stream>>>(
      dst_bf, src_bf, Wqb, Wkv, bq, bk, bv, Qh, Kh, Vt, total_dst, total_src);

  // 3: attention -> Ob (bf16 [M,512])
  attn_v6<<<dim3(NBATCH, N_HEADS, 8), blk256, 0, stream>>>(
      Qh, Kh, Vt, d_lens, s_lens, Ob, total_dst, total_src);

  // 4: FFN1 (merge folded in): [dst_bf | Ob] @ Wf^T + b1p -> X1 + BN1 stats
  gemm_ffn<<<dim3(mbd * 4), blk256, 0, stream>>>(
      dst_bf, Ob, Wf, b1p, X1, st1, total_dst, 1024);

  // 5: BN1 + ReLU -> X1bf
  bn_apply<<<dim3(512), blk256, 0, stream>>>(X1, st1, g1, be1, nullptr, X1bf,
                                             total_dst, 1.f / (float)total_dst, 1, 1);

  // 6: FFN2 -> X2 + BN2 stats
  gemm_ffn<<<dim3(mbd * 4), blk256, 0, stream>>>(
      X1bf, X1bf, W2b, b2, X2, st2, total_dst, 512);

  // 7: BN2 + residual -> d_out
  bn_apply<<<dim3(512), blk256, 0, stream>>>(X2, st2, g2, be2, dst_h, d_out,
                                             total_dst, 1.f / (float)total_dst, 0, 0);
}